// Round 4
// baseline (495.350 us; speedup 1.0000x reference)
//
#include <hip/hip_runtime.h>

// ---------------------------------------------------------------------------
// TransformerEncoderLayer on MI355X (gfx950).  B=4 L=2048 D=256 H=8 FF=128.
// Input dtype (fp32 vs bf16) detected at runtime; compute bf16 MFMA, fp32 acc.
// Layouts: A[m=lane&15][k=8*(lane>>4)+j], B[k=8*(lane>>4)+j][n=lane&15],
//          C/D[row=(lane>>4)*4+r][col=lane&15]
// R3: V pre-transposed [B,h,D,L].  R8: 128 q/block, XCD swizzle.
// R12: transposed dataflow (S^T = K Q^T, O^T = V^T P^T), per-lane softmax.
// R13: STATIC-MAX softmax — p = 2^(s*cexp), no running max; accum+LN1 fused.
// R14: 4 waves x 32 q (2 q-tiles/wave); NEUTRAL -> LDS read BW not binding.
// R15: cross-barrier deferred-PV pipeline; REGRESSED.  REVERTED.
// R16: bare v_exp_f32 + v_cvt_pk_bf16_f32 softmax: 198->177us, VALU 34->22%.
//      KEY EVIDENCE: VALU cycles removed converted ~1:1 to wall -> softmax
//      is fully EXPOSED serial (compiler does not overlap it with MFMAs).
// R17: intra-iteration phase interleave (no sync change, all same-wave):
//      QK-A (s0, 16 MFMA) -> QK-B (s1, 16 MFMA) with sm0's 8 exp2/pack
//      hand-interleaved 1-per-kt under the MFMA stream; pa0 read issued
//      before sm1 (in-order LDS) so the P roundtrip drains under sm1.
//      K-frags re-read in QK-B (regs would cross the 256-reg cliff).
// ---------------------------------------------------------------------------

typedef unsigned short u16;
typedef unsigned int   u32;
typedef __bf16 bf16x8 __attribute__((ext_vector_type(8)));
typedef __bf16 bf16x2 __attribute__((ext_vector_type(2)));
typedef float  f32x4  __attribute__((ext_vector_type(4)));

#define MFMA(a, b, c) __builtin_amdgcn_mfma_f32_16x16x32_bf16(a, b, c, 0, 0, 0)

#if __has_builtin(__builtin_amdgcn_exp2f)
#define EXP2(x) __builtin_amdgcn_exp2f(x)
#else
#define EXP2(x) exp2f(x)
#endif

__device__ __forceinline__ float b2f(u16 h) {
  return __uint_as_float(((u32)h) << 16);
}
__device__ __forceinline__ u16 f2b(float f) {
  u32 u = __float_as_uint(f);
  u += 0x7FFFu + ((u >> 16) & 1u);   // round-to-nearest-even
  return (u16)(u >> 16);
}
// packed f32x2 -> bf16x2 (RTNE); gfx950 backend emits v_cvt_pk_bf16_f32
__device__ __forceinline__ u32 pkbf(float lo, float hi) {
  bf16x2 v;
  v[0] = (__bf16)lo;
  v[1] = (__bf16)hi;
  return __builtin_bit_cast(u32, v);
}
__device__ __forceinline__ bf16x8 ldb8(const u16* p) { return *(const bf16x8*)p; }

typedef const __attribute__((address_space(1))) u32* gas1_t;
typedef __attribute__((address_space(3))) u32* las3_t;
__device__ __forceinline__ void gload_lds16(const u16* g, u16* lds_base) {
  __builtin_amdgcn_global_load_lds((gas1_t)(const void*)g,
                                   (las3_t)(void*)lds_base, 16, 0, 0);
}

__device__ __forceinline__ int detect_f32(const void* seq) {
  const u32* s = (const u32*)seq;
  int cnt = 0;
  #pragma unroll
  for (int i = 0; i < 64; i++) {
    u32 e = (s[i] >> 7) & 0xFFu;
    cnt += (e >= 100u && e <= 140u) ? 1 : 0;
  }
  return cnt < 48;  // 1 => fp32
}

__device__ __forceinline__ u16 ldw(const void* W, size_t idx, int isf32) {
  return isf32 ? f2b(((const float*)W)[idx]) : ((const u16*)W)[idx];
}

// ---------------------------------------------------------------------------
// Ingest: canonicalize seq (2M elems) + 6 small vectors to bf16 in ws.
// ---------------------------------------------------------------------------
__global__ __launch_bounds__(256) void ingest_kernel(
    const void* __restrict__ seq, const void* __restrict__ g1,
    const void* __restrict__ be1, const void* __restrict__ b1,
    const void* __restrict__ b2v, const void* __restrict__ g2,
    const void* __restrict__ be2, u16* __restrict__ sbuf,
    u16* __restrict__ vecs) {
  int isf32 = detect_f32(seq);
  int bx = blockIdx.x, tid = threadIdx.x;
  if (bx < 2048) {
    size_t i = (size_t)bx * 1024 + tid * 4;
    if (isf32) {
      const float* sp = (const float*)seq;
      u16 o0 = f2b(sp[i]), o1 = f2b(sp[i + 1]), o2 = f2b(sp[i + 2]), o3 = f2b(sp[i + 3]);
      uint2 ov; ov.x = (u32)o0 | ((u32)o1 << 16); ov.y = (u32)o2 | ((u32)o3 << 16);
      *(uint2*)(sbuf + i) = ov;
    } else {
      *(uint2*)(sbuf + i) = ((const uint2*)seq)[i >> 2];
    }
  } else {
    int t = bx - 2048;
    const void* src; int n;
    switch (t) {
      case 0: src = g1;  n = 256; break;
      case 1: src = be1; n = 256; break;
      case 2: src = b1;  n = 128; break;
      case 3: src = b2v; n = 256; break;
      case 4: src = g2;  n = 256; break;
      default: src = be2; n = 256; break;
    }
    if (tid < n) vecs[t * 256 + tid] = ldw(src, tid, isf32);
  }
}

// ---------------------------------------------------------------------------
// Pack weights into B-fragment-linear layout.  grid (256, 6), 256 thr.
// ---------------------------------------------------------------------------
__global__ __launch_bounds__(256) void pack_kernel(
    const void* __restrict__ Wq, const void* __restrict__ Wk,
    const void* __restrict__ Wv, const void* __restrict__ Wo,
    const void* __restrict__ W1, const void* __restrict__ W2,
    const void* __restrict__ seq,
    u16* __restrict__ pWq, u16* __restrict__ pWk, u16* __restrict__ pWv,
    u16* __restrict__ pWo, u16* __restrict__ pW1, u16* __restrict__ pW2) {
  int isf32 = detect_f32(seq);
  const void* W; u16* P; int K, N;
  switch (blockIdx.y) {
    case 0: W = Wq; P = pWq; K = 256;  N = 2048; break;
    case 1: W = Wk; P = pWk; K = 256;  N = 2048; break;
    case 2: W = Wv; P = pWv; K = 256;  N = 2048; break;
    case 3: W = Wo; P = pWo; K = 2048; N = 256;  break;
    case 4: W = W1; P = pW1; K = 256;  N = 128;  break;
    default: W = W2; P = pW2; K = 128; N = 256;  break;
  }
  int t = blockIdx.x * 256 + threadIdx.x;
  int total = (K >> 5) * (N >> 4) * 64;
  if (t >= total) return;
  int lane = t & 63, f = t >> 6;
  int NT = N >> 4;
  int kt = f / NT, nt = f - kt * NT;
  int row0 = kt * 32 + ((lane >> 4) << 3);
  int col = nt * 16 + (lane & 15);
  u16 e[8];
  #pragma unroll
  for (int j = 0; j < 8; j++) e[j] = ldw(W, (size_t)(row0 + j) * N + col, isf32);
  uint4 u;
  u.x = (u32)e[0] | ((u32)e[1] << 16);
  u.y = (u32)e[2] | ((u32)e[3] << 16);
  u.z = (u32)e[4] | ((u32)e[5] << 16);
  u.w = (u32)e[6] | ((u32)e[7] << 16);
  *(uint4*)(P + ((size_t)f * 64 + lane) * 8) = u;
}

// ---------------------------------------------------------------------------
// QKV projection for one h-chunk: X(8192x256) @ W(256, hc*256).
// Q,K -> [B,hc,L,D]; V -> transposed [B,hc,D,L].  Coalesced 16B stores via
// LDS transpose.  grid (2*hc, 64, 3), 256 threads.
// ---------------------------------------------------------------------------
__global__ __launch_bounds__(256) void qkv_kernel(
    const u16* __restrict__ X,
    const u16* __restrict__ pWq, const u16* __restrict__ pWk,
    const u16* __restrict__ pWv,
    u16* __restrict__ Qo, u16* __restrict__ Ko, u16* __restrict__ Vo,
    int ntbase, int hc) {
  __shared__ u16 blds[64 * 512];
  const u16* Pw = (blockIdx.z == 0) ? pWq : ((blockIdx.z == 1) ? pWk : pWv);
  u16* Out = (blockIdx.z == 0) ? Qo : ((blockIdx.z == 1) ? Ko : Vo);
  int tid = threadIdx.x, lane = tid & 63, w = tid >> 6;
  int nt0 = ntbase + blockIdx.x * 8;
  #pragma unroll
  for (int i = 0; i < 16; i++) {
    int u = tid + i * 256;
    int fl = u >> 6, q = u & 63;
    int kt = fl >> 3, nt = fl & 7;
    ((uint4*)blds)[u] = ((const uint4*)Pw)[(size_t)(kt * 128 + nt0 + nt) * 64 + q];
  }
  __syncthreads();
  int m0 = blockIdx.y * 128 + w * 32;
  f32x4 acc[2][8] = {};
  #pragma unroll
  for (int kt = 0; kt < 8; kt++) {
    bf16x8 a0 = ldb8(X + (size_t)(m0 + (lane & 15)) * 256 + kt * 32 + (lane >> 4) * 8);
    bf16x8 a1 = ldb8(X + (size_t)(m0 + 16 + (lane & 15)) * 256 + kt * 32 + (lane >> 4) * 8);
    const u16* bp = blds + (size_t)kt * 8 * 512 + (size_t)lane * 8;
    #pragma unroll
    for (int nt = 0; nt < 8; nt++) {
      bf16x8 b = ldb8(bp + nt * 512);
      acc[0][nt] = MFMA(a0, b, acc[0][nt]);
      acc[1][nt] = MFMA(a1, b, acc[1][nt]);
    }
  }
  int isv = (blockIdx.z == 2);
  int hl = blockIdx.x >> 1;
  int dd0 = (blockIdx.x & 1) * 128;
  int m0b = blockIdx.y * 128;
  int bi = m0b >> 11, l0 = m0b & 2047;
  __syncthreads();
  if (!isv) {
    #pragma unroll
    for (int mt = 0; mt < 2; mt++)
      #pragma unroll
      for (int nt = 0; nt < 8; nt++)
        #pragma unroll
        for (int r = 0; r < 4; r++)
          blds[(w * 32 + mt * 16 + (lane >> 4) * 4 + r) * 136 + nt * 16 + (lane & 15)] =
              f2b(acc[mt][nt][r]);
    __syncthreads();
    #pragma unroll
    for (int i = 0; i < 8; i++) {
      int c = tid + i * 256;
      int mloc = c >> 4, q = c & 15;
      uint4 v = *(uint4*)(blds + mloc * 136 + q * 8);
      *(uint4*)(Out + ((size_t)(bi * hc + hl) * 2048 + l0 + mloc) * 256 + dd0 + q * 8) = v;
    }
  } else {
    #pragma unroll
    for (int mt = 0; mt < 2; mt++)
      #pragma unroll
      for (int nt = 0; nt < 8; nt++)
        #pragma unroll
        for (int r = 0; r < 4; r++)
          blds[(nt * 16 + (lane & 15)) * 136 + w * 32 + mt * 16 + (lane >> 4) * 4 + r] =
              f2b(acc[mt][nt][r]);
    __syncthreads();
    #pragma unroll
    for (int i = 0; i < 8; i++) {
      int c = tid + i * 256;
      int nloc = c >> 4, q = c & 15;
      uint4 v = *(uint4*)(blds + nloc * 136 + q * 8);
      *(uint4*)(Out + ((size_t)(bi * hc + hl) * 256 + dd0 + nloc) * 2048 + l0 + q * 8) = v;
    }
  }
}

// ---------------------------------------------------------------------------
// Flash attention, transposed dataflow, STATIC-MAX softmax.
// R14 base: 4 waves x 32 q (2 q-tiles/wave); K+V double-buffered, ONE
// barrier/iter.  R16: cheap softmax (v_exp_f32 + cvt_pk).
// R17: intra-iter interleave — QK-A(s0) -> QK-B(s1) with sm0 under it,
// early pa0 read, sm1 covers the P roundtrip.  grid (nbh*16), 256 thr,
// 128 q/block; LDS 75776 B -> 2 blocks/CU.
// ---------------------------------------------------------------------------
__global__ __launch_bounds__(256, 2) void attn_kernel(
    const u16* __restrict__ Q, const u16* __restrict__ K,
    const u16* __restrict__ Vt, u16* __restrict__ O, int nbh) {
  __shared__ u16 kbuf[2 * 8192];   // 2 bufs x 16 frags x 512 u16 (frag-linear)
  __shared__ u16 vbuf[2 * 8192];
  __shared__ u16 plds[4 * 1280];   // per-wave P [32 q][40]
  int tid = threadIdx.x, lane = tid & 63, w = tid >> 6;
  int bi2 = blockIdx.x;
  int bh, qt;
  if (nbh >= 8) {
    int G = nbh >> 3;
    bh = (bi2 & 7) * G + (bi2 >> 3) % G;
    qt = bi2 / (8 * G);
  } else {
    bh = bi2 % nbh; qt = bi2 / nbh;
  }
  const u16* Qb  = Q  + (size_t)bh * 2048 * 256;
  const u16* Kb  = K  + (size_t)bh * 2048 * 256;
  const u16* Vtb = Vt + (size_t)bh * 256 * 2048;
  u16* Ob = O + (size_t)bh * 2048 * 256;
  int q0 = qt * 128 + w * 32;
  bf16x8 qf[2][8];   // B-operand per q-tile: n=q=lane&15, k=d
  #pragma unroll
  for (int qq = 0; qq < 2; qq++)
    #pragma unroll
    for (int kt = 0; kt < 8; kt++)
      qf[qq][kt] = ldb8(Qb + (size_t)(q0 + qq * 16 + (lane & 15)) * 256 +
                        kt * 32 + (lane >> 4) * 8);
  f32x4 o[2][16] = {};             // O^T per q-tile: [d=16nt+4quad+r][q=lane&15]
  float lsum[2] = {0.f, 0.f};      // per-lane partial sum of p, per q-tile
  const float cexp = 0.0625f * 1.44269504088896f;  // scale * log2(e)
  u16* pl = plds + (size_t)w * 1280;

  // pre-loop: issue K(0), V(0) into buffer 0 (4 waves x 4 frags = 16)
  #pragma unroll
  for (int j = 0; j < 4; j++) {
    int f = w * 4 + j;
    gload_lds16(Kb + (size_t)((f >> 3) * 16 + (lane & 15)) * 256 +
                    (f & 7) * 32 + (lane >> 4) * 8,
                kbuf + f * 512);
    gload_lds16(Vtb + (size_t)(f * 16 + (lane & 15)) * 2048 + (lane >> 4) * 8,
                vbuf + f * 512);
  }

  for (int t = 0; t < 64; t++) {
    int s0i = t * 32;
    // ONE barrier: K(t),V(t) (issued a full iteration ago) landed.
    asm volatile("s_waitcnt vmcnt(0)\ns_barrier" ::: "memory");
    if (t < 63) {
      int nb = (t + 1) & 1;
      #pragma unroll
      for (int j = 0; j < 4; j++) {
        int f = w * 4 + j;
        gload_lds16(Kb + (size_t)(s0i + 32 + (f >> 3) * 16 + (lane & 15)) * 256 +
                        (f & 7) * 32 + (lane >> 4) * 8,
                    kbuf + nb * 8192 + f * 512);
        gload_lds16(Vtb + (size_t)(f * 16 + (lane & 15)) * 2048 + s0i + 32 +
                        (lane >> 4) * 8,
                    vbuf + nb * 8192 + f * 512);
      }
    }
    const u16* kb = kbuf + (t & 1) * 8192;
    // ---- QK-A: q-tile 0 only (2 interleaved dep chains, 16 MFMA) ----
    f32x4 s0[2] = {};
    f32x4 s1[2] = {};
    __builtin_amdgcn_s_setprio(1);
    #pragma unroll
    for (int kt = 0; kt < 8; kt++) {
      bf16x8 a0 = ldb8(kb + (size_t)kt * 512 + lane * 8);
      bf16x8 a1 = ldb8(kb + (size_t)(8 + kt) * 512 + lane * 8);
      s0[0] = MFMA(a0, qf[0][kt], s0[0]);
      s0[1] = MFMA(a1, qf[0][kt], s0[1]);
    }
    // ---- QK-B (q-tile 1) with sm0 interleaved one element per kt ----
    float pp0, pp1, pp2;
    #pragma unroll
    for (int kt = 0; kt < 8; kt++) {
      bf16x8 a0 = ldb8(kb + (size_t)kt * 512 + lane * 8);
      bf16x8 a1 = ldb8(kb + (size_t)(8 + kt) * 512 + lane * 8);
      s1[0] = MFMA(a0, qf[1][kt], s1[0]);
      s1[1] = MFMA(a1, qf[1][kt], s1[1]);
      // sm0 element (kt = n2*4 + r): p = 2^(s0*cexp)
      {
        const int n2 = kt >> 2, r = kt & 3;
        float p = EXP2(s0[n2][r] * cexp);
        lsum[0] += p;
        if (r == 0) pp0 = p;
        else if (r == 1) pp1 = p;
        else if (r == 2) pp2 = p;
        else {
          uint2 pk;
          pk.x = pkbf(pp0, pp1);
          pk.y = pkbf(pp2, p);
          *(uint2*)(pl + (lane & 15) * 40 + 16 * n2 + 4 * (lane >> 4)) = pk;
        }
      }
    }
    __builtin_amdgcn_s_setprio(0);
    // issue pa0 read NOW: same-wave LDS is in-order, so it queues behind the
    // P0 writes and its latency drains under sm1 below.
    bf16x8 pa0 = ldb8(pl + (lane & 15) * 40 + (lane >> 4) * 8);
    // ---- sm1: q-tile 1 softmax (8 elems), then pa1 read ----
    #pragma unroll
    for (int ntk = 0; ntk < 2; ntk++) {
      float p0 = EXP2(s1[ntk][0] * cexp);
      float p1 = EXP2(s1[ntk][1] * cexp);
      float p2 = EXP2(s1[ntk][2] * cexp);
      float p3 = EXP2(s1[ntk][3] * cexp);
      lsum[1] += (p0 + p1) + (p2 + p3);
      uint2 pk;
      pk.x = pkbf(p0, p1);
      pk.y = pkbf(p2, p3);
      *(uint2*)(pl + (16 + (lane & 15)) * 40 + 16 * ntk + 4 * (lane >> 4)) = pk;
    }
    bf16x8 pa1 = ldb8(pl + (16 + (lane & 15)) * 40 + (lane >> 4) * 8);
    asm volatile("s_waitcnt lgkmcnt(0)" ::: "memory");
    // ---- O^T += V^T P^T: A = V frag (m=d,k=key); feeds both q-tiles ----
    const u16* vb0 = vbuf + (t & 1) * 8192;
    __builtin_amdgcn_s_setprio(1);
    #pragma unroll
    for (int nt = 0; nt < 16; nt++) {
      bf16x8 vb = ldb8(vb0 + (size_t)nt * 512 + lane * 8);
      o[0][nt] = MFMA(vb, pa0, o[0][nt]);
      o[1][nt] = MFMA(vb, pa1, o[1][nt]);
    }
    __builtin_amdgcn_s_setprio(0);
  }
  // ---- epilogue: o is O^T [d][q]; transpose via kbuf, b64 writes ----
  u16* el = kbuf + w * 1152;             // per-wave [16 q][72]
  __syncthreads();
  #pragma unroll
  for (int qq = 0; qq < 2; qq++) {
    // final l reduction: sum partials across the 4 quads of this q
    float l = lsum[qq];
    l += __shfl_xor(l, 16);
    l += __shfl_xor(l, 32);
    float linv = 1.0f / l;
    #pragma unroll
    for (int g = 0; g < 4; g++) {
      if (qq || g) asm volatile("s_waitcnt lgkmcnt(0)" ::: "memory");
      #pragma unroll
      for (int t2 = 0; t2 < 4; t2++) {
        int nt = g * 4 + t2;
        uint2 pk;
        pk.x = pkbf(o[qq][nt][0] * linv, o[qq][nt][1] * linv);
        pk.y = pkbf(o[qq][nt][2] * linv, o[qq][nt][3] * linv);
        *(uint2*)(el + (lane & 15) * 72 + t2 * 16 + 4 * (lane >> 4)) = pk;
      }
      asm volatile("s_waitcnt lgkmcnt(0)" ::: "memory");
      #pragma unroll
      for (int rep = 0; rep < 2; rep++) {
        int ch = lane + rep * 64;          // 128 chunks: 16 q-rows x 8
        int row = ch >> 3, c8 = ch & 7;
        uint4 v = *(uint4*)(el + row * 72 + c8 * 8);
        *(uint4*)(Ob + (size_t)(q0 + qq * 16 + row) * 256 + g * 64 + c8 * 8) = v;
      }
    }
  }
}

// ---------------------------------------------------------------------------
// Fused (hc==8): x = LN1(seq + O @ Wo).  grid (128), 256 threads.
// Each wave computes 16 complete 256-wide rows -> LN inline.
// ---------------------------------------------------------------------------
__global__ __launch_bounds__(256) void accum_ln1_kernel(
    const u16* __restrict__ Oc, const u16* __restrict__ pWo,
    const u16* __restrict__ sbuf, const u16* __restrict__ vecs,
    u16* __restrict__ xout) {
  __shared__ u16 blds[64 * 512];
  int tid = threadIdx.x, lane = tid & 63, w = tid >> 6;
  int m0 = blockIdx.x * 64 + w * 16;
  int arow = m0 + (lane & 15);
  int bq = arow >> 11, lrow = arow & 2047;
  f32x4 acc[16] = {};
  for (int k0 = 0; k0 < 64; k0 += 4) {
    __syncthreads();
    #pragma unroll
    for (int i = 0; i < 16; i++) {
      int u = tid + i * 256;
      int fl = u >> 6, q = u & 63;
      int ktg = k0 + (fl >> 4), nt = fl & 15;
      ((uint4*)blds)[u] = ((const uint4*)pWo)[(size_t)(ktg * 16 + nt) * 64 + q];
    }
    __syncthreads();
    #pragma unroll
    for (int kl = 0; kl < 4; kl++) {
      int ktl = k0 + kl;
      int hl = ktl >> 3;
      int d0 = (ktl & 7) * 32 + (lane >> 4) * 8;
      bf16x8 a = ldb8(Oc + ((size_t)(bq * 8 + hl) * 2048 + lrow) * 256 + d0);
      const u16* bp = blds + (size_t)kl * 16 * 512 + (size_t)lane * 8;
      #pragma unroll
      for (int nt = 0; nt < 16; nt++) {
        bf16x8 b = ldb8(bp + nt * 512);
        acc[nt] = MFMA(a, b, acc[nt]);
      }
    }
  }
  int rbase = m0 + (lane >> 4) * 4;
  #pragma unroll
  for (int nt = 0; nt < 16; nt++) {
    int d = nt * 16 + (lane & 15);
    #pragma unroll
    for (int r = 0; r < 4; r++)
      acc[nt][r] += b2f(sbuf[(size_t)(rbase + r) * 256 + d]);
  }
  float mu[4], rs[4];
  #pragma unroll
  for (int r = 0; r < 4; r++) {
    float sm = 0.f;
    #pragma unroll
    for (int nt = 0; nt < 16; nt++) sm += acc[nt][r];
    sm += __shfl_xor(sm, 1); sm += __shfl_xor(sm, 2);
    sm += __shfl_xor(sm, 4); sm += __shfl_xor(sm, 8);
    mu[r] = sm * (1.0f / 256.0f);
    float v = 0.f;
    #pragma unroll
    for (int nt = 0; nt < 16; nt++) { float dd = acc[nt][r] - mu[r]; v += dd * dd; }
    v += __shfl_xor(v, 1); v += __shfl_xor(v, 2);
    v += __shfl_xor(v, 4); v += __shfl_xor(v, 8);
    rs[r] = rsqrtf(v * (1.0f / 256.0f) + 1e-5f);
  }
  #pragma unroll
  for (int nt = 0; nt < 16; nt++) {
    int d = nt * 16 + (lane & 15);
    float gg = b2f(vecs[d]), bb = b2f(vecs[256 + d]);
    #pragma unroll
    for (int r = 0; r < 4; r++)
      xout[(size_t)(rbase + r) * 256 + d] = f2b((acc[nt][r] - mu[r]) * rs[r] * gg + bb);
  }
}

// ---------------------------------------------------------------------------
// Fallback (hc<8): att_out(f32) += O_chunk @ Wo_chunk.  grid (128), 256 thr.
// ---------------------------------------------------------------------------
__global__ __launch_bounds__(256) void accum_kernel(
    const u16* __restrict__ Oc, const u16* __restrict__ pWo,
    float* __restrict__ att_out, int kt0, int hc) {
  __shared__ u16 blds[64 * 512];
  int tid = threadIdx.x, lane = tid & 63, w = tid >> 6;
  int m0 = blockIdx.x * 64 + w * 16;
  int arow = m0 + (lane & 15);
  int bq = arow >> 11, lrow = arow & 2047;
  int ktn = hc * 8;
  f32x4 acc[16] = {};
  for (int k0 = 0; k0 < ktn; k0 += 4) {
    __syncthreads();
    #pragma unroll
    for (int i = 0; i < 16; i++) {
      int u = tid + i * 256;
      int fl = u >> 6, q = u & 63;
      int ktg = kt0 + k0 + (fl >> 4), nt = fl & 15;
      ((uint4*)blds)[u] = ((const uint4*)pWo)[(size_t)(ktg * 16 + nt) * 64 + q];
    }
    __syncthreads();
    #pragma unroll
    for (int kl = 0; kl < 4; kl++) {
      int ktl = k0 + kl;
      int hl = ktl >> 3;
      int d0 = (ktl & 7) * 32 + (lane >> 4) * 8;
      bf16x8 a = ldb8(Oc + ((size_t)(bq * hc + hl) * 2048 + lrow) * 256 + d0);
      const u16* bp = blds + (size_t)kl * 16 * 512 + (size_t)lane * 8;
      #pragma unroll
      for (int nt = 0; nt < 16; nt++) {
        bf16x8 b = ldb8(bp + nt * 512);
        acc[nt] = MFMA(a, b, acc[nt]);
      }
    }
  }
  int rbase = m0 + (lane >> 4) * 4;
  #pragma unroll
  for (int nt = 0; nt < 16; nt++) {
    int d = nt * 16 + (lane & 15);
    #pragma unroll
    for (int r = 0; r < 4; r++)
      att_out[(size_t)(rbase + r) * 256 + d] += acc[nt][r];
  }
}

// ---------------------------------------------------------------------------
// x = LN1(seq + att_out).  grid (2048), 256 threads; fallback path only.
// ---------------------------------------------------------------------------
__global__ __launch_bounds__(256) void ln1_kernel(
    const float* __restrict__ att_out, const u16* __restrict__ sbuf,
    const u16* __restrict__ vecs, u16* __restrict__ xout) {
  int tid = threadIdx.x, lane = tid & 63, w = tid >> 6;
  int row = blockIdx.x * 4 + w;
  const float* ar = att_out + (size_t)row * 256;
  f32x4 a = *(const f32x4*)(ar + lane * 4);
  uint2 sv = *(const uint2*)(sbuf + (size_t)row * 256 + lane * 4);
  float y[4];
  y[0] = a[0] + b2f((u16)(sv.x & 0xFFFF));
  y[1] = a[1] + b2f((u16)(sv.x >> 16));
  y[2] = a[2] + b2f((u16)(sv.y & 0xFFFF));
  y[3] = a[3] + b2f((u16)(sv.y >> 16));
  float sm = y[0] + y[1] + y[2] + y[3];
  sm += __shfl_xor(sm, 1);  sm += __shfl_xor(sm, 2);  sm += __shfl_xor(sm, 4);
  sm += __shfl_xor(sm, 8);  sm += __shfl_xor(sm, 16); sm += __shfl_xor(sm, 32);
  float mu = sm * (1.0f / 256.0f);
  float v = 0.f;
  #pragma unroll
  for (int j = 0; j < 4; j++) { float d = y[j] - mu; v += d * d; }
  v += __shfl_xor(v, 1);  v += __shfl_xor(v, 2);  v += __shfl_xor(v, 4);
  v += __shfl_xor(v, 8);  v += __shfl_xor(v, 16); v += __shfl_xor(v, 32);
  float rs = rsqrtf(v * (1.0f / 256.0f) + 1e-5f);
  u16 o[4];
  #pragma unroll
  for (int j = 0; j < 4; j++) {
    int d = lane * 4 + j;
    o[j] = f2b((y[j] - mu) * rs * b2f(vecs[d]) + b2f(vecs[256 + d]));
  }
  uint2 ov; ov.x = (u32)o[0] | ((u32)o[1] << 16); ov.y = (u32)o[2] | ((u32)o[3] << 16);
  *(uint2*)(xout + (size_t)row * 256 + lane * 4) = ov;
}

// ---------------------------------------------------------------------------
// FFN + LN2.  out = LN2(x + relu(x@W1+b1)@W2 + b2).  grid(128), 256 thr.
// ---------------------------------------------------------------------------
__global__ __launch_bounds__(256) void ffn_ln2_kernel(
    const u16* __restrict__ x, const u16* __restrict__ pW1,
    const u16* __restrict__ pW2, const u16* __restrict__ vecs,
    const void* __restrict__ seq, void* __restrict__ out) {
  __shared__ u16 hbuf[4 * 16 * 136];
  int isf32 = detect_f32(seq);
  int tid = threadIdx.x, lane = tid & 63, w = tid >> 6;
  int m0 = blockIdx.x * 64 + w * 16;
  int arow = m0 + (lane & 15);
  u16* hb = hbuf + w * 16 * 136;
  f32x4 acc1[8] = {};
  #pragma unroll
  for (int kt = 0; kt < 8; kt++) {
    bf16x8 a = ldb8(x + (size_t)arow * 256 + kt * 32 + (lane >> 4) * 8);
    const u16* bp = pW1 + ((size_t)kt * 8 * 64 + lane) * 8;
    #pragma unroll
    for (int nt = 0; nt < 8; nt++) {
      bf16x8 b = ldb8(bp + nt * 512);
      acc1[nt] = MFMA(a, b, acc1[nt]);
    }
  }
  #pragma unroll
  for (int nt = 0; nt < 8; nt++) {
    int col = nt * 16 + (lane & 15);
    float bb = b2f(vecs[512 + col]);
    #pragma unroll
    for (int r = 0; r < 4; r++) {
      float h = fmaxf(acc1[nt][r] + bb, 0.f);
      hb[((lane >> 4) * 4 + r) * 136 + col] = f2b(h);
    }
  }
  __syncthreads();
  f32x4 acc2[16] = {};
  #pragma unroll
  for (int ks = 0; ks < 4; ks++) {
    bf16x8 a = ldb8(hb + (lane & 15) * 136 + ks * 32 + (lane >> 4) * 8);
    const u16* bp = pW2 + ((size_t)ks * 16 * 64 + lane) * 8;
    #pragma unroll
    for (int nt = 0; nt < 16; nt++) {
      bf16x8 b = ldb8(bp + nt * 512);
      acc2[nt] = MFMA(a, b, acc2[nt]);
    }
  }
  int rbase = m0 + (lane >> 4) * 4;
  #pragma unroll
  for (int nt = 0; nt < 16; nt++) {
    int d = nt * 16 + (lane & 15);
    float bb = b2f(vecs[768 + d]);
    #pragma unroll
    for (int r = 0; r < 4; r++)
      acc2[nt][r] += bb + b2f(x[(size_t)(rbase + r) * 256 + d]);
  }
  float mu[4], rs[4];
  #pragma unroll
  for (int r = 0; r < 4; r++) {
    float sm = 0.f;
    #pragma unroll
    for (int nt = 0; nt < 16; nt++) sm += acc2[nt][r];
    sm += __shfl_xor(sm, 1); sm += __shfl_xor(sm, 2);
    sm += __shfl_xor(sm, 4); sm += __shfl_xor(sm, 8);
    mu[r] = sm * (1.0f / 256.0f);
    float v = 0.f;
    #pragma unroll
    for (int nt = 0; nt < 16; nt++) { float dd = acc2[nt][r] - mu[r]; v += dd * dd; }
    v += __shfl_xor(v, 1); v += __shfl_xor(v, 2);
    v += __shfl_xor(v, 4); v += __shfl_xor(v, 8);
    rs[r] = rsqrtf(v * (1.0f / 256.0f) + 1e-5f);
  }
  #pragma unroll
  for (int nt = 0; nt < 16; nt++) {
    int d = nt * 16 + (lane & 15);
    float gg = b2f(vecs[1024 + d]), bb = b2f(vecs[1280 + d]);
    #pragma unroll
    for (int r = 0; r < 4; r++) {
      float val = (acc2[nt][r] - mu[r]) * rs[r] * gg + bb;
      size_t idx = (size_t)(rbase + r) * 256 + d;
      if (isf32) ((float*)out)[idx] = val;
      else       ((u16*)out)[idx]   = f2b(val);
    }
  }
}

// ---------------------------------------------------------------------------
__global__ __launch_bounds__(256) void sentinel_kernel(void* out, int n,
                                                       const void* seq) {
  int isf32 = detect_f32(seq);
  int i = blockIdx.x * 256 + threadIdx.x;
  if (i < n) {
    if (isf32) ((float*)out)[i] = 777.0f;
    else       ((u16*)out)[i]   = 0x4442;
  }
}

// ---------------------------------------------------------------------------
extern "C" void kernel_launch(void* const* d_in, const int* in_sizes, int n_in,
                              void* d_out, int out_size, void* d_ws, size_t ws_size,
                              hipStream_t stream) {
  (void)in_sizes; (void)n_in;
  const void* seq  = d_in[0];
  const void* Wq   = d_in[1];
  const void* Wk   = d_in[2];
  const void* Wv   = d_in[3];
  const void* Wo   = d_in[4];
  const void* g1   = d_in[5];
  const void* be1  = d_in[6];
  const void* W1   = d_in[7];
  const void* b1   = d_in[8];
  const void* W2   = d_in[9];
  const void* b2   = d_in[10];
  const void* g2   = d_in[11];
  const void* be2  = d_in[12];

  size_t o = 0;
  u16* ws = (u16*)d_ws;
  u16* pWq = ws + o; o += 524288;
  u16* pWk = ws + o; o += 524288;
  u16* pWv = ws + o; o += 524288;
  u16* pWo = ws + o; o += 524288;
  u16* pW1 = ws + o; o += 32768;
  u16* pW2 = ws + o; o += 32768;
  float* att = (float*)(ws + o); o += 4194304;   // 2M f32 (fallback path)
  u16* xb   = ws + o; o += 2097152;
  u16* sbuf = ws + o; o += 2097152;
  u16* vecs = ws + o; o += 2048;
  size_t fixed_elems = o;

  int hc = 0;
  for (int c = 8; c >= 1; c >>= 1) {
    size_t need = (fixed_elems + (size_t)4 * c * 2097152) * 2;
    if (need <= ws_size) { hc = c; break; }
  }
  if (hc == 0) {
    sentinel_kernel<<<dim3((out_size + 255) / 256), 256, 0, stream>>>(
        d_out, out_size, seq);
    return;
  }
  u16* Qc = ws + o; o += (size_t)hc * 2097152;
  u16* Kc = ws + o; o += (size_t)hc * 2097152;
  u16* Vc = ws + o; o += (size_t)hc * 2097152;   // V^T [B,hc,D,L]
  u16* Oc = ws + o;

  ingest_kernel<<<dim3(2054), 256, 0, stream>>>(seq, g1, be1, b1, b2, g2, be2,
                                                sbuf, vecs);
  pack_kernel<<<dim3(256, 6), 256, 0, stream>>>(Wq, Wk, Wv, Wo, W1, W2, seq,
                                                pWq, pWk, pWv, pWo, pW1, pW2);
  if (hc == 8) {
    // single-chunk fast path: fused accum+LN1, no f32 att buffer
    qkv_kernel<<<dim3(16, 64, 3), 256, 0, stream>>>(
        sbuf, pWq, pWk, pWv, Qc, Kc, Vc, 0, 8);
    attn_kernel<<<dim3(32 * 16), 256, 0, stream>>>(Qc, Kc, Vc, Oc, 32);
    accum_ln1_kernel<<<dim3(128), 256, 0, stream>>>(Oc, pWo, sbuf, vecs, xb);
  } else {
    hipMemsetAsync(att, 0, 2097152 * sizeof(float), stream);
    int nchunks = 8 / hc;
    for (int c = 0; c < nchunks; c++) {
      int nbh = 4 * hc;
      qkv_kernel<<<dim3(2 * hc, 64, 3), 256, 0, stream>>>(
          sbuf, pWq, pWk, pWv, Qc, Kc, Vc, c * hc * 16, hc);
      attn_kernel<<<dim3(nbh * 16), 256, 0, stream>>>(Qc, Kc, Vc, Oc, nbh);
      accum_kernel<<<dim3(128), 256, 0, stream>>>(Oc, pWo, att, c * hc * 8, hc);
    }
    ln1_kernel<<<dim3(2048), 256, 0, stream>>>(att, sbuf, vecs, xb);
  }
  ffn_ln2_kernel<<<dim3(128), 256, 0, stream>>>(xb, pW1, pW2, vecs, seq,
                                                (void*)d_out);
}

// Round 5
// 349.601 us; speedup vs baseline: 1.4169x; 1.4169x over previous
//
#include <hip/hip_runtime.h>

// ---------------------------------------------------------------------------
// TransformerEncoderLayer on MI355X (gfx950).  B=4 L=2048 D=256 H=8 FF=128.
// Input dtype (fp32 vs bf16) detected at runtime; compute bf16 MFMA, fp32 acc.
// Layouts: A[m=lane&15][k=8*(lane>>4)+j], B[k=8*(lane>>4)+j][n=lane&15],
//          C/D[row=(lane>>4)*4+r][col=lane&15]
// R3: V pre-transposed [B,h,D,L].  R8: 128 q/block, XCD swizzle.
// R12: transposed dataflow (S^T = K Q^T, O^T = V^T P^T), per-lane softmax.
// R13: STATIC-MAX softmax — p = 2^(s*cexp), no running max; accum+LN1 fused.
// R14: 4 waves x 32 q (2 q-tiles/wave); NEUTRAL -> LDS read BW not binding.
// R15: cross-barrier deferred-PV pipeline; REGRESSED (exposed issue chain).
// R16: bare v_exp_f32 + v_cvt_pk_bf16_f32 softmax: 198->177us, VALU 34->22%.
//      VALU cycles removed converted ~1:1 to wall -> softmax phase is
//      EXPOSED serial.
// R17: QK split + interleave; REGRESSED 177->332 via SCRATCH SPILL
//      (WRITE_SIZE +22MB): duplicated K-reads + extended live ranges broke
//      the 256-reg budget.  REVERTED.
// R18: R16 base + P redistribution IN REGISTERS via permlane32/16_swap
//      (T12): kills the plds write->lgkmcnt(0)->read serial roundtrip and
//      10 LDS ops/iter; zero new live state; plds deleted (LDS 75776->65536).
//      Mapping (verified): lane(q,Q) holds P[4Q+r+16ntk][q]; PV needs keys
//      8Q..8Q+7.  A0=pk(p0[0],p0[1]),A1=pk(p0[2],p0[3]),B0/B1 same for ntk=1.
//      ra=pl32swap(A0,B0); sa=pl16swap(ra0,ra1) -> w0=sa0, w2=sa1;
//      (A1,B1) -> w1,w3.  pa = {w0,w1,w2,w3}.
// ---------------------------------------------------------------------------

typedef unsigned short u16;
typedef unsigned int   u32;
typedef __bf16 bf16x8 __attribute__((ext_vector_type(8)));
typedef __bf16 bf16x2 __attribute__((ext_vector_type(2)));
typedef float  f32x4  __attribute__((ext_vector_type(4)));

#define MFMA(a, b, c) __builtin_amdgcn_mfma_f32_16x16x32_bf16(a, b, c, 0, 0, 0)

#if __has_builtin(__builtin_amdgcn_exp2f)
#define EXP2(x) __builtin_amdgcn_exp2f(x)
#else
#define EXP2(x) exp2f(x)
#endif

#if __has_builtin(__builtin_amdgcn_permlane16_swap) && \
    __has_builtin(__builtin_amdgcn_permlane32_swap)
#define HAS_PERMSWAP 1
#else
#define HAS_PERMSWAP 0
#endif

__device__ __forceinline__ float b2f(u16 h) {
  return __uint_as_float(((u32)h) << 16);
}
__device__ __forceinline__ u16 f2b(float f) {
  u32 u = __float_as_uint(f);
  u += 0x7FFFu + ((u >> 16) & 1u);   // round-to-nearest-even
  return (u16)(u >> 16);
}
// packed f32x2 -> bf16x2 (RTNE); gfx950 backend emits v_cvt_pk_bf16_f32
__device__ __forceinline__ u32 pkbf(float lo, float hi) {
  bf16x2 v;
  v[0] = (__bf16)lo;
  v[1] = (__bf16)hi;
  return __builtin_bit_cast(u32, v);
}
__device__ __forceinline__ bf16x8 ldb8(const u16* p) { return *(const bf16x8*)p; }

typedef const __attribute__((address_space(1))) u32* gas1_t;
typedef __attribute__((address_space(3))) u32* las3_t;
__device__ __forceinline__ void gload_lds16(const u16* g, u16* lds_base) {
  __builtin_amdgcn_global_load_lds((gas1_t)(const void*)g,
                                   (las3_t)(void*)lds_base, 16, 0, 0);
}

__device__ __forceinline__ int detect_f32(const void* seq) {
  const u32* s = (const u32*)seq;
  int cnt = 0;
  #pragma unroll
  for (int i = 0; i < 64; i++) {
    u32 e = (s[i] >> 7) & 0xFFu;
    cnt += (e >= 100u && e <= 140u) ? 1 : 0;
  }
  return cnt < 48;  // 1 => fp32
}

__device__ __forceinline__ u16 ldw(const void* W, size_t idx, int isf32) {
  return isf32 ? f2b(((const float*)W)[idx]) : ((const u16*)W)[idx];
}

#if HAS_PERMSWAP
// softmax for one q-tile: p = 2^(s*cexp); accumulate per-lane l; return the
// PV B-operand fragment entirely in registers via permlane swaps (T12).
__device__ __forceinline__ bf16x8 softmax_pa(f32x4 sn0, f32x4 sn1,
                                             float cexp, float& lsum) {
  float p00 = EXP2(sn0[0] * cexp), p01 = EXP2(sn0[1] * cexp);
  float p02 = EXP2(sn0[2] * cexp), p03 = EXP2(sn0[3] * cexp);
  float p10 = EXP2(sn1[0] * cexp), p11 = EXP2(sn1[1] * cexp);
  float p12 = EXP2(sn1[2] * cexp), p13 = EXP2(sn1[3] * cexp);
  lsum += ((p00 + p01) + (p02 + p03)) + ((p10 + p11) + (p12 + p13));
  u32 A0 = pkbf(p00, p01), A1 = pkbf(p02, p03);
  u32 B0 = pkbf(p10, p11), B1 = pkbf(p12, p13);
  auto ra = __builtin_amdgcn_permlane32_swap(A0, B0, false, false);
  auto rb = __builtin_amdgcn_permlane32_swap(A1, B1, false, false);
  auto sa = __builtin_amdgcn_permlane16_swap(ra[0], ra[1], false, false);
  auto sb = __builtin_amdgcn_permlane16_swap(rb[0], rb[1], false, false);
  uint4 wv;
  wv.x = sa[0];  // keys 8Q+0,1
  wv.y = sb[0];  // keys 8Q+2,3
  wv.z = sa[1];  // keys 8Q+4,5
  wv.w = sb[1];  // keys 8Q+6,7
  return __builtin_bit_cast(bf16x8, wv);
}
#endif

// ---------------------------------------------------------------------------
// Ingest: canonicalize seq (2M elems) + 6 small vectors to bf16 in ws.
// ---------------------------------------------------------------------------
__global__ __launch_bounds__(256) void ingest_kernel(
    const void* __restrict__ seq, const void* __restrict__ g1,
    const void* __restrict__ be1, const void* __restrict__ b1,
    const void* __restrict__ b2v, const void* __restrict__ g2,
    const void* __restrict__ be2, u16* __restrict__ sbuf,
    u16* __restrict__ vecs) {
  int isf32 = detect_f32(seq);
  int bx = blockIdx.x, tid = threadIdx.x;
  if (bx < 2048) {
    size_t i = (size_t)bx * 1024 + tid * 4;
    if (isf32) {
      const float* sp = (const float*)seq;
      u16 o0 = f2b(sp[i]), o1 = f2b(sp[i + 1]), o2 = f2b(sp[i + 2]), o3 = f2b(sp[i + 3]);
      uint2 ov; ov.x = (u32)o0 | ((u32)o1 << 16); ov.y = (u32)o2 | ((u32)o3 << 16);
      *(uint2*)(sbuf + i) = ov;
    } else {
      *(uint2*)(sbuf + i) = ((const uint2*)seq)[i >> 2];
    }
  } else {
    int t = bx - 2048;
    const void* src; int n;
    switch (t) {
      case 0: src = g1;  n = 256; break;
      case 1: src = be1; n = 256; break;
      case 2: src = b1;  n = 128; break;
      case 3: src = b2v; n = 256; break;
      case 4: src = g2;  n = 256; break;
      default: src = be2; n = 256; break;
    }
    if (tid < n) vecs[t * 256 + tid] = ldw(src, tid, isf32);
  }
}

// ---------------------------------------------------------------------------
// Pack weights into B-fragment-linear layout.  grid (256, 6), 256 thr.
// ---------------------------------------------------------------------------
__global__ __launch_bounds__(256) void pack_kernel(
    const void* __restrict__ Wq, const void* __restrict__ Wk,
    const void* __restrict__ Wv, const void* __restrict__ Wo,
    const void* __restrict__ W1, const void* __restrict__ W2,
    const void* __restrict__ seq,
    u16* __restrict__ pWq, u16* __restrict__ pWk, u16* __restrict__ pWv,
    u16* __restrict__ pWo, u16* __restrict__ pW1, u16* __restrict__ pW2) {
  int isf32 = detect_f32(seq);
  const void* W; u16* P; int K, N;
  switch (blockIdx.y) {
    case 0: W = Wq; P = pWq; K = 256;  N = 2048; break;
    case 1: W = Wk; P = pWk; K = 256;  N = 2048; break;
    case 2: W = Wv; P = pWv; K = 256;  N = 2048; break;
    case 3: W = Wo; P = pWo; K = 2048; N = 256;  break;
    case 4: W = W1; P = pW1; K = 256;  N = 128;  break;
    default: W = W2; P = pW2; K = 128; N = 256;  break;
  }
  int t = blockIdx.x * 256 + threadIdx.x;
  int total = (K >> 5) * (N >> 4) * 64;
  if (t >= total) return;
  int lane = t & 63, f = t >> 6;
  int NT = N >> 4;
  int kt = f / NT, nt = f - kt * NT;
  int row0 = kt * 32 + ((lane >> 4) << 3);
  int col = nt * 16 + (lane & 15);
  u16 e[8];
  #pragma unroll
  for (int j = 0; j < 8; j++) e[j] = ldw(W, (size_t)(row0 + j) * N + col, isf32);
  uint4 u;
  u.x = (u32)e[0] | ((u32)e[1] << 16);
  u.y = (u32)e[2] | ((u32)e[3] << 16);
  u.z = (u32)e[4] | ((u32)e[5] << 16);
  u.w = (u32)e[6] | ((u32)e[7] << 16);
  *(uint4*)(P + ((size_t)f * 64 + lane) * 8) = u;
}

// ---------------------------------------------------------------------------
// QKV projection for one h-chunk: X(8192x256) @ W(256, hc*256).
// Q,K -> [B,hc,L,D]; V -> transposed [B,hc,D,L].  Coalesced 16B stores via
// LDS transpose.  grid (2*hc, 64, 3), 256 threads.
// ---------------------------------------------------------------------------
__global__ __launch_bounds__(256) void qkv_kernel(
    const u16* __restrict__ X,
    const u16* __restrict__ pWq, const u16* __restrict__ pWk,
    const u16* __restrict__ pWv,
    u16* __restrict__ Qo, u16* __restrict__ Ko, u16* __restrict__ Vo,
    int ntbase, int hc) {
  __shared__ u16 blds[64 * 512];
  const u16* Pw = (blockIdx.z == 0) ? pWq : ((blockIdx.z == 1) ? pWk : pWv);
  u16* Out = (blockIdx.z == 0) ? Qo : ((blockIdx.z == 1) ? Ko : Vo);
  int tid = threadIdx.x, lane = tid & 63, w = tid >> 6;
  int nt0 = ntbase + blockIdx.x * 8;
  #pragma unroll
  for (int i = 0; i < 16; i++) {
    int u = tid + i * 256;
    int fl = u >> 6, q = u & 63;
    int kt = fl >> 3, nt = fl & 7;
    ((uint4*)blds)[u] = ((const uint4*)Pw)[(size_t)(kt * 128 + nt0 + nt) * 64 + q];
  }
  __syncthreads();
  int m0 = blockIdx.y * 128 + w * 32;
  f32x4 acc[2][8] = {};
  #pragma unroll
  for (int kt = 0; kt < 8; kt++) {
    bf16x8 a0 = ldb8(X + (size_t)(m0 + (lane & 15)) * 256 + kt * 32 + (lane >> 4) * 8);
    bf16x8 a1 = ldb8(X + (size_t)(m0 + 16 + (lane & 15)) * 256 + kt * 32 + (lane >> 4) * 8);
    const u16* bp = blds + (size_t)kt * 8 * 512 + (size_t)lane * 8;
    #pragma unroll
    for (int nt = 0; nt < 8; nt++) {
      bf16x8 b = ldb8(bp + nt * 512);
      acc[0][nt] = MFMA(a0, b, acc[0][nt]);
      acc[1][nt] = MFMA(a1, b, acc[1][nt]);
    }
  }
  int isv = (blockIdx.z == 2);
  int hl = blockIdx.x >> 1;
  int dd0 = (blockIdx.x & 1) * 128;
  int m0b = blockIdx.y * 128;
  int bi = m0b >> 11, l0 = m0b & 2047;
  __syncthreads();
  if (!isv) {
    #pragma unroll
    for (int mt = 0; mt < 2; mt++)
      #pragma unroll
      for (int nt = 0; nt < 8; nt++)
        #pragma unroll
        for (int r = 0; r < 4; r++)
          blds[(w * 32 + mt * 16 + (lane >> 4) * 4 + r) * 136 + nt * 16 + (lane & 15)] =
              f2b(acc[mt][nt][r]);
    __syncthreads();
    #pragma unroll
    for (int i = 0; i < 8; i++) {
      int c = tid + i * 256;
      int mloc = c >> 4, q = c & 15;
      uint4 v = *(uint4*)(blds + mloc * 136 + q * 8);
      *(uint4*)(Out + ((size_t)(bi * hc + hl) * 2048 + l0 + mloc) * 256 + dd0 + q * 8) = v;
    }
  } else {
    #pragma unroll
    for (int mt = 0; mt < 2; mt++)
      #pragma unroll
      for (int nt = 0; nt < 8; nt++)
        #pragma unroll
        for (int r = 0; r < 4; r++)
          blds[(nt * 16 + (lane & 15)) * 136 + w * 32 + mt * 16 + (lane >> 4) * 4 + r] =
              f2b(acc[mt][nt][r]);
    __syncthreads();
    #pragma unroll
    for (int i = 0; i < 8; i++) {
      int c = tid + i * 256;
      int nloc = c >> 4, q = c & 15;
      uint4 v = *(uint4*)(blds + nloc * 136 + q * 8);
      *(uint4*)(Out + ((size_t)(bi * hc + hl) * 256 + dd0 + nloc) * 2048 + l0 + q * 8) = v;
    }
  }
}

// ---------------------------------------------------------------------------
// Flash attention, transposed dataflow, STATIC-MAX softmax.
// R14 base: 4 waves x 32 q (2 q-tiles/wave); K+V double-buffered, ONE
// barrier/iter.  R16: cheap softmax (v_exp_f32 + cvt_pk).
// R18: P redistribution in registers via permlane32/16_swap — plds deleted,
// no lgkmcnt drain between softmax and PV.  grid (nbh*16), 256 thr,
// 128 q/block; LDS 65536 B -> 2 blocks/CU.
// ---------------------------------------------------------------------------
__global__ __launch_bounds__(256, 2) void attn_kernel(
    const u16* __restrict__ Q, const u16* __restrict__ K,
    const u16* __restrict__ Vt, u16* __restrict__ O, int nbh) {
  __shared__ u16 kbuf[2 * 8192];   // 2 bufs x 16 frags x 512 u16 (frag-linear)
  __shared__ u16 vbuf[2 * 8192];
#if !HAS_PERMSWAP
  __shared__ u16 plds[4 * 1280];   // per-wave P [32 q][40] (fallback path)
#endif
  int tid = threadIdx.x, lane = tid & 63, w = tid >> 6;
  int bi2 = blockIdx.x;
  int bh, qt;
  if (nbh >= 8) {
    int G = nbh >> 3;
    bh = (bi2 & 7) * G + (bi2 >> 3) % G;
    qt = bi2 / (8 * G);
  } else {
    bh = bi2 % nbh; qt = bi2 / nbh;
  }
  const u16* Qb  = Q  + (size_t)bh * 2048 * 256;
  const u16* Kb  = K  + (size_t)bh * 2048 * 256;
  const u16* Vtb = Vt + (size_t)bh * 256 * 2048;
  u16* Ob = O + (size_t)bh * 2048 * 256;
  int q0 = qt * 128 + w * 32;
  bf16x8 qf[2][8];   // B-operand per q-tile: n=q=lane&15, k=d
  #pragma unroll
  for (int qq = 0; qq < 2; qq++)
    #pragma unroll
    for (int kt = 0; kt < 8; kt++)
      qf[qq][kt] = ldb8(Qb + (size_t)(q0 + qq * 16 + (lane & 15)) * 256 +
                        kt * 32 + (lane >> 4) * 8);
  f32x4 o[2][16] = {};             // O^T per q-tile: [d=16nt+4quad+r][q=lane&15]
  float lsum[2] = {0.f, 0.f};      // per-lane partial sum of p, per q-tile
  const float cexp = 0.0625f * 1.44269504088896f;  // scale * log2(e)
#if !HAS_PERMSWAP
  u16* pl = plds + (size_t)w * 1280;
#endif

  // pre-loop: issue K(0), V(0) into buffer 0 (4 waves x 4 frags = 16)
  #pragma unroll
  for (int j = 0; j < 4; j++) {
    int f = w * 4 + j;
    gload_lds16(Kb + (size_t)((f >> 3) * 16 + (lane & 15)) * 256 +
                    (f & 7) * 32 + (lane >> 4) * 8,
                kbuf + f * 512);
    gload_lds16(Vtb + (size_t)(f * 16 + (lane & 15)) * 2048 + (lane >> 4) * 8,
                vbuf + f * 512);
  }

  for (int t = 0; t < 64; t++) {
    int s0i = t * 32;
    // ONE barrier: K(t),V(t) (issued a full iteration ago) landed.
    asm volatile("s_waitcnt vmcnt(0)\ns_barrier" ::: "memory");
    if (t < 63) {
      int nb = (t + 1) & 1;
      #pragma unroll
      for (int j = 0; j < 4; j++) {
        int f = w * 4 + j;
        gload_lds16(Kb + (size_t)(s0i + 32 + (f >> 3) * 16 + (lane & 15)) * 256 +
                        (f & 7) * 32 + (lane >> 4) * 8,
                    kbuf + nb * 8192 + f * 512);
        gload_lds16(Vtb + (size_t)(f * 16 + (lane & 15)) * 2048 + s0i + 32 +
                        (lane >> 4) * 8,
                    vbuf + nb * 8192 + f * 512);
      }
    }
    // S^T = K Q^T: A = K frag (m=key,k=d), B = qf (k=d,n=q).
    // Each K frag read feeds BOTH q-tiles' MFMAs.
    const u16* kb = kbuf + (t & 1) * 8192;
    f32x4 s[2][2] = {};
    __builtin_amdgcn_s_setprio(1);
    #pragma unroll
    for (int ntk = 0; ntk < 2; ntk++)
      #pragma unroll
      for (int kt = 0; kt < 8; kt++) {
        bf16x8 a = ldb8(kb + (size_t)(ntk * 8 + kt) * 512 + lane * 8);
        s[0][ntk] = MFMA(a, qf[0][kt], s[0][ntk]);
        s[1][ntk] = MFMA(a, qf[1][kt], s[1][ntk]);
      }
    __builtin_amdgcn_s_setprio(0);
#if HAS_PERMSWAP
    // static-max softmax + in-register P redistribution (no LDS roundtrip)
    bf16x8 pa0 = softmax_pa(s[0][0], s[0][1], cexp, lsum[0]);
    bf16x8 pa1 = softmax_pa(s[1][0], s[1][1], cexp, lsum[1]);
#else
    // fallback: softmax via plds roundtrip (R16 path)
    #pragma unroll
    for (int qq = 0; qq < 2; qq++)
      #pragma unroll
      for (int ntk = 0; ntk < 2; ntk++) {
        float p0 = EXP2(s[qq][ntk][0] * cexp);
        float p1 = EXP2(s[qq][ntk][1] * cexp);
        float p2 = EXP2(s[qq][ntk][2] * cexp);
        float p3 = EXP2(s[qq][ntk][3] * cexp);
        lsum[qq] += (p0 + p1) + (p2 + p3);
        uint2 pk;
        pk.x = pkbf(p0, p1);
        pk.y = pkbf(p2, p3);
        *(uint2*)(pl + (qq * 16 + (lane & 15)) * 40 + 16 * ntk + 4 * (lane >> 4)) = pk;
      }
    asm volatile("s_waitcnt lgkmcnt(0)" ::: "memory");
    bf16x8 pa0 = ldb8(pl + (lane & 15) * 40 + (lane >> 4) * 8);
    bf16x8 pa1 = ldb8(pl + (16 + (lane & 15)) * 40 + (lane >> 4) * 8);
    asm volatile("s_waitcnt lgkmcnt(0)" ::: "memory");
#endif
    // ---- O^T += V^T P^T: A = V frag (m=d,k=key); feeds both q-tiles ----
    const u16* vb0 = vbuf + (t & 1) * 8192;
    __builtin_amdgcn_s_setprio(1);
    #pragma unroll
    for (int nt = 0; nt < 16; nt++) {
      bf16x8 vb = ldb8(vb0 + (size_t)nt * 512 + lane * 8);
      o[0][nt] = MFMA(vb, pa0, o[0][nt]);
      o[1][nt] = MFMA(vb, pa1, o[1][nt]);
    }
    __builtin_amdgcn_s_setprio(0);
  }
  // ---- epilogue: o is O^T [d][q]; transpose via kbuf, b64 writes ----
  u16* el = kbuf + w * 1152;             // per-wave [16 q][72]
  __syncthreads();
  #pragma unroll
  for (int qq = 0; qq < 2; qq++) {
    // final l reduction: sum partials across the 4 quads of this q
    float l = lsum[qq];
    l += __shfl_xor(l, 16);
    l += __shfl_xor(l, 32);
    float linv = 1.0f / l;
    #pragma unroll
    for (int g = 0; g < 4; g++) {
      if (qq || g) asm volatile("s_waitcnt lgkmcnt(0)" ::: "memory");
      #pragma unroll
      for (int t2 = 0; t2 < 4; t2++) {
        int nt = g * 4 + t2;
        uint2 pk;
        pk.x = pkbf(o[qq][nt][0] * linv, o[qq][nt][1] * linv);
        pk.y = pkbf(o[qq][nt][2] * linv, o[qq][nt][3] * linv);
        *(uint2*)(el + (lane & 15) * 72 + t2 * 16 + 4 * (lane >> 4)) = pk;
      }
      asm volatile("s_waitcnt lgkmcnt(0)" ::: "memory");
      #pragma unroll
      for (int rep = 0; rep < 2; rep++) {
        int ch = lane + rep * 64;          // 128 chunks: 16 q-rows x 8
        int row = ch >> 3, c8 = ch & 7;
        uint4 v = *(uint4*)(el + row * 72 + c8 * 8);
        *(uint4*)(Ob + (size_t)(q0 + qq * 16 + row) * 256 + g * 64 + c8 * 8) = v;
      }
    }
  }
}

// ---------------------------------------------------------------------------
// Fused (hc==8): x = LN1(seq + O @ Wo).  grid (128), 256 threads.
// Each wave computes 16 complete 256-wide rows -> LN inline.
// ---------------------------------------------------------------------------
__global__ __launch_bounds__(256) void accum_ln1_kernel(
    const u16* __restrict__ Oc, const u16* __restrict__ pWo,
    const u16* __restrict__ sbuf, const u16* __restrict__ vecs,
    u16* __restrict__ xout) {
  __shared__ u16 blds[64 * 512];
  int tid = threadIdx.x, lane = tid & 63, w = tid >> 6;
  int m0 = blockIdx.x * 64 + w * 16;
  int arow = m0 + (lane & 15);
  int bq = arow >> 11, lrow = arow & 2047;
  f32x4 acc[16] = {};
  for (int k0 = 0; k0 < 64; k0 += 4) {
    __syncthreads();
    #pragma unroll
    for (int i = 0; i < 16; i++) {
      int u = tid + i * 256;
      int fl = u >> 6, q = u & 63;
      int ktg = k0 + (fl >> 4), nt = fl & 15;
      ((uint4*)blds)[u] = ((const uint4*)pWo)[(size_t)(ktg * 16 + nt) * 64 + q];
    }
    __syncthreads();
    #pragma unroll
    for (int kl = 0; kl < 4; kl++) {
      int ktl = k0 + kl;
      int hl = ktl >> 3;
      int d0 = (ktl & 7) * 32 + (lane >> 4) * 8;
      bf16x8 a = ldb8(Oc + ((size_t)(bq * 8 + hl) * 2048 + lrow) * 256 + d0);
      const u16* bp = blds + (size_t)kl * 16 * 512 + (size_t)lane * 8;
      #pragma unroll
      for (int nt = 0; nt < 16; nt++) {
        bf16x8 b = ldb8(bp + nt * 512);
        acc[nt] = MFMA(a, b, acc[nt]);
      }
    }
  }
  int rbase = m0 + (lane >> 4) * 4;
  #pragma unroll
  for (int nt = 0; nt < 16; nt++) {
    int d = nt * 16 + (lane & 15);
    #pragma unroll
    for (int r = 0; r < 4; r++)
      acc[nt][r] += b2f(sbuf[(size_t)(rbase + r) * 256 + d]);
  }
  float mu[4], rs[4];
  #pragma unroll
  for (int r = 0; r < 4; r++) {
    float sm = 0.f;
    #pragma unroll
    for (int nt = 0; nt < 16; nt++) sm += acc[nt][r];
    sm += __shfl_xor(sm, 1); sm += __shfl_xor(sm, 2);
    sm += __shfl_xor(sm, 4); sm += __shfl_xor(sm, 8);
    mu[r] = sm * (1.0f / 256.0f);
    float v = 0.f;
    #pragma unroll
    for (int nt = 0; nt < 16; nt++) { float dd = acc[nt][r] - mu[r]; v += dd * dd; }
    v += __shfl_xor(v, 1); v += __shfl_xor(v, 2);
    v += __shfl_xor(v, 4); v += __shfl_xor(v, 8);
    rs[r] = rsqrtf(v * (1.0f / 256.0f) + 1e-5f);
  }
  #pragma unroll
  for (int nt = 0; nt < 16; nt++) {
    int d = nt * 16 + (lane & 15);
    float gg = b2f(vecs[d]), bb = b2f(vecs[256 + d]);
    #pragma unroll
    for (int r = 0; r < 4; r++)
      xout[(size_t)(rbase + r) * 256 + d] = f2b((acc[nt][r] - mu[r]) * rs[r] * gg + bb);
  }
}

// ---------------------------------------------------------------------------
// Fallback (hc<8): att_out(f32) += O_chunk @ Wo_chunk.  grid (128), 256 thr.
// ---------------------------------------------------------------------------
__global__ __launch_bounds__(256) void accum_kernel(
    const u16* __restrict__ Oc, const u16* __restrict__ pWo,
    float* __restrict__ att_out, int kt0, int hc) {
  __shared__ u16 blds[64 * 512];
  int tid = threadIdx.x, lane = tid & 63, w = tid >> 6;
  int m0 = blockIdx.x * 64 + w * 16;
  int arow = m0 + (lane & 15);
  int bq = arow >> 11, lrow = arow & 2047;
  int ktn = hc * 8;
  f32x4 acc[16] = {};
  for (int k0 = 0; k0 < ktn; k0 += 4) {
    __syncthreads();
    #pragma unroll
    for (int i = 0; i < 16; i++) {
      int u = tid + i * 256;
      int fl = u >> 6, q = u & 63;
      int ktg = kt0 + k0 + (fl >> 4), nt = fl & 15;
      ((uint4*)blds)[u] = ((const uint4*)pWo)[(size_t)(ktg * 16 + nt) * 64 + q];
    }
    __syncthreads();
    #pragma unroll
    for (int kl = 0; kl < 4; kl++) {
      int ktl = k0 + kl;
      int hl = ktl >> 3;
      int d0 = (ktl & 7) * 32 + (lane >> 4) * 8;
      bf16x8 a = ldb8(Oc + ((size_t)(bq * hc + hl) * 2048 + lrow) * 256 + d0);
      const u16* bp = blds + (size_t)kl * 16 * 512 + (size_t)lane * 8;
      #pragma unroll
      for (int nt = 0; nt < 16; nt++) {
        bf16x8 b = ldb8(bp + nt * 512);
        acc[nt] = MFMA(a, b, acc[nt]);
      }
    }
  }
  int rbase = m0 + (lane >> 4) * 4;
  #pragma unroll
  for (int nt = 0; nt < 16; nt++) {
    int d = nt * 16 + (lane & 15);
    #pragma unroll
    for (int r = 0; r < 4; r++)
      att_out[(size_t)(rbase + r) * 256 + d] += acc[nt][r];
  }
}

// ---------------------------------------------------------------------------
// x = LN1(seq + att_out).  grid (2048), 256 threads; fallback path only.
// ---------------------------------------------------------------------------
__global__ __launch_bounds__(256) void ln1_kernel(
    const float* __restrict__ att_out, const u16* __restrict__ sbuf,
    const u16* __restrict__ vecs, u16* __restrict__ xout) {
  int tid = threadIdx.x, lane = tid & 63, w = tid >> 6;
  int row = blockIdx.x * 4 + w;
  const float* ar = att_out + (size_t)row * 256;
  f32x4 a = *(const f32x4*)(ar + lane * 4);
  uint2 sv = *(const uint2*)(sbuf + (size_t)row * 256 + lane * 4);
  float y[4];
  y[0] = a[0] + b2f((u16)(sv.x & 0xFFFF));
  y[1] = a[1] + b2f((u16)(sv.x >> 16));
  y[2] = a[2] + b2f((u16)(sv.y & 0xFFFF));
  y[3] = a[3] + b2f((u16)(sv.y >> 16));
  float sm = y[0] + y[1] + y[2] + y[3];
  sm += __shfl_xor(sm, 1);  sm += __shfl_xor(sm, 2);  sm += __shfl_xor(sm, 4);
  sm += __shfl_xor(sm, 8);  sm += __shfl_xor(sm, 16); sm += __shfl_xor(sm, 32);
  float mu = sm * (1.0f / 256.0f);
  float v = 0.f;
  #pragma unroll
  for (int j = 0; j < 4; j++) { float d = y[j] - mu; v += d * d; }
  v += __shfl_xor(v, 1);  v += __shfl_xor(v, 2);  v += __shfl_xor(v, 4);
  v += __shfl_xor(v, 8);  v += __shfl_xor(v, 16); v += __shfl_xor(v, 32);
  float rs = rsqrtf(v * (1.0f / 256.0f) + 1e-5f);
  u16 o[4];
  #pragma unroll
  for (int j = 0; j < 4; j++) {
    int d = lane * 4 + j;
    o[j] = f2b((y[j] - mu) * rs * b2f(vecs[d]) + b2f(vecs[256 + d]));
  }
  uint2 ov; ov.x = (u32)o[0] | ((u32)o[1] << 16); ov.y = (u32)o[2] | ((u32)o[3] << 16);
  *(uint2*)(xout + (size_t)row * 256 + lane * 4) = ov;
}

// ---------------------------------------------------------------------------
// FFN + LN2.  out = LN2(x + relu(x@W1+b1)@W2 + b2).  grid(128), 256 thr.
// ---------------------------------------------------------------------------
__global__ __launch_bounds__(256) void ffn_ln2_kernel(
    const u16* __restrict__ x, const u16* __restrict__ pW1,
    const u16* __restrict__ pW2, const u16* __restrict__ vecs,
    const void* __restrict__ seq, void* __restrict__ out) {
  __shared__ u16 hbuf[4 * 16 * 136];
  int isf32 = detect_f32(seq);
  int tid = threadIdx.x, lane = tid & 63, w = tid >> 6;
  int m0 = blockIdx.x * 64 + w * 16;
  int arow = m0 + (lane & 15);
  u16* hb = hbuf + w * 16 * 136;
  f32x4 acc1[8] = {};
  #pragma unroll
  for (int kt = 0; kt < 8; kt++) {
    bf16x8 a = ldb8(x + (size_t)arow * 256 + kt * 32 + (lane >> 4) * 8);
    const u16* bp = pW1 + ((size_t)kt * 8 * 64 + lane) * 8;
    #pragma unroll
    for (int nt = 0; nt < 8; nt++) {
      bf16x8 b = ldb8(bp + nt * 512);
      acc1[nt] = MFMA(a, b, acc1[nt]);
    }
  }
  #pragma unroll
  for (int nt = 0; nt < 8; nt++) {
    int col = nt * 16 + (lane & 15);
    float bb = b2f(vecs[512 + col]);
    #pragma unroll
    for (int r = 0; r < 4; r++) {
      float h = fmaxf(acc1[nt][r] + bb, 0.f);
      hb[((lane >> 4) * 4 + r) * 136 + col] = f2b(h);
    }
  }
  __syncthreads();
  f32x4 acc2[16] = {};
  #pragma unroll
  for (int ks = 0; ks < 4; ks++) {
    bf16x8 a = ldb8(hb + (lane & 15) * 136 + ks * 32 + (lane >> 4) * 8);
    const u16* bp = pW2 + ((size_t)ks * 16 * 64 + lane) * 8;
    #pragma unroll
    for (int nt = 0; nt < 16; nt++) {
      bf16x8 b = ldb8(bp + nt * 512);
      acc2[nt] = MFMA(a, b, acc2[nt]);
    }
  }
  int rbase = m0 + (lane >> 4) * 4;
  #pragma unroll
  for (int nt = 0; nt < 16; nt++) {
    int d = nt * 16 + (lane & 15);
    float bb = b2f(vecs[768 + d]);
    #pragma unroll
    for (int r = 0; r < 4; r++)
      acc2[nt][r] += bb + b2f(x[(size_t)(rbase + r) * 256 + d]);
  }
  float mu[4], rs[4];
  #pragma unroll
  for (int r = 0; r < 4; r++) {
    float sm = 0.f;
    #pragma unroll
    for (int nt = 0; nt < 16; nt++) sm += acc2[nt][r];
    sm += __shfl_xor(sm, 1); sm += __shfl_xor(sm, 2);
    sm += __shfl_xor(sm, 4); sm += __shfl_xor(sm, 8);
    mu[r] = sm * (1.0f / 256.0f);
    float v = 0.f;
    #pragma unroll
    for (int nt = 0; nt < 16; nt++) { float dd = acc2[nt][r] - mu[r]; v += dd * dd; }
    v += __shfl_xor(v, 1); v += __shfl_xor(v, 2);
    v += __shfl_xor(v, 4); v += __shfl_xor(v, 8);
    rs[r] = rsqrtf(v * (1.0f / 256.0f) + 1e-5f);
  }
  #pragma unroll
  for (int nt = 0; nt < 16; nt++) {
    int d = nt * 16 + (lane & 15);
    float gg = b2f(vecs[1024 + d]), bb = b2f(vecs[1280 + d]);
    #pragma unroll
    for (int r = 0; r < 4; r++) {
      float val = (acc2[nt][r] - mu[r]) * rs[r] * gg + bb;
      size_t idx = (size_t)(rbase + r) * 256 + d;
      if (isf32) ((float*)out)[idx] = val;
      else       ((u16*)out)[idx]   = f2b(val);
    }
  }
}

// ---------------------------------------------------------------------------
__global__ __launch_bounds__(256) void sentinel_kernel(void* out, int n,
                                                       const void* seq) {
  int isf32 = detect_f32(seq);
  int i = blockIdx.x * 256 + threadIdx.x;
  if (i < n) {
    if (isf32) ((float*)out)[i] = 777.0f;
    else       ((u16*)out)[i]   = 0x4442;
  }
}

// ---------------------------------------------------------------------------
extern "C" void kernel_launch(void* const* d_in, const int* in_sizes, int n_in,
                              void* d_out, int out_size, void* d_ws, size_t ws_size,
                              hipStream_t stream) {
  (void)in_sizes; (void)n_in;
  const void* seq  = d_in[0];
  const void* Wq   = d_in[1];
  const void* Wk   = d_in[2];
  const void* Wv   = d_in[3];
  const void* Wo   = d_in[4];
  const void* g1   = d_in[5];
  const void* be1  = d_in[6];
  const void* W1   = d_in[7];
  const void* b1   = d_in[8];
  const void* W2   = d_in[9];
  const void* b2   = d_in[10];
  const void* g2   = d_in[11];
  const void* be2  = d_in[12];

  size_t o = 0;
  u16* ws = (u16*)d_ws;
  u16* pWq = ws + o; o += 524288;
  u16* pWk = ws + o; o += 524288;
  u16* pWv = ws + o; o += 524288;
  u16* pWo = ws + o; o += 524288;
  u16* pW1 = ws + o; o += 32768;
  u16* pW2 = ws + o; o += 32768;
  float* att = (float*)(ws + o); o += 4194304;   // 2M f32 (fallback path)
  u16* xb   = ws + o; o += 2097152;
  u16* sbuf = ws + o; o += 2097152;
  u16* vecs = ws + o; o += 2048;
  size_t fixed_elems = o;

  int hc = 0;
  for (int c = 8; c >= 1; c >>= 1) {
    size_t need = (fixed_elems + (size_t)4 * c * 2097152) * 2;
    if (need <= ws_size) { hc = c; break; }
  }
  if (hc == 0) {
    sentinel_kernel<<<dim3((out_size + 255) / 256), 256, 0, stream>>>(
        d_out, out_size, seq);
    return;
  }
  u16* Qc = ws + o; o += (size_t)hc * 2097152;
  u16* Kc = ws + o; o += (size_t)hc * 2097152;
  u16* Vc = ws + o; o += (size_t)hc * 2097152;   // V^T [B,hc,D,L]
  u16* Oc = ws + o;

  ingest_kernel<<<dim3(2054), 256, 0, stream>>>(seq, g1, be1, b1, b2, g2, be2,
                                                sbuf, vecs);
  pack_kernel<<<dim3(256, 6), 256, 0, stream>>>(Wq, Wk, Wv, Wo, W1, W2, seq,
                                                pWq, pWk, pWv, pWo, pW1, pW2);
  if (hc == 8) {
    // single-chunk fast path: fused accum+LN1, no f32 att buffer
    qkv_kernel<<<dim3(16, 64, 3), 256, 0, stream>>>(
        sbuf, pWq, pWk, pWv, Qc, Kc, Vc, 0, 8);
    attn_kernel<<<dim3(32 * 16), 256, 0, stream>>>(Qc, Kc, Vc, Oc, 32);
    accum_ln1_kernel<<<dim3(128), 256, 0, stream>>>(Oc, pWo, sbuf, vecs, xb);
  } else {
    hipMemsetAsync(att, 0, 2097152 * sizeof(float), stream);
    int nchunks = 8 / hc;
    for (int c = 0; c < nchunks; c++) {
      int nbh = 4 * hc;
      qkv_kernel<<<dim3(2 * hc, 64, 3), 256, 0, stream>>>(
          sbuf, pWq, pWk, pWv, Qc, Kc, Vc, c * hc * 16, hc);
      attn_kernel<<<dim3(nbh * 16), 256, 0, stream>>>(Qc, Kc, Vc, Oc, nbh);
      accum_kernel<<<dim3(128), 256, 0, stream>>>(Oc, pWo, att, c * hc * 8, hc);
    }
    ln1_kernel<<<dim3(2048), 256, 0, stream>>>(att, sbuf, vecs, xb);
  }
  ffn_ln2_kernel<<<dim3(128), 256, 0, stream>>>(xb, pW1, pW2, vecs, seq,
                                                (void*)d_out);
}

// Round 6
// 348.750 us; speedup vs baseline: 1.4204x; 1.0024x over previous
//
#include <hip/hip_runtime.h>

// ---------------------------------------------------------------------------
// TransformerEncoderLayer on MI355X (gfx950).  B=4 L=2048 D=256 H=8 FF=128.
// Input dtype (fp32 vs bf16) detected at runtime; compute bf16 MFMA, fp32 acc.
// Layouts: A[m=lane&15][k=8*(lane>>4)+j], B[k=8*(lane>>4)+j][n=lane&15],
//          C/D[row=(lane>>4)*4+r][col=lane&15]
// R3: V pre-transposed [B,h,D,L].  R8: 128 q/block, XCD swizzle.
// R12: transposed dataflow (S^T = K Q^T, O^T = V^T P^T), per-lane softmax.
// R13: STATIC-MAX softmax — p = 2^(s*cexp), no running max; accum+LN1 fused.
// R14: 4 waves x 32 q (2 q-tiles/wave); NEUTRAL -> LDS read BW not binding.
// R15: cross-barrier deferred-PV pipeline; REGRESSED (exposed issue chain).
// R16: bare v_exp_f32 + v_cvt_pk_bf16_f32 softmax: 198->177us.  Exposed
//      VALU converts ~1:1 to wall.
// R17: QK split + interleave; REGRESSED via scratch spill.  REVERTED.
// R18: P redistribution in registers via permlane32/16_swap: 177->173us,
//      bank conflicts 3.5M->0.39M, plds deleted (LDS 65536).
// R19: (a) softmax scale folded into Q at qkv time (Q *= 0.0625*log2e in
//      fp32 epilogue) -> removes 16 v_mul/wave/iter from attn's exposed
//      softmax phase.  (b) qkv/accum staging via global_load_lds (async,
//      no VGPR roundtrip; accum_ln1 stages 1MB/block through this path).
// ---------------------------------------------------------------------------

typedef unsigned short u16;
typedef unsigned int   u32;
typedef __bf16 bf16x8 __attribute__((ext_vector_type(8)));
typedef __bf16 bf16x2 __attribute__((ext_vector_type(2)));
typedef float  f32x4  __attribute__((ext_vector_type(4)));

#define MFMA(a, b, c) __builtin_amdgcn_mfma_f32_16x16x32_bf16(a, b, c, 0, 0, 0)

#if __has_builtin(__builtin_amdgcn_exp2f)
#define EXP2(x) __builtin_amdgcn_exp2f(x)
#else
#define EXP2(x) exp2f(x)
#endif

#if __has_builtin(__builtin_amdgcn_permlane16_swap) && \
    __has_builtin(__builtin_amdgcn_permlane32_swap)
#define HAS_PERMSWAP 1
#else
#define HAS_PERMSWAP 0
#endif

// softmax scale * log2(e), folded into Q at projection time (R19)
#define CEXP 0.09016844f

__device__ __forceinline__ float b2f(u16 h) {
  return __uint_as_float(((u32)h) << 16);
}
__device__ __forceinline__ u16 f2b(float f) {
  u32 u = __float_as_uint(f);
  u += 0x7FFFu + ((u >> 16) & 1u);   // round-to-nearest-even
  return (u16)(u >> 16);
}
// packed f32x2 -> bf16x2 (RTNE); gfx950 backend emits v_cvt_pk_bf16_f32
__device__ __forceinline__ u32 pkbf(float lo, float hi) {
  bf16x2 v;
  v[0] = (__bf16)lo;
  v[1] = (__bf16)hi;
  return __builtin_bit_cast(u32, v);
}
__device__ __forceinline__ bf16x8 ldb8(const u16* p) { return *(const bf16x8*)p; }

typedef const __attribute__((address_space(1))) u32* gas1_t;
typedef __attribute__((address_space(3))) u32* las3_t;
__device__ __forceinline__ void gload_lds16(const u16* g, u16* lds_base) {
  __builtin_amdgcn_global_load_lds((gas1_t)(const void*)g,
                                   (las3_t)(void*)lds_base, 16, 0, 0);
}

__device__ __forceinline__ int detect_f32(const void* seq) {
  const u32* s = (const u32*)seq;
  int cnt = 0;
  #pragma unroll
  for (int i = 0; i < 64; i++) {
    u32 e = (s[i] >> 7) & 0xFFu;
    cnt += (e >= 100u && e <= 140u) ? 1 : 0;
  }
  return cnt < 48;  // 1 => fp32
}

__device__ __forceinline__ u16 ldw(const void* W, size_t idx, int isf32) {
  return isf32 ? f2b(((const float*)W)[idx]) : ((const u16*)W)[idx];
}

#if HAS_PERMSWAP
// softmax for one q-tile: p = 2^s (scale pre-folded into Q); accumulate
// per-lane l; return PV B-operand fragment in registers via permlane swaps.
__device__ __forceinline__ bf16x8 softmax_pa(f32x4 sn0, f32x4 sn1,
                                             float& lsum) {
  float p00 = EXP2(sn0[0]), p01 = EXP2(sn0[1]);
  float p02 = EXP2(sn0[2]), p03 = EXP2(sn0[3]);
  float p10 = EXP2(sn1[0]), p11 = EXP2(sn1[1]);
  float p12 = EXP2(sn1[2]), p13 = EXP2(sn1[3]);
  lsum += ((p00 + p01) + (p02 + p03)) + ((p10 + p11) + (p12 + p13));
  u32 A0 = pkbf(p00, p01), A1 = pkbf(p02, p03);
  u32 B0 = pkbf(p10, p11), B1 = pkbf(p12, p13);
  auto ra = __builtin_amdgcn_permlane32_swap(A0, B0, false, false);
  auto rb = __builtin_amdgcn_permlane32_swap(A1, B1, false, false);
  auto sa = __builtin_amdgcn_permlane16_swap(ra[0], ra[1], false, false);
  auto sb = __builtin_amdgcn_permlane16_swap(rb[0], rb[1], false, false);
  uint4 wv;
  wv.x = sa[0];  // keys 8Q+0,1
  wv.y = sb[0];  // keys 8Q+2,3
  wv.z = sa[1];  // keys 8Q+4,5
  wv.w = sb[1];  // keys 8Q+6,7
  return __builtin_bit_cast(bf16x8, wv);
}
#endif

// ---------------------------------------------------------------------------
// Ingest: canonicalize seq (2M elems) + 6 small vectors to bf16 in ws.
// ---------------------------------------------------------------------------
__global__ __launch_bounds__(256) void ingest_kernel(
    const void* __restrict__ seq, const void* __restrict__ g1,
    const void* __restrict__ be1, const void* __restrict__ b1,
    const void* __restrict__ b2v, const void* __restrict__ g2,
    const void* __restrict__ be2, u16* __restrict__ sbuf,
    u16* __restrict__ vecs) {
  int isf32 = detect_f32(seq);
  int bx = blockIdx.x, tid = threadIdx.x;
  if (bx < 2048) {
    size_t i = (size_t)bx * 1024 + tid * 4;
    if (isf32) {
      const float* sp = (const float*)seq;
      u16 o0 = f2b(sp[i]), o1 = f2b(sp[i + 1]), o2 = f2b(sp[i + 2]), o3 = f2b(sp[i + 3]);
      uint2 ov; ov.x = (u32)o0 | ((u32)o1 << 16); ov.y = (u32)o2 | ((u32)o3 << 16);
      *(uint2*)(sbuf + i) = ov;
    } else {
      *(uint2*)(sbuf + i) = ((const uint2*)seq)[i >> 2];
    }
  } else {
    int t = bx - 2048;
    const void* src; int n;
    switch (t) {
      case 0: src = g1;  n = 256; break;
      case 1: src = be1; n = 256; break;
      case 2: src = b1;  n = 128; break;
      case 3: src = b2v; n = 256; break;
      case 4: src = g2;  n = 256; break;
      default: src = be2; n = 256; break;
    }
    if (tid < n) vecs[t * 256 + tid] = ldw(src, tid, isf32);
  }
}

// ---------------------------------------------------------------------------
// Pack weights into B-fragment-linear layout.  grid (256, 6), 256 thr.
// ---------------------------------------------------------------------------
__global__ __launch_bounds__(256) void pack_kernel(
    const void* __restrict__ Wq, const void* __restrict__ Wk,
    const void* __restrict__ Wv, const void* __restrict__ Wo,
    const void* __restrict__ W1, const void* __restrict__ W2,
    const void* __restrict__ seq,
    u16* __restrict__ pWq, u16* __restrict__ pWk, u16* __restrict__ pWv,
    u16* __restrict__ pWo, u16* __restrict__ pW1, u16* __restrict__ pW2) {
  int isf32 = detect_f32(seq);
  const void* W; u16* P; int K, N;
  switch (blockIdx.y) {
    case 0: W = Wq; P = pWq; K = 256;  N = 2048; break;
    case 1: W = Wk; P = pWk; K = 256;  N = 2048; break;
    case 2: W = Wv; P = pWv; K = 256;  N = 2048; break;
    case 3: W = Wo; P = pWo; K = 2048; N = 256;  break;
    case 4: W = W1; P = pW1; K = 256;  N = 128;  break;
    default: W = W2; P = pW2; K = 128; N = 256;  break;
  }
  int t = blockIdx.x * 256 + threadIdx.x;
  int total = (K >> 5) * (N >> 4) * 64;
  if (t >= total) return;
  int lane = t & 63, f = t >> 6;
  int NT = N >> 4;
  int kt = f / NT, nt = f - kt * NT;
  int row0 = kt * 32 + ((lane >> 4) << 3);
  int col = nt * 16 + (lane & 15);
  u16 e[8];
  #pragma unroll
  for (int j = 0; j < 8; j++) e[j] = ldw(W, (size_t)(row0 + j) * N + col, isf32);
  uint4 u;
  u.x = (u32)e[0] | ((u32)e[1] << 16);
  u.y = (u32)e[2] | ((u32)e[3] << 16);
  u.z = (u32)e[4] | ((u32)e[5] << 16);
  u.w = (u32)e[6] | ((u32)e[7] << 16);
  *(uint4*)(P + ((size_t)f * 64 + lane) * 8) = u;
}

// ---------------------------------------------------------------------------
// QKV projection for one h-chunk: X(8192x256) @ W(256, hc*256).
// Q,K -> [B,hc,L,D]; V -> transposed [B,hc,D,L].  Coalesced 16B stores via
// LDS transpose.  grid (2*hc, 64, 3), 256 threads.
// R19: weight staging via global_load_lds (async, no VGPR roundtrip);
//      Q output pre-scaled by CEXP (softmax scale folded in).
// ---------------------------------------------------------------------------
__global__ __launch_bounds__(256) void qkv_kernel(
    const u16* __restrict__ X,
    const u16* __restrict__ pWq, const u16* __restrict__ pWk,
    const u16* __restrict__ pWv,
    u16* __restrict__ Qo, u16* __restrict__ Ko, u16* __restrict__ Vo,
    int ntbase, int hc) {
  __shared__ u16 blds[64 * 512];
  const u16* Pw = (blockIdx.z == 0) ? pWq : ((blockIdx.z == 1) ? pWk : pWv);
  u16* Out = (blockIdx.z == 0) ? Qo : ((blockIdx.z == 1) ? Ko : Vo);
  int tid = threadIdx.x, lane = tid & 63, w = tid >> 6;
  int nt0 = ntbase + blockIdx.x * 8;
  // async staging: frag fl = w + i*4; dst = blds + fl*512 (+ lane*8 by HW)
  #pragma unroll
  for (int i = 0; i < 16; i++) {
    int fl = w + i * 4;
    int kt = fl >> 3, nt = fl & 7;
    gload_lds16(Pw + ((size_t)(kt * 128 + nt0 + nt) * 64 + lane) * 8,
                blds + (size_t)fl * 512);
  }
  asm volatile("s_waitcnt vmcnt(0)" ::: "memory");
  __syncthreads();
  int m0 = blockIdx.y * 128 + w * 32;
  f32x4 acc[2][8] = {};
  #pragma unroll
  for (int kt = 0; kt < 8; kt++) {
    bf16x8 a0 = ldb8(X + (size_t)(m0 + (lane & 15)) * 256 + kt * 32 + (lane >> 4) * 8);
    bf16x8 a1 = ldb8(X + (size_t)(m0 + 16 + (lane & 15)) * 256 + kt * 32 + (lane >> 4) * 8);
    const u16* bp = blds + (size_t)kt * 8 * 512 + (size_t)lane * 8;
    #pragma unroll
    for (int nt = 0; nt < 8; nt++) {
      bf16x8 b = ldb8(bp + nt * 512);
      acc[0][nt] = MFMA(a0, b, acc[0][nt]);
      acc[1][nt] = MFMA(a1, b, acc[1][nt]);
    }
  }
  int isv = (blockIdx.z == 2);
  float sc = (blockIdx.z == 0) ? CEXP : 1.0f;   // R19: fold softmax scale into Q
  int hl = blockIdx.x >> 1;
  int dd0 = (blockIdx.x & 1) * 128;
  int m0b = blockIdx.y * 128;
  int bi = m0b >> 11, l0 = m0b & 2047;
  __syncthreads();
  if (!isv) {
    #pragma unroll
    for (int mt = 0; mt < 2; mt++)
      #pragma unroll
      for (int nt = 0; nt < 8; nt++)
        #pragma unroll
        for (int r = 0; r < 4; r++)
          blds[(w * 32 + mt * 16 + (lane >> 4) * 4 + r) * 136 + nt * 16 + (lane & 15)] =
              f2b(acc[mt][nt][r] * sc);
    __syncthreads();
    #pragma unroll
    for (int i = 0; i < 8; i++) {
      int c = tid + i * 256;
      int mloc = c >> 4, q = c & 15;
      uint4 v = *(uint4*)(blds + mloc * 136 + q * 8);
      *(uint4*)(Out + ((size_t)(bi * hc + hl) * 2048 + l0 + mloc) * 256 + dd0 + q * 8) = v;
    }
  } else {
    #pragma unroll
    for (int mt = 0; mt < 2; mt++)
      #pragma unroll
      for (int nt = 0; nt < 8; nt++)
        #pragma unroll
        for (int r = 0; r < 4; r++)
          blds[(nt * 16 + (lane & 15)) * 136 + w * 32 + mt * 16 + (lane >> 4) * 4 + r] =
              f2b(acc[mt][nt][r]);
    __syncthreads();
    #pragma unroll
    for (int i = 0; i < 8; i++) {
      int c = tid + i * 256;
      int nloc = c >> 4, q = c & 15;
      uint4 v = *(uint4*)(blds + nloc * 136 + q * 8);
      *(uint4*)(Out + ((size_t)(bi * hc + hl) * 256 + dd0 + nloc) * 2048 + l0 + q * 8) = v;
    }
  }
}

// ---------------------------------------------------------------------------
// Flash attention, transposed dataflow, STATIC-MAX softmax.
// R14 base: 4 waves x 32 q (2 q-tiles/wave); K+V double-buffered, ONE
// barrier/iter.  R16/R18: cheap softmax, in-register P via permlane.
// R19: p = 2^s directly (scale pre-folded into Q).  grid (nbh*16), 256 thr,
// 128 q/block; LDS 65536 B -> 2 blocks/CU.
// ---------------------------------------------------------------------------
__global__ __launch_bounds__(256, 2) void attn_kernel(
    const u16* __restrict__ Q, const u16* __restrict__ K,
    const u16* __restrict__ Vt, u16* __restrict__ O, int nbh) {
  __shared__ u16 kbuf[2 * 8192];   // 2 bufs x 16 frags x 512 u16 (frag-linear)
  __shared__ u16 vbuf[2 * 8192];
#if !HAS_PERMSWAP
  __shared__ u16 plds[4 * 1280];   // per-wave P [32 q][40] (fallback path)
#endif
  int tid = threadIdx.x, lane = tid & 63, w = tid >> 6;
  int bi2 = blockIdx.x;
  int bh, qt;
  if (nbh >= 8) {
    int G = nbh >> 3;
    bh = (bi2 & 7) * G + (bi2 >> 3) % G;
    qt = bi2 / (8 * G);
  } else {
    bh = bi2 % nbh; qt = bi2 / nbh;
  }
  const u16* Qb  = Q  + (size_t)bh * 2048 * 256;
  const u16* Kb  = K  + (size_t)bh * 2048 * 256;
  const u16* Vtb = Vt + (size_t)bh * 256 * 2048;
  u16* Ob = O + (size_t)bh * 2048 * 256;
  int q0 = qt * 128 + w * 32;
  bf16x8 qf[2][8];   // B-operand per q-tile: n=q=lane&15, k=d
  #pragma unroll
  for (int qq = 0; qq < 2; qq++)
    #pragma unroll
    for (int kt = 0; kt < 8; kt++)
      qf[qq][kt] = ldb8(Qb + (size_t)(q0 + qq * 16 + (lane & 15)) * 256 +
                        kt * 32 + (lane >> 4) * 8);
  f32x4 o[2][16] = {};             // O^T per q-tile: [d=16nt+4quad+r][q=lane&15]
  float lsum[2] = {0.f, 0.f};      // per-lane partial sum of p, per q-tile
#if !HAS_PERMSWAP
  u16* pl = plds + (size_t)w * 1280;
#endif

  // pre-loop: issue K(0), V(0) into buffer 0 (4 waves x 4 frags = 16)
  #pragma unroll
  for (int j = 0; j < 4; j++) {
    int f = w * 4 + j;
    gload_lds16(Kb + (size_t)((f >> 3) * 16 + (lane & 15)) * 256 +
                    (f & 7) * 32 + (lane >> 4) * 8,
                kbuf + f * 512);
    gload_lds16(Vtb + (size_t)(f * 16 + (lane & 15)) * 2048 + (lane >> 4) * 8,
                vbuf + f * 512);
  }

  for (int t = 0; t < 64; t++) {
    int s0i = t * 32;
    // ONE barrier: K(t),V(t) (issued a full iteration ago) landed.
    asm volatile("s_waitcnt vmcnt(0)\ns_barrier" ::: "memory");
    if (t < 63) {
      int nb = (t + 1) & 1;
      #pragma unroll
      for (int j = 0; j < 4; j++) {
        int f = w * 4 + j;
        gload_lds16(Kb + (size_t)(s0i + 32 + (f >> 3) * 16 + (lane & 15)) * 256 +
                        (f & 7) * 32 + (lane >> 4) * 8,
                    kbuf + nb * 8192 + f * 512);
        gload_lds16(Vtb + (size_t)(f * 16 + (lane & 15)) * 2048 + s0i + 32 +
                        (lane >> 4) * 8,
                    vbuf + nb * 8192 + f * 512);
      }
    }
    // S^T = K Q^T: A = K frag (m=key,k=d), B = qf (k=d,n=q).
    // Each K frag read feeds BOTH q-tiles' MFMAs.
    const u16* kb = kbuf + (t & 1) * 8192;
    f32x4 s[2][2] = {};
    __builtin_amdgcn_s_setprio(1);
    #pragma unroll
    for (int ntk = 0; ntk < 2; ntk++)
      #pragma unroll
      for (int kt = 0; kt < 8; kt++) {
        bf16x8 a = ldb8(kb + (size_t)(ntk * 8 + kt) * 512 + lane * 8);
        s[0][ntk] = MFMA(a, qf[0][kt], s[0][ntk]);
        s[1][ntk] = MFMA(a, qf[1][kt], s[1][ntk]);
      }
    __builtin_amdgcn_s_setprio(0);
#if HAS_PERMSWAP
    // static-max softmax + in-register P redistribution (no LDS roundtrip)
    bf16x8 pa0 = softmax_pa(s[0][0], s[0][1], lsum[0]);
    bf16x8 pa1 = softmax_pa(s[1][0], s[1][1], lsum[1]);
#else
    // fallback: softmax via plds roundtrip (R16 path)
    #pragma unroll
    for (int qq = 0; qq < 2; qq++)
      #pragma unroll
      for (int ntk = 0; ntk < 2; ntk++) {
        float p0 = EXP2(s[qq][ntk][0]);
        float p1 = EXP2(s[qq][ntk][1]);
        float p2 = EXP2(s[qq][ntk][2]);
        float p3 = EXP2(s[qq][ntk][3]);
        lsum[qq] += (p0 + p1) + (p2 + p3);
        uint2 pk;
        pk.x = pkbf(p0, p1);
        pk.y = pkbf(p2, p3);
        *(uint2*)(pl + (qq * 16 + (lane & 15)) * 40 + 16 * ntk + 4 * (lane >> 4)) = pk;
      }
    asm volatile("s_waitcnt lgkmcnt(0)" ::: "memory");
    bf16x8 pa0 = ldb8(pl + (lane & 15) * 40 + (lane >> 4) * 8);
    bf16x8 pa1 = ldb8(pl + (16 + (lane & 15)) * 40 + (lane >> 4) * 8);
    asm volatile("s_waitcnt lgkmcnt(0)" ::: "memory");
#endif
    // ---- O^T += V^T P^T: A = V frag (m=d,k=key); feeds both q-tiles ----
    const u16* vb0 = vbuf + (t & 1) * 8192;
    __builtin_amdgcn_s_setprio(1);
    #pragma unroll
    for (int nt = 0; nt < 16; nt++) {
      bf16x8 vb = ldb8(vb0 + (size_t)nt * 512 + lane * 8);
      o[0][nt] = MFMA(vb, pa0, o[0][nt]);
      o[1][nt] = MFMA(vb, pa1, o[1][nt]);
    }
    __builtin_amdgcn_s_setprio(0);
  }
  // ---- epilogue: o is O^T [d][q]; transpose via kbuf, b64 writes ----
  u16* el = kbuf + w * 1152;             // per-wave [16 q][72]
  __syncthreads();
  #pragma unroll
  for (int qq = 0; qq < 2; qq++) {
    // final l reduction: sum partials across the 4 quads of this q
    float l = lsum[qq];
    l += __shfl_xor(l, 16);
    l += __shfl_xor(l, 32);
    float linv = 1.0f / l;
    #pragma unroll
    for (int g = 0; g < 4; g++) {
      if (qq || g) asm volatile("s_waitcnt lgkmcnt(0)" ::: "memory");
      #pragma unroll
      for (int t2 = 0; t2 < 4; t2++) {
        int nt = g * 4 + t2;
        uint2 pk;
        pk.x = pkbf(o[qq][nt][0] * linv, o[qq][nt][1] * linv);
        pk.y = pkbf(o[qq][nt][2] * linv, o[qq][nt][3] * linv);
        *(uint2*)(el + (lane & 15) * 72 + t2 * 16 + 4 * (lane >> 4)) = pk;
      }
      asm volatile("s_waitcnt lgkmcnt(0)" ::: "memory");
      #pragma unroll
      for (int rep = 0; rep < 2; rep++) {
        int ch = lane + rep * 64;          // 128 chunks: 16 q-rows x 8
        int row = ch >> 3, c8 = ch & 7;
        uint4 v = *(uint4*)(el + row * 72 + c8 * 8);
        *(uint4*)(Ob + (size_t)(q0 + qq * 16 + row) * 256 + g * 64 + c8 * 8) = v;
      }
    }
  }
}

// ---------------------------------------------------------------------------
// Fused (hc==8): x = LN1(seq + O @ Wo).  grid (128), 256 threads.
// Each wave computes 16 complete 256-wide rows -> LN inline.
// R19: Wo staging via global_load_lds (1 MB staged per block).
// ---------------------------------------------------------------------------
__global__ __launch_bounds__(256) void accum_ln1_kernel(
    const u16* __restrict__ Oc, const u16* __restrict__ pWo,
    const u16* __restrict__ sbuf, const u16* __restrict__ vecs,
    u16* __restrict__ xout) {
  __shared__ u16 blds[64 * 512];
  int tid = threadIdx.x, lane = tid & 63, w = tid >> 6;
  int m0 = blockIdx.x * 64 + w * 16;
  int arow = m0 + (lane & 15);
  int bq = arow >> 11, lrow = arow & 2047;
  f32x4 acc[16] = {};
  for (int k0 = 0; k0 < 64; k0 += 4) {
    __syncthreads();
    #pragma unroll
    for (int i = 0; i < 16; i++) {
      int fl = w + i * 4;
      int ktg = k0 + (fl >> 4), nt = fl & 15;
      gload_lds16(pWo + ((size_t)(ktg * 16 + nt) * 64 + lane) * 8,
                  blds + (size_t)fl * 512);
    }
    asm volatile("s_waitcnt vmcnt(0)" ::: "memory");
    __syncthreads();
    #pragma unroll
    for (int kl = 0; kl < 4; kl++) {
      int ktl = k0 + kl;
      int hl = ktl >> 3;
      int d0 = (ktl & 7) * 32 + (lane >> 4) * 8;
      bf16x8 a = ldb8(Oc + ((size_t)(bq * 8 + hl) * 2048 + lrow) * 256 + d0);
      const u16* bp = blds + (size_t)kl * 16 * 512 + (size_t)lane * 8;
      #pragma unroll
      for (int nt = 0; nt < 16; nt++) {
        bf16x8 b = ldb8(bp + nt * 512);
        acc[nt] = MFMA(a, b, acc[nt]);
      }
    }
  }
  int rbase = m0 + (lane >> 4) * 4;
  #pragma unroll
  for (int nt = 0; nt < 16; nt++) {
    int d = nt * 16 + (lane & 15);
    #pragma unroll
    for (int r = 0; r < 4; r++)
      acc[nt][r] += b2f(sbuf[(size_t)(rbase + r) * 256 + d]);
  }
  float mu[4], rs[4];
  #pragma unroll
  for (int r = 0; r < 4; r++) {
    float sm = 0.f;
    #pragma unroll
    for (int nt = 0; nt < 16; nt++) sm += acc[nt][r];
    sm += __shfl_xor(sm, 1); sm += __shfl_xor(sm, 2);
    sm += __shfl_xor(sm, 4); sm += __shfl_xor(sm, 8);
    mu[r] = sm * (1.0f / 256.0f);
    float v = 0.f;
    #pragma unroll
    for (int nt = 0; nt < 16; nt++) { float dd = acc[nt][r] - mu[r]; v += dd * dd; }
    v += __shfl_xor(v, 1); v += __shfl_xor(v, 2);
    v += __shfl_xor(v, 4); v += __shfl_xor(v, 8);
    rs[r] = rsqrtf(v * (1.0f / 256.0f) + 1e-5f);
  }
  #pragma unroll
  for (int nt = 0; nt < 16; nt++) {
    int d = nt * 16 + (lane & 15);
    float gg = b2f(vecs[d]), bb = b2f(vecs[256 + d]);
    #pragma unroll
    for (int r = 0; r < 4; r++)
      xout[(size_t)(rbase + r) * 256 + d] = f2b((acc[nt][r] - mu[r]) * rs[r] * gg + bb);
  }
}

// ---------------------------------------------------------------------------
// Fallback (hc<8): att_out(f32) += O_chunk @ Wo_chunk.  grid (128), 256 thr.
// ---------------------------------------------------------------------------
__global__ __launch_bounds__(256) void accum_kernel(
    const u16* __restrict__ Oc, const u16* __restrict__ pWo,
    float* __restrict__ att_out, int kt0, int hc) {
  __shared__ u16 blds[64 * 512];
  int tid = threadIdx.x, lane = tid & 63, w = tid >> 6;
  int m0 = blockIdx.x * 64 + w * 16;
  int arow = m0 + (lane & 15);
  int bq = arow >> 11, lrow = arow & 2047;
  int ktn = hc * 8;
  f32x4 acc[16] = {};
  for (int k0 = 0; k0 < ktn; k0 += 4) {
    __syncthreads();
    #pragma unroll
    for (int i = 0; i < 16; i++) {
      int fl = w + i * 4;
      int ktg = kt0 + k0 + (fl >> 4), nt = fl & 15;
      gload_lds16(pWo + ((size_t)(ktg * 16 + nt) * 64 + lane) * 8,
                  blds + (size_t)fl * 512);
    }
    asm volatile("s_waitcnt vmcnt(0)" ::: "memory");
    __syncthreads();
    #pragma unroll
    for (int kl = 0; kl < 4; kl++) {
      int ktl = k0 + kl;
      int hl = ktl >> 3;
      int d0 = (ktl & 7) * 32 + (lane >> 4) * 8;
      bf16x8 a = ldb8(Oc + ((size_t)(bq * hc + hl) * 2048 + lrow) * 256 + d0);
      const u16* bp = blds + (size_t)kl * 16 * 512 + (size_t)lane * 8;
      #pragma unroll
      for (int nt = 0; nt < 16; nt++) {
        bf16x8 b = ldb8(bp + nt * 512);
        acc[nt] = MFMA(a, b, acc[nt]);
      }
    }
  }
  int rbase = m0 + (lane >> 4) * 4;
  #pragma unroll
  for (int nt = 0; nt < 16; nt++) {
    int d = nt * 16 + (lane & 15);
    #pragma unroll
    for (int r = 0; r < 4; r++)
      att_out[(size_t)(rbase + r) * 256 + d] += acc[nt][r];
  }
}

// ---------------------------------------------------------------------------
// x = LN1(seq + att_out).  grid (2048), 256 threads; fallback path only.
// ---------------------------------------------------------------------------
__global__ __launch_bounds__(256) void ln1_kernel(
    const float* __restrict__ att_out, const u16* __restrict__ sbuf,
    const u16* __restrict__ vecs, u16* __restrict__ xout) {
  int tid = threadIdx.x, lane = tid & 63, w = tid >> 6;
  int row = blockIdx.x * 4 + w;
  const float* ar = att_out + (size_t)row * 256;
  f32x4 a = *(const f32x4*)(ar + lane * 4);
  uint2 sv = *(const uint2*)(sbuf + (size_t)row * 256 + lane * 4);
  float y[4];
  y[0] = a[0] + b2f((u16)(sv.x & 0xFFFF));
  y[1] = a[1] + b2f((u16)(sv.x >> 16));
  y[2] = a[2] + b2f((u16)(sv.y & 0xFFFF));
  y[3] = a[3] + b2f((u16)(sv.y >> 16));
  float sm = y[0] + y[1] + y[2] + y[3];
  sm += __shfl_xor(sm, 1);  sm += __shfl_xor(sm, 2);  sm += __shfl_xor(sm, 4);
  sm += __shfl_xor(sm, 8);  sm += __shfl_xor(sm, 16); sm += __shfl_xor(sm, 32);
  float mu = sm * (1.0f / 256.0f);
  float v = 0.f;
  #pragma unroll
  for (int j = 0; j < 4; j++) { float d = y[j] - mu; v += d * d; }
  v += __shfl_xor(v, 1);  v += __shfl_xor(v, 2);  v += __shfl_xor(v, 4);
  v += __shfl_xor(v, 8);  v += __shfl_xor(v, 16); v += __shfl_xor(v, 32);
  float rs = rsqrtf(v * (1.0f / 256.0f) + 1e-5f);
  u16 o[4];
  #pragma unroll
  for (int j = 0; j < 4; j++) {
    int d = lane * 4 + j;
    o[j] = f2b((y[j] - mu) * rs * b2f(vecs[d]) + b2f(vecs[256 + d]));
  }
  uint2 ov; ov.x = (u32)o[0] | ((u32)o[1] << 16); ov.y = (u32)o[2] | ((u32)o[3] << 16);
  *(uint2*)(xout + (size_t)row * 256 + lane * 4) = ov;
}

// ---------------------------------------------------------------------------
// FFN + LN2.  out = LN2(x + relu(x@W1+b1)@W2 + b2).  grid(128), 256 thr.
// ---------------------------------------------------------------------------
__global__ __launch_bounds__(256) void ffn_ln2_kernel(
    const u16* __restrict__ x, const u16* __restrict__ pW1,
    const u16* __restrict__ pW2, const u16* __restrict__ vecs,
    const void* __restrict__ seq, void* __restrict__ out) {
  __shared__ u16 hbuf[4 * 16 * 136];
  int isf32 = detect_f32(seq);
  int tid = threadIdx.x, lane = tid & 63, w = tid >> 6;
  int m0 = blockIdx.x * 64 + w * 16;
  int arow = m0 + (lane & 15);
  u16* hb = hbuf + w * 16 * 136;
  f32x4 acc1[8] = {};
  #pragma unroll
  for (int kt = 0; kt < 8; kt++) {
    bf16x8 a = ldb8(x + (size_t)arow * 256 + kt * 32 + (lane >> 4) * 8);
    const u16* bp = pW1 + ((size_t)kt * 8 * 64 + lane) * 8;
    #pragma unroll
    for (int nt = 0; nt < 8; nt++) {
      bf16x8 b = ldb8(bp + nt * 512);
      acc1[nt] = MFMA(a, b, acc1[nt]);
    }
  }
  #pragma unroll
  for (int nt = 0; nt < 8; nt++) {
    int col = nt * 16 + (lane & 15);
    float bb = b2f(vecs[512 + col]);
    #pragma unroll
    for (int r = 0; r < 4; r++) {
      float h = fmaxf(acc1[nt][r] + bb, 0.f);
      hb[((lane >> 4) * 4 + r) * 136 + col] = f2b(h);
    }
  }
  __syncthreads();
  f32x4 acc2[16] = {};
  #pragma unroll
  for (int ks = 0; ks < 4; ks++) {
    bf16x8 a = ldb8(hb + (lane & 15) * 136 + ks * 32 + (lane >> 4) * 8);
    const u16* bp = pW2 + ((size_t)ks * 16 * 64 + lane) * 8;
    #pragma unroll
    for (int nt = 0; nt < 16; nt++) {
      bf16x8 b = ldb8(bp + nt * 512);
      acc2[nt] = MFMA(a, b, acc2[nt]);
    }
  }
  int rbase = m0 + (lane >> 4) * 4;
  #pragma unroll
  for (int nt = 0; nt < 16; nt++) {
    int d = nt * 16 + (lane & 15);
    float bb = b2f(vecs[768 + d]);
    #pragma unroll
    for (int r = 0; r < 4; r++)
      acc2[nt][r] += bb + b2f(x[(size_t)(rbase + r) * 256 + d]);
  }
  float mu[4], rs[4];
  #pragma unroll
  for (int r = 0; r < 4; r++) {
    float sm = 0.f;
    #pragma unroll
    for (int nt = 0; nt < 16; nt++) sm += acc2[nt][r];
    sm += __shfl_xor(sm, 1); sm += __shfl_xor(sm, 2);
    sm += __shfl_xor(sm, 4); sm += __shfl_xor(sm, 8);
    mu[r] = sm * (1.0f / 256.0f);
    float v = 0.f;
    #pragma unroll
    for (int nt = 0; nt < 16; nt++) { float dd = acc2[nt][r] - mu[r]; v += dd * dd; }
    v += __shfl_xor(v, 1); v += __shfl_xor(v, 2);
    v += __shfl_xor(v, 4); v += __shfl_xor(v, 8);
    rs[r] = rsqrtf(v * (1.0f / 256.0f) + 1e-5f);
  }
  #pragma unroll
  for (int nt = 0; nt < 16; nt++) {
    int d = nt * 16 + (lane & 15);
    float gg = b2f(vecs[1024 + d]), bb = b2f(vecs[1280 + d]);
    #pragma unroll
    for (int r = 0; r < 4; r++) {
      float val = (acc2[nt][r] - mu[r]) * rs[r] * gg + bb;
      size_t idx = (size_t)(rbase + r) * 256 + d;
      if (isf32) ((float*)out)[idx] = val;
      else       ((u16*)out)[idx]   = f2b(val);
    }
  }
}

// ---------------------------------------------------------------------------
__global__ __launch_bounds__(256) void sentinel_kernel(void* out, int n,
                                                       const void* seq) {
  int isf32 = detect_f32(seq);
  int i = blockIdx.x * 256 + threadIdx.x;
  if (i < n) {
    if (isf32) ((float*)out)[i] = 777.0f;
    else       ((u16*)out)[i]   = 0x4442;
  }
}

// ---------------------------------------------------------------------------
extern "C" void kernel_launch(void* const* d_in, const int* in_sizes, int n_in,
                              void* d_out, int out_size, void* d_ws, size_t ws_size,
                              hipStream_t stream) {
  (void)in_sizes; (void)n_in;
  const void* seq  = d_in[0];
  const void* Wq   = d_in[1];
  const void* Wk   = d_in[2];
  const void* Wv   = d_in[3];
  const void* Wo   = d_in[4];
  const void* g1   = d_in[5];
  const void* be1  = d_in[6];
  const void* W1   = d_in[7];
  const void* b1   = d_in[8];
  const void* W2   = d_in[9];
  const void* b2   = d_in[10];
  const void* g2   = d_in[11];
  const void* be2  = d_in[12];

  size_t o = 0;
  u16* ws = (u16*)d_ws;
  u16* pWq = ws + o; o += 524288;
  u16* pWk = ws + o; o += 524288;
  u16* pWv = ws + o; o += 524288;
  u16* pWo = ws + o; o += 524288;
  u16* pW1 = ws + o; o += 32768;
  u16* pW2 = ws + o; o += 32768;
  float* att = (float*)(ws + o); o += 4194304;   // 2M f32 (fallback path)
  u16* xb   = ws + o; o += 2097152;
  u16* sbuf = ws + o; o += 2097152;
  u16* vecs = ws + o; o += 2048;
  size_t fixed_elems = o;

  int hc = 0;
  for (int c = 8; c >= 1; c >>= 1) {
    size_t need = (fixed_elems + (size_t)4 * c * 2097152) * 2;
    if (need <= ws_size) { hc = c; break; }
  }
  if (hc == 0) {
    sentinel_kernel<<<dim3((out_size + 255) / 256), 256, 0, stream>>>(
        d_out, out_size, seq);
    return;
  }
  u16* Qc = ws + o; o += (size_t)hc * 2097152;
  u16* Kc = ws + o; o += (size_t)hc * 2097152;
  u16* Vc = ws + o; o += (size_t)hc * 2097152;   // V^T [B,hc,D,L]
  u16* Oc = ws + o;

  ingest_kernel<<<dim3(2054), 256, 0, stream>>>(seq, g1, be1, b1, b2, g2, be2,
                                                sbuf, vecs);
  pack_kernel<<<dim3(256, 6), 256, 0, stream>>>(Wq, Wk, Wv, Wo, W1, W2, seq,
                                                pWq, pWk, pWv, pWo, pW1, pW2);
  if (hc == 8) {
    // single-chunk fast path: fused accum+LN1, no f32 att buffer
    qkv_kernel<<<dim3(16, 64, 3), 256, 0, stream>>>(
        sbuf, pWq, pWk, pWv, Qc, Kc, Vc, 0, 8);
    attn_kernel<<<dim3(32 * 16), 256, 0, stream>>>(Qc, Kc, Vc, Oc, 32);
    accum_ln1_kernel<<<dim3(128), 256, 0, stream>>>(Oc, pWo, sbuf, vecs, xb);
  } else {
    hipMemsetAsync(att, 0, 2097152 * sizeof(float), stream);
    int nchunks = 8 / hc;
    for (int c = 0; c < nchunks; c++) {
      int nbh = 4 * hc;
      qkv_kernel<<<dim3(2 * hc, 64, 3), 256, 0, stream>>>(
          sbuf, pWq, pWk, pWv, Qc, Kc, Vc, c * hc * 16, hc);
      attn_kernel<<<dim3(nbh * 16), 256, 0, stream>>>(Qc, Kc, Vc, Oc, nbh);
      accum_kernel<<<dim3(128), 256, 0, stream>>>(Oc, pWo, att, c * hc * 8, hc);
    }
    ln1_kernel<<<dim3(2048), 256, 0, stream>>>(att, sbuf, vecs, xb);
  }
  ffn_ln2_kernel<<<dim3(128), 256, 0, stream>>>(xb, pW1, pW2, vecs, seq,
                                                (void*)d_out);
}

// Round 7
// 345.837 us; speedup vs baseline: 1.4323x; 1.0084x over previous
//
#include <hip/hip_runtime.h>

// ---------------------------------------------------------------------------
// TransformerEncoderLayer on MI355X (gfx950).  B=4 L=2048 D=256 H=8 FF=128.
// Input dtype (fp32 vs bf16) detected at runtime; compute bf16 MFMA, fp32 acc.
// Layouts: A[m=lane&15][k=8*(lane>>4)+j], B[k=8*(lane>>4)+j][n=lane&15],
//          C/D[row=(lane>>4)*4+r][col=lane&15]
// R3: V pre-transposed [B,h,D,L].  R8: 128 q/block, XCD swizzle.
// R12: transposed dataflow (S^T = K Q^T, O^T = V^T P^T), per-lane softmax.
// R13: STATIC-MAX softmax — p = 2^(s*cexp), no running max; accum+LN1 fused.
// R14: 4 waves x 32 q (2 q-tiles/wave); NEUTRAL -> LDS read BW not binding.
// R15: cross-barrier deferred-PV pipeline; REGRESSED.  REVERTED.
// R16: bare v_exp_f32 + v_cvt_pk_bf16_f32 softmax: 198->177us.
// R17: QK split + interleave; REGRESSED via scratch spill.  REVERTED.
// R18: P redistribution in registers via permlane32/16_swap: 177->173us.
// R19: softmax scale folded into Q (attn 173->169); gload_lds staging in
//      qkv/accum was ~neutral (still synchronous stage).
// R20: the non-attn 180us pool.  (a) accum_ln1 + ffn_ln2 used grid(128) =
//      HALF the 256 CUs idle -> now 256 blocks x 128 thr (2 waves x 16
//      complete rows each; LN math per-wave unchanged).  (b) accum_ln1
//      staging was serial 2-phase (16x stage->drain->compute) -> now
//      K-step=2, double-buffered 2x32KB: stage(r+1) in flight under
//      compute(r).  Fallback (hc<8) path untouched.
// ---------------------------------------------------------------------------

typedef unsigned short u16;
typedef unsigned int   u32;
typedef __bf16 bf16x8 __attribute__((ext_vector_type(8)));
typedef __bf16 bf16x2 __attribute__((ext_vector_type(2)));
typedef float  f32x4  __attribute__((ext_vector_type(4)));

#define MFMA(a, b, c) __builtin_amdgcn_mfma_f32_16x16x32_bf16(a, b, c, 0, 0, 0)

#if __has_builtin(__builtin_amdgcn_exp2f)
#define EXP2(x) __builtin_amdgcn_exp2f(x)
#else
#define EXP2(x) exp2f(x)
#endif

#if __has_builtin(__builtin_amdgcn_permlane16_swap) && \
    __has_builtin(__builtin_amdgcn_permlane32_swap)
#define HAS_PERMSWAP 1
#else
#define HAS_PERMSWAP 0
#endif

// softmax scale * log2(e), folded into Q at projection time (R19)
#define CEXP 0.09016844f

__device__ __forceinline__ float b2f(u16 h) {
  return __uint_as_float(((u32)h) << 16);
}
__device__ __forceinline__ u16 f2b(float f) {
  u32 u = __float_as_uint(f);
  u += 0x7FFFu + ((u >> 16) & 1u);   // round-to-nearest-even
  return (u16)(u >> 16);
}
// packed f32x2 -> bf16x2 (RTNE); gfx950 backend emits v_cvt_pk_bf16_f32
__device__ __forceinline__ u32 pkbf(float lo, float hi) {
  bf16x2 v;
  v[0] = (__bf16)lo;
  v[1] = (__bf16)hi;
  return __builtin_bit_cast(u32, v);
}
__device__ __forceinline__ bf16x8 ldb8(const u16* p) { return *(const bf16x8*)p; }

typedef const __attribute__((address_space(1))) u32* gas1_t;
typedef __attribute__((address_space(3))) u32* las3_t;
__device__ __forceinline__ void gload_lds16(const u16* g, u16* lds_base) {
  __builtin_amdgcn_global_load_lds((gas1_t)(const void*)g,
                                   (las3_t)(void*)lds_base, 16, 0, 0);
}

__device__ __forceinline__ int detect_f32(const void* seq) {
  const u32* s = (const u32*)seq;
  int cnt = 0;
  #pragma unroll
  for (int i = 0; i < 64; i++) {
    u32 e = (s[i] >> 7) & 0xFFu;
    cnt += (e >= 100u && e <= 140u) ? 1 : 0;
  }
  return cnt < 48;  // 1 => fp32
}

__device__ __forceinline__ u16 ldw(const void* W, size_t idx, int isf32) {
  return isf32 ? f2b(((const float*)W)[idx]) : ((const u16*)W)[idx];
}

#if HAS_PERMSWAP
// softmax for one q-tile: p = 2^s (scale pre-folded into Q); accumulate
// per-lane l; return PV B-operand fragment in registers via permlane swaps.
__device__ __forceinline__ bf16x8 softmax_pa(f32x4 sn0, f32x4 sn1,
                                             float& lsum) {
  float p00 = EXP2(sn0[0]), p01 = EXP2(sn0[1]);
  float p02 = EXP2(sn0[2]), p03 = EXP2(sn0[3]);
  float p10 = EXP2(sn1[0]), p11 = EXP2(sn1[1]);
  float p12 = EXP2(sn1[2]), p13 = EXP2(sn1[3]);
  lsum += ((p00 + p01) + (p02 + p03)) + ((p10 + p11) + (p12 + p13));
  u32 A0 = pkbf(p00, p01), A1 = pkbf(p02, p03);
  u32 B0 = pkbf(p10, p11), B1 = pkbf(p12, p13);
  auto ra = __builtin_amdgcn_permlane32_swap(A0, B0, false, false);
  auto rb = __builtin_amdgcn_permlane32_swap(A1, B1, false, false);
  auto sa = __builtin_amdgcn_permlane16_swap(ra[0], ra[1], false, false);
  auto sb = __builtin_amdgcn_permlane16_swap(rb[0], rb[1], false, false);
  uint4 wv;
  wv.x = sa[0];  // keys 8Q+0,1
  wv.y = sb[0];  // keys 8Q+2,3
  wv.z = sa[1];  // keys 8Q+4,5
  wv.w = sb[1];  // keys 8Q+6,7
  return __builtin_bit_cast(bf16x8, wv);
}
#endif

// ---------------------------------------------------------------------------
// Ingest: canonicalize seq (2M elems) + 6 small vectors to bf16 in ws.
// ---------------------------------------------------------------------------
__global__ __launch_bounds__(256) void ingest_kernel(
    const void* __restrict__ seq, const void* __restrict__ g1,
    const void* __restrict__ be1, const void* __restrict__ b1,
    const void* __restrict__ b2v, const void* __restrict__ g2,
    const void* __restrict__ be2, u16* __restrict__ sbuf,
    u16* __restrict__ vecs) {
  int isf32 = detect_f32(seq);
  int bx = blockIdx.x, tid = threadIdx.x;
  if (bx < 2048) {
    size_t i = (size_t)bx * 1024 + tid * 4;
    if (isf32) {
      const float* sp = (const float*)seq;
      u16 o0 = f2b(sp[i]), o1 = f2b(sp[i + 1]), o2 = f2b(sp[i + 2]), o3 = f2b(sp[i + 3]);
      uint2 ov; ov.x = (u32)o0 | ((u32)o1 << 16); ov.y = (u32)o2 | ((u32)o3 << 16);
      *(uint2*)(sbuf + i) = ov;
    } else {
      *(uint2*)(sbuf + i) = ((const uint2*)seq)[i >> 2];
    }
  } else {
    int t = bx - 2048;
    const void* src; int n;
    switch (t) {
      case 0: src = g1;  n = 256; break;
      case 1: src = be1; n = 256; break;
      case 2: src = b1;  n = 128; break;
      case 3: src = b2v; n = 256; break;
      case 4: src = g2;  n = 256; break;
      default: src = be2; n = 256; break;
    }
    if (tid < n) vecs[t * 256 + tid] = ldw(src, tid, isf32);
  }
}

// ---------------------------------------------------------------------------
// Pack weights into B-fragment-linear layout.  grid (256, 6), 256 thr.
// ---------------------------------------------------------------------------
__global__ __launch_bounds__(256) void pack_kernel(
    const void* __restrict__ Wq, const void* __restrict__ Wk,
    const void* __restrict__ Wv, const void* __restrict__ Wo,
    const void* __restrict__ W1, const void* __restrict__ W2,
    const void* __restrict__ seq,
    u16* __restrict__ pWq, u16* __restrict__ pWk, u16* __restrict__ pWv,
    u16* __restrict__ pWo, u16* __restrict__ pW1, u16* __restrict__ pW2) {
  int isf32 = detect_f32(seq);
  const void* W; u16* P; int K, N;
  switch (blockIdx.y) {
    case 0: W = Wq; P = pWq; K = 256;  N = 2048; break;
    case 1: W = Wk; P = pWk; K = 256;  N = 2048; break;
    case 2: W = Wv; P = pWv; K = 256;  N = 2048; break;
    case 3: W = Wo; P = pWo; K = 2048; N = 256;  break;
    case 4: W = W1; P = pW1; K = 256;  N = 128;  break;
    default: W = W2; P = pW2; K = 128; N = 256;  break;
  }
  int t = blockIdx.x * 256 + threadIdx.x;
  int total = (K >> 5) * (N >> 4) * 64;
  if (t >= total) return;
  int lane = t & 63, f = t >> 6;
  int NT = N >> 4;
  int kt = f / NT, nt = f - kt * NT;
  int row0 = kt * 32 + ((lane >> 4) << 3);
  int col = nt * 16 + (lane & 15);
  u16 e[8];
  #pragma unroll
  for (int j = 0; j < 8; j++) e[j] = ldw(W, (size_t)(row0 + j) * N + col, isf32);
  uint4 u;
  u.x = (u32)e[0] | ((u32)e[1] << 16);
  u.y = (u32)e[2] | ((u32)e[3] << 16);
  u.z = (u32)e[4] | ((u32)e[5] << 16);
  u.w = (u32)e[6] | ((u32)e[7] << 16);
  *(uint4*)(P + ((size_t)f * 64 + lane) * 8) = u;
}

// ---------------------------------------------------------------------------
// QKV projection for one h-chunk: X(8192x256) @ W(256, hc*256).
// Q,K -> [B,hc,L,D]; V -> transposed [B,hc,D,L].  Coalesced 16B stores via
// LDS transpose.  grid (2*hc, 64, 3), 256 threads.
// R19: weight staging via global_load_lds; Q pre-scaled by CEXP.
// ---------------------------------------------------------------------------
__global__ __launch_bounds__(256) void qkv_kernel(
    const u16* __restrict__ X,
    const u16* __restrict__ pWq, const u16* __restrict__ pWk,
    const u16* __restrict__ pWv,
    u16* __restrict__ Qo, u16* __restrict__ Ko, u16* __restrict__ Vo,
    int ntbase, int hc) {
  __shared__ u16 blds[64 * 512];
  const u16* Pw = (blockIdx.z == 0) ? pWq : ((blockIdx.z == 1) ? pWk : pWv);
  u16* Out = (blockIdx.z == 0) ? Qo : ((blockIdx.z == 1) ? Ko : Vo);
  int tid = threadIdx.x, lane = tid & 63, w = tid >> 6;
  int nt0 = ntbase + blockIdx.x * 8;
  // async staging: frag fl = w + i*4; dst = blds + fl*512 (+ lane*8 by HW)
  #pragma unroll
  for (int i = 0; i < 16; i++) {
    int fl = w + i * 4;
    int kt = fl >> 3, nt = fl & 7;
    gload_lds16(Pw + ((size_t)(kt * 128 + nt0 + nt) * 64 + lane) * 8,
                blds + (size_t)fl * 512);
  }
  asm volatile("s_waitcnt vmcnt(0)" ::: "memory");
  __syncthreads();
  int m0 = blockIdx.y * 128 + w * 32;
  f32x4 acc[2][8] = {};
  #pragma unroll
  for (int kt = 0; kt < 8; kt++) {
    bf16x8 a0 = ldb8(X + (size_t)(m0 + (lane & 15)) * 256 + kt * 32 + (lane >> 4) * 8);
    bf16x8 a1 = ldb8(X + (size_t)(m0 + 16 + (lane & 15)) * 256 + kt * 32 + (lane >> 4) * 8);
    const u16* bp = blds + (size_t)kt * 8 * 512 + (size_t)lane * 8;
    #pragma unroll
    for (int nt = 0; nt < 8; nt++) {
      bf16x8 b = ldb8(bp + nt * 512);
      acc[0][nt] = MFMA(a0, b, acc[0][nt]);
      acc[1][nt] = MFMA(a1, b, acc[1][nt]);
    }
  }
  int isv = (blockIdx.z == 2);
  float sc = (blockIdx.z == 0) ? CEXP : 1.0f;   // R19: fold softmax scale into Q
  int hl = blockIdx.x >> 1;
  int dd0 = (blockIdx.x & 1) * 128;
  int m0b = blockIdx.y * 128;
  int bi = m0b >> 11, l0 = m0b & 2047;
  __syncthreads();
  if (!isv) {
    #pragma unroll
    for (int mt = 0; mt < 2; mt++)
      #pragma unroll
      for (int nt = 0; nt < 8; nt++)
        #pragma unroll
        for (int r = 0; r < 4; r++)
          blds[(w * 32 + mt * 16 + (lane >> 4) * 4 + r) * 136 + nt * 16 + (lane & 15)] =
              f2b(acc[mt][nt][r] * sc);
    __syncthreads();
    #pragma unroll
    for (int i = 0; i < 8; i++) {
      int c = tid + i * 256;
      int mloc = c >> 4, q = c & 15;
      uint4 v = *(uint4*)(blds + mloc * 136 + q * 8);
      *(uint4*)(Out + ((size_t)(bi * hc + hl) * 2048 + l0 + mloc) * 256 + dd0 + q * 8) = v;
    }
  } else {
    #pragma unroll
    for (int mt = 0; mt < 2; mt++)
      #pragma unroll
      for (int nt = 0; nt < 8; nt++)
        #pragma unroll
        for (int r = 0; r < 4; r++)
          blds[(nt * 16 + (lane & 15)) * 136 + w * 32 + mt * 16 + (lane >> 4) * 4 + r] =
              f2b(acc[mt][nt][r]);
    __syncthreads();
    #pragma unroll
    for (int i = 0; i < 8; i++) {
      int c = tid + i * 256;
      int nloc = c >> 4, q = c & 15;
      uint4 v = *(uint4*)(blds + nloc * 136 + q * 8);
      *(uint4*)(Out + ((size_t)(bi * hc + hl) * 256 + dd0 + nloc) * 2048 + l0 + q * 8) = v;
    }
  }
}

// ---------------------------------------------------------------------------
// Flash attention, transposed dataflow, STATIC-MAX softmax.
// R14 base: 4 waves x 32 q (2 q-tiles/wave); K+V double-buffered, ONE
// barrier/iter.  R16/R18/R19: cheap softmax, in-register P, scale in Q.
// grid (nbh*16), 256 thr, 128 q/block; LDS 65536 B -> 2 blocks/CU.
// ---------------------------------------------------------------------------
__global__ __launch_bounds__(256, 2) void attn_kernel(
    const u16* __restrict__ Q, const u16* __restrict__ K,
    const u16* __restrict__ Vt, u16* __restrict__ O, int nbh) {
  __shared__ u16 kbuf[2 * 8192];   // 2 bufs x 16 frags x 512 u16 (frag-linear)
  __shared__ u16 vbuf[2 * 8192];
#if !HAS_PERMSWAP
  __shared__ u16 plds[4 * 1280];   // per-wave P [32 q][40] (fallback path)
#endif
  int tid = threadIdx.x, lane = tid & 63, w = tid >> 6;
  int bi2 = blockIdx.x;
  int bh, qt;
  if (nbh >= 8) {
    int G = nbh >> 3;
    bh = (bi2 & 7) * G + (bi2 >> 3) % G;
    qt = bi2 / (8 * G);
  } else {
    bh = bi2 % nbh; qt = bi2 / nbh;
  }
  const u16* Qb  = Q  + (size_t)bh * 2048 * 256;
  const u16* Kb  = K  + (size_t)bh * 2048 * 256;
  const u16* Vtb = Vt + (size_t)bh * 256 * 2048;
  u16* Ob = O + (size_t)bh * 2048 * 256;
  int q0 = qt * 128 + w * 32;
  bf16x8 qf[2][8];   // B-operand per q-tile: n=q=lane&15, k=d
  #pragma unroll
  for (int qq = 0; qq < 2; qq++)
    #pragma unroll
    for (int kt = 0; kt < 8; kt++)
      qf[qq][kt] = ldb8(Qb + (size_t)(q0 + qq * 16 + (lane & 15)) * 256 +
                        kt * 32 + (lane >> 4) * 8);
  f32x4 o[2][16] = {};             // O^T per q-tile: [d=16nt+4quad+r][q=lane&15]
  float lsum[2] = {0.f, 0.f};      // per-lane partial sum of p, per q-tile
#if !HAS_PERMSWAP
  u16* pl = plds + (size_t)w * 1280;
#endif

  // pre-loop: issue K(0), V(0) into buffer 0 (4 waves x 4 frags = 16)
  #pragma unroll
  for (int j = 0; j < 4; j++) {
    int f = w * 4 + j;
    gload_lds16(Kb + (size_t)((f >> 3) * 16 + (lane & 15)) * 256 +
                    (f & 7) * 32 + (lane >> 4) * 8,
                kbuf + f * 512);
    gload_lds16(Vtb + (size_t)(f * 16 + (lane & 15)) * 2048 + (lane >> 4) * 8,
                vbuf + f * 512);
  }

  for (int t = 0; t < 64; t++) {
    int s0i = t * 32;
    // ONE barrier: K(t),V(t) (issued a full iteration ago) landed.
    asm volatile("s_waitcnt vmcnt(0)\ns_barrier" ::: "memory");
    if (t < 63) {
      int nb = (t + 1) & 1;
      #pragma unroll
      for (int j = 0; j < 4; j++) {
        int f = w * 4 + j;
        gload_lds16(Kb + (size_t)(s0i + 32 + (f >> 3) * 16 + (lane & 15)) * 256 +
                        (f & 7) * 32 + (lane >> 4) * 8,
                    kbuf + nb * 8192 + f * 512);
        gload_lds16(Vtb + (size_t)(f * 16 + (lane & 15)) * 2048 + s0i + 32 +
                        (lane >> 4) * 8,
                    vbuf + nb * 8192 + f * 512);
      }
    }
    // S^T = K Q^T: A = K frag (m=key,k=d), B = qf (k=d,n=q).
    // Each K frag read feeds BOTH q-tiles' MFMAs.
    const u16* kb = kbuf + (t & 1) * 8192;
    f32x4 s[2][2] = {};
    __builtin_amdgcn_s_setprio(1);
    #pragma unroll
    for (int ntk = 0; ntk < 2; ntk++)
      #pragma unroll
      for (int kt = 0; kt < 8; kt++) {
        bf16x8 a = ldb8(kb + (size_t)(ntk * 8 + kt) * 512 + lane * 8);
        s[0][ntk] = MFMA(a, qf[0][kt], s[0][ntk]);
        s[1][ntk] = MFMA(a, qf[1][kt], s[1][ntk]);
      }
    __builtin_amdgcn_s_setprio(0);
#if HAS_PERMSWAP
    // static-max softmax + in-register P redistribution (no LDS roundtrip)
    bf16x8 pa0 = softmax_pa(s[0][0], s[0][1], lsum[0]);
    bf16x8 pa1 = softmax_pa(s[1][0], s[1][1], lsum[1]);
#else
    // fallback: softmax via plds roundtrip (R16 path)
    #pragma unroll
    for (int qq = 0; qq < 2; qq++)
      #pragma unroll
      for (int ntk = 0; ntk < 2; ntk++) {
        float p0 = EXP2(s[qq][ntk][0]);
        float p1 = EXP2(s[qq][ntk][1]);
        float p2 = EXP2(s[qq][ntk][2]);
        float p3 = EXP2(s[qq][ntk][3]);
        lsum[qq] += (p0 + p1) + (p2 + p3);
        uint2 pk;
        pk.x = pkbf(p0, p1);
        pk.y = pkbf(p2, p3);
        *(uint2*)(pl + (qq * 16 + (lane & 15)) * 40 + 16 * ntk + 4 * (lane >> 4)) = pk;
      }
    asm volatile("s_waitcnt lgkmcnt(0)" ::: "memory");
    bf16x8 pa0 = ldb8(pl + (lane & 15) * 40 + (lane >> 4) * 8);
    bf16x8 pa1 = ldb8(pl + (16 + (lane & 15)) * 40 + (lane >> 4) * 8);
    asm volatile("s_waitcnt lgkmcnt(0)" ::: "memory");
#endif
    // ---- O^T += V^T P^T: A = V frag (m=d,k=key); feeds both q-tiles ----
    const u16* vb0 = vbuf + (t & 1) * 8192;
    __builtin_amdgcn_s_setprio(1);
    #pragma unroll
    for (int nt = 0; nt < 16; nt++) {
      bf16x8 vb = ldb8(vb0 + (size_t)nt * 512 + lane * 8);
      o[0][nt] = MFMA(vb, pa0, o[0][nt]);
      o[1][nt] = MFMA(vb, pa1, o[1][nt]);
    }
    __builtin_amdgcn_s_setprio(0);
  }
  // ---- epilogue: o is O^T [d][q]; transpose via kbuf, b64 writes ----
  u16* el = kbuf + w * 1152;             // per-wave [16 q][72]
  __syncthreads();
  #pragma unroll
  for (int qq = 0; qq < 2; qq++) {
    // final l reduction: sum partials across the 4 quads of this q
    float l = lsum[qq];
    l += __shfl_xor(l, 16);
    l += __shfl_xor(l, 32);
    float linv = 1.0f / l;
    #pragma unroll
    for (int g = 0; g < 4; g++) {
      if (qq || g) asm volatile("s_waitcnt lgkmcnt(0)" ::: "memory");
      #pragma unroll
      for (int t2 = 0; t2 < 4; t2++) {
        int nt = g * 4 + t2;
        uint2 pk;
        pk.x = pkbf(o[qq][nt][0] * linv, o[qq][nt][1] * linv);
        pk.y = pkbf(o[qq][nt][2] * linv, o[qq][nt][3] * linv);
        *(uint2*)(el + (lane & 15) * 72 + t2 * 16 + 4 * (lane >> 4)) = pk;
      }
      asm volatile("s_waitcnt lgkmcnt(0)" ::: "memory");
      #pragma unroll
      for (int rep = 0; rep < 2; rep++) {
        int ch = lane + rep * 64;          // 128 chunks: 16 q-rows x 8
        int row = ch >> 3, c8 = ch & 7;
        uint4 v = *(uint4*)(el + row * 72 + c8 * 8);
        *(uint4*)(Ob + (size_t)(q0 + qq * 16 + row) * 256 + g * 64 + c8 * 8) = v;
      }
    }
  }
}

// ---------------------------------------------------------------------------
// Fused (hc==8): x = LN1(seq + O @ Wo).  R20: grid (256), 128 thr (2 waves
// x 16 complete rows); Wo staging K-step=2, double-buffered 2x32KB so the
// next chunk's loads fly under the current chunk's 32 MFMAs.
// ---------------------------------------------------------------------------
__global__ __launch_bounds__(128) void accum_ln1_kernel(
    const u16* __restrict__ Oc, const u16* __restrict__ pWo,
    const u16* __restrict__ sbuf, const u16* __restrict__ vecs,
    u16* __restrict__ xout) {
  __shared__ u16 blds[2 * 32 * 512];   // 2 bufs x (2 kt x 16 nt) frags
  int tid = threadIdx.x, lane = tid & 63, w = tid >> 6;   // w in {0,1}
  int m0 = blockIdx.x * 32 + w * 16;
  int arow = m0 + (lane & 15);
  int bq = arow >> 11, lrow = arow & 2047;
  f32x4 acc[16] = {};
  // prologue: stage round 0 (kt 0,1) into buf 0
  #pragma unroll
  for (int i = 0; i < 16; i++) {
    int fl = w + i * 2;                // 32 frags across 2 waves
    int ktg = fl >> 4, nt = fl & 15;
    gload_lds16(pWo + ((size_t)(ktg * 16 + nt) * 64 + lane) * 8,
                blds + (size_t)fl * 512);
  }
  asm volatile("s_waitcnt vmcnt(0)" ::: "memory");
  __syncthreads();
  for (int r = 0; r < 32; r++) {
    int k0 = r * 2;
    const u16* cur = blds + (size_t)(r & 1) * 16384;
    if (r < 31) {
      u16* nxt = blds + (size_t)((r + 1) & 1) * 16384;
      #pragma unroll
      for (int i = 0; i < 16; i++) {
        int fl = w + i * 2;
        int ktg = k0 + 2 + (fl >> 4), nt = fl & 15;
        gload_lds16(pWo + ((size_t)(ktg * 16 + nt) * 64 + lane) * 8,
                    nxt + (size_t)fl * 512);
      }
    }
    #pragma unroll
    for (int kl = 0; kl < 2; kl++) {
      int ktl = k0 + kl;
      int hl = ktl >> 3;
      int d0 = (ktl & 7) * 32 + (lane >> 4) * 8;
      bf16x8 a = ldb8(Oc + ((size_t)(bq * 8 + hl) * 2048 + lrow) * 256 + d0);
      const u16* bp = cur + (size_t)kl * 16 * 512 + (size_t)lane * 8;
      #pragma unroll
      for (int nt = 0; nt < 16; nt++) {
        bf16x8 b = ldb8(bp + nt * 512);
        acc[nt] = MFMA(a, b, acc[nt]);
      }
    }
    asm volatile("s_waitcnt vmcnt(0)" ::: "memory");
    __syncthreads();
  }
  int rbase = m0 + (lane >> 4) * 4;
  #pragma unroll
  for (int nt = 0; nt < 16; nt++) {
    int d = nt * 16 + (lane & 15);
    #pragma unroll
    for (int r = 0; r < 4; r++)
      acc[nt][r] += b2f(sbuf[(size_t)(rbase + r) * 256 + d]);
  }
  float mu[4], rs[4];
  #pragma unroll
  for (int r = 0; r < 4; r++) {
    float sm = 0.f;
    #pragma unroll
    for (int nt = 0; nt < 16; nt++) sm += acc[nt][r];
    sm += __shfl_xor(sm, 1); sm += __shfl_xor(sm, 2);
    sm += __shfl_xor(sm, 4); sm += __shfl_xor(sm, 8);
    mu[r] = sm * (1.0f / 256.0f);
    float v = 0.f;
    #pragma unroll
    for (int nt = 0; nt < 16; nt++) { float dd = acc[nt][r] - mu[r]; v += dd * dd; }
    v += __shfl_xor(v, 1); v += __shfl_xor(v, 2);
    v += __shfl_xor(v, 4); v += __shfl_xor(v, 8);
    rs[r] = rsqrtf(v * (1.0f / 256.0f) + 1e-5f);
  }
  #pragma unroll
  for (int nt = 0; nt < 16; nt++) {
    int d = nt * 16 + (lane & 15);
    float gg = b2f(vecs[d]), bb = b2f(vecs[256 + d]);
    #pragma unroll
    for (int r = 0; r < 4; r++)
      xout[(size_t)(rbase + r) * 256 + d] = f2b((acc[nt][r] - mu[r]) * rs[r] * gg + bb);
  }
}

// ---------------------------------------------------------------------------
// Fallback (hc<8): att_out(f32) += O_chunk @ Wo_chunk.  grid (128), 256 thr.
// ---------------------------------------------------------------------------
__global__ __launch_bounds__(256) void accum_kernel(
    const u16* __restrict__ Oc, const u16* __restrict__ pWo,
    float* __restrict__ att_out, int kt0, int hc) {
  __shared__ u16 blds[64 * 512];
  int tid = threadIdx.x, lane = tid & 63, w = tid >> 6;
  int m0 = blockIdx.x * 64 + w * 16;
  int arow = m0 + (lane & 15);
  int bq = arow >> 11, lrow = arow & 2047;
  int ktn = hc * 8;
  f32x4 acc[16] = {};
  for (int k0 = 0; k0 < ktn; k0 += 4) {
    __syncthreads();
    #pragma unroll
    for (int i = 0; i < 16; i++) {
      int fl = w + i * 4;
      int ktg = kt0 + k0 + (fl >> 4), nt = fl & 15;
      gload_lds16(pWo + ((size_t)(ktg * 16 + nt) * 64 + lane) * 8,
                  blds + (size_t)fl * 512);
    }
    asm volatile("s_waitcnt vmcnt(0)" ::: "memory");
    __syncthreads();
    #pragma unroll
    for (int kl = 0; kl < 4; kl++) {
      int ktl = k0 + kl;
      int hl = ktl >> 3;
      int d0 = (ktl & 7) * 32 + (lane >> 4) * 8;
      bf16x8 a = ldb8(Oc + ((size_t)(bq * hc + hl) * 2048 + lrow) * 256 + d0);
      const u16* bp = blds + (size_t)kl * 16 * 512 + (size_t)lane * 8;
      #pragma unroll
      for (int nt = 0; nt < 16; nt++) {
        bf16x8 b = ldb8(bp + nt * 512);
        acc[nt] = MFMA(a, b, acc[nt]);
      }
    }
  }
  int rbase = m0 + (lane >> 4) * 4;
  #pragma unroll
  for (int nt = 0; nt < 16; nt++) {
    int d = nt * 16 + (lane & 15);
    #pragma unroll
    for (int r = 0; r < 4; r++)
      att_out[(size_t)(rbase + r) * 256 + d] += acc[nt][r];
  }
}

// ---------------------------------------------------------------------------
// x = LN1(seq + att_out).  grid (2048), 256 threads; fallback path only.
// ---------------------------------------------------------------------------
__global__ __launch_bounds__(256) void ln1_kernel(
    const float* __restrict__ att_out, const u16* __restrict__ sbuf,
    const u16* __restrict__ vecs, u16* __restrict__ xout) {
  int tid = threadIdx.x, lane = tid & 63, w = tid >> 6;
  int row = blockIdx.x * 4 + w;
  const float* ar = att_out + (size_t)row * 256;
  f32x4 a = *(const f32x4*)(ar + lane * 4);
  uint2 sv = *(const uint2*)(sbuf + (size_t)row * 256 + lane * 4);
  float y[4];
  y[0] = a[0] + b2f((u16)(sv.x & 0xFFFF));
  y[1] = a[1] + b2f((u16)(sv.x >> 16));
  y[2] = a[2] + b2f((u16)(sv.y & 0xFFFF));
  y[3] = a[3] + b2f((u16)(sv.y >> 16));
  float sm = y[0] + y[1] + y[2] + y[3];
  sm += __shfl_xor(sm, 1);  sm += __shfl_xor(sm, 2);  sm += __shfl_xor(sm, 4);
  sm += __shfl_xor(sm, 8);  sm += __shfl_xor(sm, 16); sm += __shfl_xor(sm, 32);
  float mu = sm * (1.0f / 256.0f);
  float v = 0.f;
  #pragma unroll
  for (int j = 0; j < 4; j++) { float d = y[j] - mu; v += d * d; }
  v += __shfl_xor(v, 1);  v += __shfl_xor(v, 2);  v += __shfl_xor(v, 4);
  v += __shfl_xor(v, 8);  v += __shfl_xor(v, 16); v += __shfl_xor(v, 32);
  float rs = rsqrtf(v * (1.0f / 256.0f) + 1e-5f);
  u16 o[4];
  #pragma unroll
  for (int j = 0; j < 4; j++) {
    int d = lane * 4 + j;
    o[j] = f2b((y[j] - mu) * rs * b2f(vecs[d]) + b2f(vecs[256 + d]));
  }
  uint2 ov; ov.x = (u32)o[0] | ((u32)o[1] << 16); ov.y = (u32)o[2] | ((u32)o[3] << 16);
  *(uint2*)(xout + (size_t)row * 256 + lane * 4) = ov;
}

// ---------------------------------------------------------------------------
// FFN + LN2.  out = LN2(x + relu(x@W1+b1)@W2 + b2).
// R20: grid (256), 128 thr (2 waves x 16 complete rows) — full-GPU spread.
// ---------------------------------------------------------------------------
__global__ __launch_bounds__(128) void ffn_ln2_kernel(
    const u16* __restrict__ x, const u16* __restrict__ pW1,
    const u16* __restrict__ pW2, const u16* __restrict__ vecs,
    const void* __restrict__ seq, void* __restrict__ out) {
  __shared__ u16 hbuf[2 * 16 * 136];
  int isf32 = detect_f32(seq);
  int tid = threadIdx.x, lane = tid & 63, w = tid >> 6;   // w in {0,1}
  int m0 = blockIdx.x * 32 + w * 16;
  int arow = m0 + (lane & 15);
  u16* hb = hbuf + w * 16 * 136;
  f32x4 acc1[8] = {};
  #pragma unroll
  for (int kt = 0; kt < 8; kt++) {
    bf16x8 a = ldb8(x + (size_t)arow * 256 + kt * 32 + (lane >> 4) * 8);
    const u16* bp = pW1 + ((size_t)kt * 8 * 64 + lane) * 8;
    #pragma unroll
    for (int nt = 0; nt < 8; nt++) {
      bf16x8 b = ldb8(bp + nt * 512);
      acc1[nt] = MFMA(a, b, acc1[nt]);
    }
  }
  #pragma unroll
  for (int nt = 0; nt < 8; nt++) {
    int col = nt * 16 + (lane & 15);
    float bb = b2f(vecs[512 + col]);
    #pragma unroll
    for (int r = 0; r < 4; r++) {
      float h = fmaxf(acc1[nt][r] + bb, 0.f);
      hb[((lane >> 4) * 4 + r) * 136 + col] = f2b(h);
    }
  }
  __syncthreads();
  f32x4 acc2[16] = {};
  #pragma unroll
  for (int ks = 0; ks < 4; ks++) {
    bf16x8 a = ldb8(hb + (lane & 15) * 136 + ks * 32 + (lane >> 4) * 8);
    const u16* bp = pW2 + ((size_t)ks * 16 * 64 + lane) * 8;
    #pragma unroll
    for (int nt = 0; nt < 16; nt++) {
      bf16x8 b = ldb8(bp + nt * 512);
      acc2[nt] = MFMA(a, b, acc2[nt]);
    }
  }
  int rbase = m0 + (lane >> 4) * 4;
  #pragma unroll
  for (int nt = 0; nt < 16; nt++) {
    int d = nt * 16 + (lane & 15);
    float bb = b2f(vecs[768 + d]);
    #pragma unroll
    for (int r = 0; r < 4; r++)
      acc2[nt][r] += bb + b2f(x[(size_t)(rbase + r) * 256 + d]);
  }
  float mu[4], rs[4];
  #pragma unroll
  for (int r = 0; r < 4; r++) {
    float sm = 0.f;
    #pragma unroll
    for (int nt = 0; nt < 16; nt++) sm += acc2[nt][r];
    sm += __shfl_xor(sm, 1); sm += __shfl_xor(sm, 2);
    sm += __shfl_xor(sm, 4); sm += __shfl_xor(sm, 8);
    mu[r] = sm * (1.0f / 256.0f);
    float v = 0.f;
    #pragma unroll
    for (int nt = 0; nt < 16; nt++) { float dd = acc2[nt][r] - mu[r]; v += dd * dd; }
    v += __shfl_xor(v, 1); v += __shfl_xor(v, 2);
    v += __shfl_xor(v, 4); v += __shfl_xor(v, 8);
    rs[r] = rsqrtf(v * (1.0f / 256.0f) + 1e-5f);
  }
  #pragma unroll
  for (int nt = 0; nt < 16; nt++) {
    int d = nt * 16 + (lane & 15);
    float gg = b2f(vecs[1024 + d]), bb = b2f(vecs[1280 + d]);
    #pragma unroll
    for (int r = 0; r < 4; r++) {
      float val = (acc2[nt][r] - mu[r]) * rs[r] * gg + bb;
      size_t idx = (size_t)(rbase + r) * 256 + d;
      if (isf32) ((float*)out)[idx] = val;
      else       ((u16*)out)[idx]   = f2b(val);
    }
  }
}

// ---------------------------------------------------------------------------
__global__ __launch_bounds__(256) void sentinel_kernel(void* out, int n,
                                                       const void* seq) {
  int isf32 = detect_f32(seq);
  int i = blockIdx.x * 256 + threadIdx.x;
  if (i < n) {
    if (isf32) ((float*)out)[i] = 777.0f;
    else       ((u16*)out)[i]   = 0x4442;
  }
}

// ---------------------------------------------------------------------------
extern "C" void kernel_launch(void* const* d_in, const int* in_sizes, int n_in,
                              void* d_out, int out_size, void* d_ws, size_t ws_size,
                              hipStream_t stream) {
  (void)in_sizes; (void)n_in;
  const void* seq  = d_in[0];
  const void* Wq   = d_in[1];
  const void* Wk   = d_in[2];
  const void* Wv   = d_in[3];
  const void* Wo   = d_in[4];
  const void* g1   = d_in[5];
  const void* be1  = d_in[6];
  const void* W1   = d_in[7];
  const void* b1   = d_in[8];
  const void* W2   = d_in[9];
  const void* b2   = d_in[10];
  const void* g2   = d_in[11];
  const void* be2  = d_in[12];

  size_t o = 0;
  u16* ws = (u16*)d_ws;
  u16* pWq = ws + o; o += 524288;
  u16* pWk = ws + o; o += 524288;
  u16* pWv = ws + o; o += 524288;
  u16* pWo = ws + o; o += 524288;
  u16* pW1 = ws + o; o += 32768;
  u16* pW2 = ws + o; o += 32768;
  float* att = (float*)(ws + o); o += 4194304;   // 2M f32 (fallback path)
  u16* xb   = ws + o; o += 2097152;
  u16* sbuf = ws + o; o += 2097152;
  u16* vecs = ws + o; o += 2048;
  size_t fixed_elems = o;

  int hc = 0;
  for (int c = 8; c >= 1; c >>= 1) {
    size_t need = (fixed_elems + (size_t)4 * c * 2097152) * 2;
    if (need <= ws_size) { hc = c; break; }
  }
  if (hc == 0) {
    sentinel_kernel<<<dim3((out_size + 255) / 256), 256, 0, stream>>>(
        d_out, out_size, seq);
    return;
  }
  u16* Qc = ws + o; o += (size_t)hc * 2097152;
  u16* Kc = ws + o; o += (size_t)hc * 2097152;
  u16* Vc = ws + o; o += (size_t)hc * 2097152;   // V^T [B,hc,D,L]
  u16* Oc = ws + o;

  ingest_kernel<<<dim3(2054), 256, 0, stream>>>(seq, g1, be1, b1, b2, g2, be2,
                                                sbuf, vecs);
  pack_kernel<<<dim3(256, 6), 256, 0, stream>>>(Wq, Wk, Wv, Wo, W1, W2, seq,
                                                pWq, pWk, pWv, pWo, pW1, pW2);
  if (hc == 8) {
    // single-chunk fast path: fused accum+LN1, no f32 att buffer
    qkv_kernel<<<dim3(16, 64, 3), 256, 0, stream>>>(
        sbuf, pWq, pWk, pWv, Qc, Kc, Vc, 0, 8);
    attn_kernel<<<dim3(32 * 16), 256, 0, stream>>>(Qc, Kc, Vc, Oc, 32);
    accum_ln1_kernel<<<dim3(256), 128, 0, stream>>>(Oc, pWo, sbuf, vecs, xb);
  } else {
    hipMemsetAsync(att, 0, 2097152 * sizeof(float), stream);
    int nchunks = 8 / hc;
    for (int c = 0; c < nchunks; c++) {
      int nbh = 4 * hc;
      qkv_kernel<<<dim3(2 * hc, 64, 3), 256, 0, stream>>>(
          sbuf, pWq, pWk, pWv, Qc, Kc, Vc, c * hc * 16, hc);
      attn_kernel<<<dim3(nbh * 16), 256, 0, stream>>>(Qc, Kc, Vc, Oc, nbh);
      accum_kernel<<<dim3(128), 256, 0, stream>>>(Oc, pWo, att, c * hc * 8, hc);
    }
    ln1_kernel<<<dim3(2048), 256, 0, stream>>>(att, sbuf, vecs, xb);
  }
  ffn_ln2_kernel<<<dim3(256), 128, 0, stream>>>(xb, pW1, pW2, vecs, seq,
                                                (void*)d_out);
}

// Round 8
// 345.629 us; speedup vs baseline: 1.4332x; 1.0006x over previous
//
#include <hip/hip_runtime.h>

// ---------------------------------------------------------------------------
// TransformerEncoderLayer on MI355X (gfx950).  B=4 L=2048 D=256 H=8 FF=128.
// Input dtype (fp32 vs bf16) detected at runtime; compute bf16 MFMA, fp32 acc.
// Layouts: A[m=lane&15][k=8*(lane>>4)+j], B[k=8*(lane>>4)+j][n=lane&15],
//          C/D[row=(lane>>4)*4+r][col=lane&15]
// R3: V pre-transposed [B,h,D,L].  R8: 128 q/block, XCD swizzle.
// R12: transposed dataflow (S^T = K Q^T, O^T = V^T P^T), per-lane softmax.
// R13: STATIC-MAX softmax; accum+LN1 fused.
// R14: 4 waves x 32 q (2 q-tiles/wave).
// R16: bare v_exp_f32 + v_cvt_pk_bf16_f32 softmax: 198->177us.
// R18: P redistribution in registers via permlane32/16_swap: 177->173us.
// R19: softmax scale folded into Q (attn 173->169).
// R20: accum_ln1/ffn_ln2 full-GPU spread + dbuf; ~neutral -> non-attn pool
//      is dominated by qkv (~90-110us by elimination; ~260 TF).
// R21: qkv A-PREFETCH: the MFMA loop read X from GLOBAL per kt (L2 latency
//      exposed, 2 waves/SIMD can't hide it).  Now all 16 A-fragments are
//      loaded into 64 VGPRs BEFORE the weight-staging vmcnt(0) drain, so
//      A-latency hides under the staging wait; MFMA loop is pure reg+LDS.
//      launch_bounds(256,2) caps regs to keep 2 blocks/CU.  Same mechanism
//      in accum_ln1: per-round A-loads hoisted above the stage-issue.
// ---------------------------------------------------------------------------

typedef unsigned short u16;
typedef unsigned int   u32;
typedef __bf16 bf16x8 __attribute__((ext_vector_type(8)));
typedef __bf16 bf16x2 __attribute__((ext_vector_type(2)));
typedef float  f32x4  __attribute__((ext_vector_type(4)));

#define MFMA(a, b, c) __builtin_amdgcn_mfma_f32_16x16x32_bf16(a, b, c, 0, 0, 0)

#if __has_builtin(__builtin_amdgcn_exp2f)
#define EXP2(x) __builtin_amdgcn_exp2f(x)
#else
#define EXP2(x) exp2f(x)
#endif

#if __has_builtin(__builtin_amdgcn_permlane16_swap) && \
    __has_builtin(__builtin_amdgcn_permlane32_swap)
#define HAS_PERMSWAP 1
#else
#define HAS_PERMSWAP 0
#endif

// softmax scale * log2(e), folded into Q at projection time (R19)
#define CEXP 0.09016844f

__device__ __forceinline__ float b2f(u16 h) {
  return __uint_as_float(((u32)h) << 16);
}
__device__ __forceinline__ u16 f2b(float f) {
  u32 u = __float_as_uint(f);
  u += 0x7FFFu + ((u >> 16) & 1u);   // round-to-nearest-even
  return (u16)(u >> 16);
}
// packed f32x2 -> bf16x2 (RTNE); gfx950 backend emits v_cvt_pk_bf16_f32
__device__ __forceinline__ u32 pkbf(float lo, float hi) {
  bf16x2 v;
  v[0] = (__bf16)lo;
  v[1] = (__bf16)hi;
  return __builtin_bit_cast(u32, v);
}
__device__ __forceinline__ bf16x8 ldb8(const u16* p) { return *(const bf16x8*)p; }

typedef const __attribute__((address_space(1))) u32* gas1_t;
typedef __attribute__((address_space(3))) u32* las3_t;
__device__ __forceinline__ void gload_lds16(const u16* g, u16* lds_base) {
  __builtin_amdgcn_global_load_lds((gas1_t)(const void*)g,
                                   (las3_t)(void*)lds_base, 16, 0, 0);
}

__device__ __forceinline__ int detect_f32(const void* seq) {
  const u32* s = (const u32*)seq;
  int cnt = 0;
  #pragma unroll
  for (int i = 0; i < 64; i++) {
    u32 e = (s[i] >> 7) & 0xFFu;
    cnt += (e >= 100u && e <= 140u) ? 1 : 0;
  }
  return cnt < 48;  // 1 => fp32
}

__device__ __forceinline__ u16 ldw(const void* W, size_t idx, int isf32) {
  return isf32 ? f2b(((const float*)W)[idx]) : ((const u16*)W)[idx];
}

#if HAS_PERMSWAP
// softmax for one q-tile: p = 2^s (scale pre-folded into Q); accumulate
// per-lane l; return PV B-operand fragment in registers via permlane swaps.
__device__ __forceinline__ bf16x8 softmax_pa(f32x4 sn0, f32x4 sn1,
                                             float& lsum) {
  float p00 = EXP2(sn0[0]), p01 = EXP2(sn0[1]);
  float p02 = EXP2(sn0[2]), p03 = EXP2(sn0[3]);
  float p10 = EXP2(sn1[0]), p11 = EXP2(sn1[1]);
  float p12 = EXP2(sn1[2]), p13 = EXP2(sn1[3]);
  lsum += ((p00 + p01) + (p02 + p03)) + ((p10 + p11) + (p12 + p13));
  u32 A0 = pkbf(p00, p01), A1 = pkbf(p02, p03);
  u32 B0 = pkbf(p10, p11), B1 = pkbf(p12, p13);
  auto ra = __builtin_amdgcn_permlane32_swap(A0, B0, false, false);
  auto rb = __builtin_amdgcn_permlane32_swap(A1, B1, false, false);
  auto sa = __builtin_amdgcn_permlane16_swap(ra[0], ra[1], false, false);
  auto sb = __builtin_amdgcn_permlane16_swap(rb[0], rb[1], false, false);
  uint4 wv;
  wv.x = sa[0];  // keys 8Q+0,1
  wv.y = sb[0];  // keys 8Q+2,3
  wv.z = sa[1];  // keys 8Q+4,5
  wv.w = sb[1];  // keys 8Q+6,7
  return __builtin_bit_cast(bf16x8, wv);
}
#endif

// ---------------------------------------------------------------------------
// Ingest: canonicalize seq (2M elems) + 6 small vectors to bf16 in ws.
// ---------------------------------------------------------------------------
__global__ __launch_bounds__(256) void ingest_kernel(
    const void* __restrict__ seq, const void* __restrict__ g1,
    const void* __restrict__ be1, const void* __restrict__ b1,
    const void* __restrict__ b2v, const void* __restrict__ g2,
    const void* __restrict__ be2, u16* __restrict__ sbuf,
    u16* __restrict__ vecs) {
  int isf32 = detect_f32(seq);
  int bx = blockIdx.x, tid = threadIdx.x;
  if (bx < 2048) {
    size_t i = (size_t)bx * 1024 + tid * 4;
    if (isf32) {
      const float* sp = (const float*)seq;
      u16 o0 = f2b(sp[i]), o1 = f2b(sp[i + 1]), o2 = f2b(sp[i + 2]), o3 = f2b(sp[i + 3]);
      uint2 ov; ov.x = (u32)o0 | ((u32)o1 << 16); ov.y = (u32)o2 | ((u32)o3 << 16);
      *(uint2*)(sbuf + i) = ov;
    } else {
      *(uint2*)(sbuf + i) = ((const uint2*)seq)[i >> 2];
    }
  } else {
    int t = bx - 2048;
    const void* src; int n;
    switch (t) {
      case 0: src = g1;  n = 256; break;
      case 1: src = be1; n = 256; break;
      case 2: src = b1;  n = 128; break;
      case 3: src = b2v; n = 256; break;
      case 4: src = g2;  n = 256; break;
      default: src = be2; n = 256; break;
    }
    if (tid < n) vecs[t * 256 + tid] = ldw(src, tid, isf32);
  }
}

// ---------------------------------------------------------------------------
// Pack weights into B-fragment-linear layout.  grid (256, 6), 256 thr.
// ---------------------------------------------------------------------------
__global__ __launch_bounds__(256) void pack_kernel(
    const void* __restrict__ Wq, const void* __restrict__ Wk,
    const void* __restrict__ Wv, const void* __restrict__ Wo,
    const void* __restrict__ W1, const void* __restrict__ W2,
    const void* __restrict__ seq,
    u16* __restrict__ pWq, u16* __restrict__ pWk, u16* __restrict__ pWv,
    u16* __restrict__ pWo, u16* __restrict__ pW1, u16* __restrict__ pW2) {
  int isf32 = detect_f32(seq);
  const void* W; u16* P; int K, N;
  switch (blockIdx.y) {
    case 0: W = Wq; P = pWq; K = 256;  N = 2048; break;
    case 1: W = Wk; P = pWk; K = 256;  N = 2048; break;
    case 2: W = Wv; P = pWv; K = 256;  N = 2048; break;
    case 3: W = Wo; P = pWo; K = 2048; N = 256;  break;
    case 4: W = W1; P = pW1; K = 256;  N = 128;  break;
    default: W = W2; P = pW2; K = 128; N = 256;  break;
  }
  int t = blockIdx.x * 256 + threadIdx.x;
  int total = (K >> 5) * (N >> 4) * 64;
  if (t >= total) return;
  int lane = t & 63, f = t >> 6;
  int NT = N >> 4;
  int kt = f / NT, nt = f - kt * NT;
  int row0 = kt * 32 + ((lane >> 4) << 3);
  int col = nt * 16 + (lane & 15);
  u16 e[8];
  #pragma unroll
  for (int j = 0; j < 8; j++) e[j] = ldw(W, (size_t)(row0 + j) * N + col, isf32);
  uint4 u;
  u.x = (u32)e[0] | ((u32)e[1] << 16);
  u.y = (u32)e[2] | ((u32)e[3] << 16);
  u.z = (u32)e[4] | ((u32)e[5] << 16);
  u.w = (u32)e[6] | ((u32)e[7] << 16);
  *(uint4*)(P + ((size_t)f * 64 + lane) * 8) = u;
}

// ---------------------------------------------------------------------------
// QKV projection for one h-chunk: X(8192x256) @ W(256, hc*256).
// Q,K -> [B,hc,L,D]; V -> transposed [B,hc,D,L].  Coalesced 16B stores via
// LDS transpose.  grid (2*hc, 64, 3), 256 threads.
// R21: ALL A-fragments (X) prefetched into 64 VGPRs before the staging
// drain — A-latency hides under the weight vmcnt(0); MFMA loop is reg+LDS.
// ---------------------------------------------------------------------------
__global__ __launch_bounds__(256, 2) void qkv_kernel(
    const u16* __restrict__ X,
    const u16* __restrict__ pWq, const u16* __restrict__ pWk,
    const u16* __restrict__ pWv,
    u16* __restrict__ Qo, u16* __restrict__ Ko, u16* __restrict__ Vo,
    int ntbase, int hc) {
  __shared__ u16 blds[64 * 512];
  const u16* Pw = (blockIdx.z == 0) ? pWq : ((blockIdx.z == 1) ? pWk : pWv);
  u16* Out = (blockIdx.z == 0) ? Qo : ((blockIdx.z == 1) ? Ko : Vo);
  int tid = threadIdx.x, lane = tid & 63, w = tid >> 6;
  int nt0 = ntbase + blockIdx.x * 8;
  int m0 = blockIdx.y * 128 + w * 32;
  // R21: issue all 16 A-loads first; they drain with the weight staging.
  bf16x8 af[2][8];
  #pragma unroll
  for (int kt = 0; kt < 8; kt++) {
    af[0][kt] = ldb8(X + (size_t)(m0 + (lane & 15)) * 256 + kt * 32 + (lane >> 4) * 8);
    af[1][kt] = ldb8(X + (size_t)(m0 + 16 + (lane & 15)) * 256 + kt * 32 + (lane >> 4) * 8);
  }
  // async weight staging: frag fl = w + i*4; dst = blds + fl*512
  #pragma unroll
  for (int i = 0; i < 16; i++) {
    int fl = w + i * 4;
    int kt = fl >> 3, nt = fl & 7;
    gload_lds16(Pw + ((size_t)(kt * 128 + nt0 + nt) * 64 + lane) * 8,
                blds + (size_t)fl * 512);
  }
  asm volatile("s_waitcnt vmcnt(0)" ::: "memory");
  __syncthreads();
  f32x4 acc[2][8] = {};
  #pragma unroll
  for (int kt = 0; kt < 8; kt++) {
    const u16* bp = blds + (size_t)kt * 8 * 512 + (size_t)lane * 8;
    #pragma unroll
    for (int nt = 0; nt < 8; nt++) {
      bf16x8 b = ldb8(bp + nt * 512);
      acc[0][nt] = MFMA(af[0][kt], b, acc[0][nt]);
      acc[1][nt] = MFMA(af[1][kt], b, acc[1][nt]);
    }
  }
  int isv = (blockIdx.z == 2);
  float sc = (blockIdx.z == 0) ? CEXP : 1.0f;   // R19: fold softmax scale into Q
  int hl = blockIdx.x >> 1;
  int dd0 = (blockIdx.x & 1) * 128;
  int m0b = blockIdx.y * 128;
  int bi = m0b >> 11, l0 = m0b & 2047;
  __syncthreads();
  if (!isv) {
    #pragma unroll
    for (int mt = 0; mt < 2; mt++)
      #pragma unroll
      for (int nt = 0; nt < 8; nt++)
        #pragma unroll
        for (int r = 0; r < 4; r++)
          blds[(w * 32 + mt * 16 + (lane >> 4) * 4 + r) * 136 + nt * 16 + (lane & 15)] =
              f2b(acc[mt][nt][r] * sc);
    __syncthreads();
    #pragma unroll
    for (int i = 0; i < 8; i++) {
      int c = tid + i * 256;
      int mloc = c >> 4, q = c & 15;
      uint4 v = *(uint4*)(blds + mloc * 136 + q * 8);
      *(uint4*)(Out + ((size_t)(bi * hc + hl) * 2048 + l0 + mloc) * 256 + dd0 + q * 8) = v;
    }
  } else {
    #pragma unroll
    for (int mt = 0; mt < 2; mt++)
      #pragma unroll
      for (int nt = 0; nt < 8; nt++)
        #pragma unroll
        for (int r = 0; r < 4; r++)
          blds[(nt * 16 + (lane & 15)) * 136 + w * 32 + mt * 16 + (lane >> 4) * 4 + r] =
              f2b(acc[mt][nt][r]);
    __syncthreads();
    #pragma unroll
    for (int i = 0; i < 8; i++) {
      int c = tid + i * 256;
      int nloc = c >> 4, q = c & 15;
      uint4 v = *(uint4*)(blds + nloc * 136 + q * 8);
      *(uint4*)(Out + ((size_t)(bi * hc + hl) * 256 + dd0 + nloc) * 2048 + l0 + q * 8) = v;
    }
  }
}

// ---------------------------------------------------------------------------
// Flash attention, transposed dataflow, STATIC-MAX softmax.
// R14 base: 4 waves x 32 q (2 q-tiles/wave); K+V double-buffered, ONE
// barrier/iter.  R16/R18/R19: cheap softmax, in-register P, scale in Q.
// grid (nbh*16), 256 thr, 128 q/block; LDS 65536 B -> 2 blocks/CU.
// ---------------------------------------------------------------------------
__global__ __launch_bounds__(256, 2) void attn_kernel(
    const u16* __restrict__ Q, const u16* __restrict__ K,
    const u16* __restrict__ Vt, u16* __restrict__ O, int nbh) {
  __shared__ u16 kbuf[2 * 8192];   // 2 bufs x 16 frags x 512 u16 (frag-linear)
  __shared__ u16 vbuf[2 * 8192];
#if !HAS_PERMSWAP
  __shared__ u16 plds[4 * 1280];   // per-wave P [32 q][40] (fallback path)
#endif
  int tid = threadIdx.x, lane = tid & 63, w = tid >> 6;
  int bi2 = blockIdx.x;
  int bh, qt;
  if (nbh >= 8) {
    int G = nbh >> 3;
    bh = (bi2 & 7) * G + (bi2 >> 3) % G;
    qt = bi2 / (8 * G);
  } else {
    bh = bi2 % nbh; qt = bi2 / nbh;
  }
  const u16* Qb  = Q  + (size_t)bh * 2048 * 256;
  const u16* Kb  = K  + (size_t)bh * 2048 * 256;
  const u16* Vtb = Vt + (size_t)bh * 256 * 2048;
  u16* Ob = O + (size_t)bh * 2048 * 256;
  int q0 = qt * 128 + w * 32;
  bf16x8 qf[2][8];   // B-operand per q-tile: n=q=lane&15, k=d
  #pragma unroll
  for (int qq = 0; qq < 2; qq++)
    #pragma unroll
    for (int kt = 0; kt < 8; kt++)
      qf[qq][kt] = ldb8(Qb + (size_t)(q0 + qq * 16 + (lane & 15)) * 256 +
                        kt * 32 + (lane >> 4) * 8);
  f32x4 o[2][16] = {};             // O^T per q-tile: [d=16nt+4quad+r][q=lane&15]
  float lsum[2] = {0.f, 0.f};      // per-lane partial sum of p, per q-tile
#if !HAS_PERMSWAP
  u16* pl = plds + (size_t)w * 1280;
#endif

  // pre-loop: issue K(0), V(0) into buffer 0 (4 waves x 4 frags = 16)
  #pragma unroll
  for (int j = 0; j < 4; j++) {
    int f = w * 4 + j;
    gload_lds16(Kb + (size_t)((f >> 3) * 16 + (lane & 15)) * 256 +
                    (f & 7) * 32 + (lane >> 4) * 8,
                kbuf + f * 512);
    gload_lds16(Vtb + (size_t)(f * 16 + (lane & 15)) * 2048 + (lane >> 4) * 8,
                vbuf + f * 512);
  }

  for (int t = 0; t < 64; t++) {
    int s0i = t * 32;
    // ONE barrier: K(t),V(t) (issued a full iteration ago) landed.
    asm volatile("s_waitcnt vmcnt(0)\ns_barrier" ::: "memory");
    if (t < 63) {
      int nb = (t + 1) & 1;
      #pragma unroll
      for (int j = 0; j < 4; j++) {
        int f = w * 4 + j;
        gload_lds16(Kb + (size_t)(s0i + 32 + (f >> 3) * 16 + (lane & 15)) * 256 +
                        (f & 7) * 32 + (lane >> 4) * 8,
                    kbuf + nb * 8192 + f * 512);
        gload_lds16(Vtb + (size_t)(f * 16 + (lane & 15)) * 2048 + s0i + 32 +
                        (lane >> 4) * 8,
                    vbuf + nb * 8192 + f * 512);
      }
    }
    // S^T = K Q^T: A = K frag (m=key,k=d), B = qf (k=d,n=q).
    // Each K frag read feeds BOTH q-tiles' MFMAs.
    const u16* kb = kbuf + (t & 1) * 8192;
    f32x4 s[2][2] = {};
    __builtin_amdgcn_s_setprio(1);
    #pragma unroll
    for (int ntk = 0; ntk < 2; ntk++)
      #pragma unroll
      for (int kt = 0; kt < 8; kt++) {
        bf16x8 a = ldb8(kb + (size_t)(ntk * 8 + kt) * 512 + lane * 8);
        s[0][ntk] = MFMA(a, qf[0][kt], s[0][ntk]);
        s[1][ntk] = MFMA(a, qf[1][kt], s[1][ntk]);
      }
    __builtin_amdgcn_s_setprio(0);
#if HAS_PERMSWAP
    // static-max softmax + in-register P redistribution (no LDS roundtrip)
    bf16x8 pa0 = softmax_pa(s[0][0], s[0][1], lsum[0]);
    bf16x8 pa1 = softmax_pa(s[1][0], s[1][1], lsum[1]);
#else
    // fallback: softmax via plds roundtrip (R16 path)
    #pragma unroll
    for (int qq = 0; qq < 2; qq++)
      #pragma unroll
      for (int ntk = 0; ntk < 2; ntk++) {
        float p0 = EXP2(s[qq][ntk][0]);
        float p1 = EXP2(s[qq][ntk][1]);
        float p2 = EXP2(s[qq][ntk][2]);
        float p3 = EXP2(s[qq][ntk][3]);
        lsum[qq] += (p0 + p1) + (p2 + p3);
        uint2 pk;
        pk.x = pkbf(p0, p1);
        pk.y = pkbf(p2, p3);
        *(uint2*)(pl + (qq * 16 + (lane & 15)) * 40 + 16 * ntk + 4 * (lane >> 4)) = pk;
      }
    asm volatile("s_waitcnt lgkmcnt(0)" ::: "memory");
    bf16x8 pa0 = ldb8(pl + (lane & 15) * 40 + (lane >> 4) * 8);
    bf16x8 pa1 = ldb8(pl + (16 + (lane & 15)) * 40 + (lane >> 4) * 8);
    asm volatile("s_waitcnt lgkmcnt(0)" ::: "memory");
#endif
    // ---- O^T += V^T P^T: A = V frag (m=d,k=key); feeds both q-tiles ----
    const u16* vb0 = vbuf + (t & 1) * 8192;
    __builtin_amdgcn_s_setprio(1);
    #pragma unroll
    for (int nt = 0; nt < 16; nt++) {
      bf16x8 vb = ldb8(vb0 + (size_t)nt * 512 + lane * 8);
      o[0][nt] = MFMA(vb, pa0, o[0][nt]);
      o[1][nt] = MFMA(vb, pa1, o[1][nt]);
    }
    __builtin_amdgcn_s_setprio(0);
  }
  // ---- epilogue: o is O^T [d][q]; transpose via kbuf, b64 writes ----
  u16* el = kbuf + w * 1152;             // per-wave [16 q][72]
  __syncthreads();
  #pragma unroll
  for (int qq = 0; qq < 2; qq++) {
    // final l reduction: sum partials across the 4 quads of this q
    float l = lsum[qq];
    l += __shfl_xor(l, 16);
    l += __shfl_xor(l, 32);
    float linv = 1.0f / l;
    #pragma unroll
    for (int g = 0; g < 4; g++) {
      if (qq || g) asm volatile("s_waitcnt lgkmcnt(0)" ::: "memory");
      #pragma unroll
      for (int t2 = 0; t2 < 4; t2++) {
        int nt = g * 4 + t2;
        uint2 pk;
        pk.x = pkbf(o[qq][nt][0] * linv, o[qq][nt][1] * linv);
        pk.y = pkbf(o[qq][nt][2] * linv, o[qq][nt][3] * linv);
        *(uint2*)(el + (lane & 15) * 72 + t2 * 16 + 4 * (lane >> 4)) = pk;
      }
      asm volatile("s_waitcnt lgkmcnt(0)" ::: "memory");
      #pragma unroll
      for (int rep = 0; rep < 2; rep++) {
        int ch = lane + rep * 64;          // 128 chunks: 16 q-rows x 8
        int row = ch >> 3, c8 = ch & 7;
        uint4 v = *(uint4*)(el + row * 72 + c8 * 8);
        *(uint4*)(Ob + (size_t)(q0 + qq * 16 + row) * 256 + g * 64 + c8 * 8) = v;
      }
    }
  }
}

// ---------------------------------------------------------------------------
// Fused (hc==8): x = LN1(seq + O @ Wo).  grid (256), 128 thr (2 waves x 16
// complete rows); Wo staging K-step=2, double-buffered.  R21: per-round
// A-loads hoisted above the stage-issue (land under ds_read/MFMA phase).
// ---------------------------------------------------------------------------
__global__ __launch_bounds__(128) void accum_ln1_kernel(
    const u16* __restrict__ Oc, const u16* __restrict__ pWo,
    const u16* __restrict__ sbuf, const u16* __restrict__ vecs,
    u16* __restrict__ xout) {
  __shared__ u16 blds[2 * 32 * 512];   // 2 bufs x (2 kt x 16 nt) frags
  int tid = threadIdx.x, lane = tid & 63, w = tid >> 6;   // w in {0,1}
  int m0 = blockIdx.x * 32 + w * 16;
  int arow = m0 + (lane & 15);
  int bq = arow >> 11, lrow = arow & 2047;
  f32x4 acc[16] = {};
  // prologue: stage round 0 (kt 0,1) into buf 0
  #pragma unroll
  for (int i = 0; i < 16; i++) {
    int fl = w + i * 2;                // 32 frags across 2 waves
    int ktg = fl >> 4, nt = fl & 15;
    gload_lds16(pWo + ((size_t)(ktg * 16 + nt) * 64 + lane) * 8,
                blds + (size_t)fl * 512);
  }
  asm volatile("s_waitcnt vmcnt(0)" ::: "memory");
  __syncthreads();
  for (int r = 0; r < 32; r++) {
    int k0 = r * 2;
    const u16* cur = blds + (size_t)(r & 1) * 16384;
    // R21: A loads first (issue right after barrier; land under stage+ds)
    bf16x8 aA, aB;
    {
      int ktl = k0, hl = ktl >> 3;
      int d0 = (ktl & 7) * 32 + (lane >> 4) * 8;
      aA = ldb8(Oc + ((size_t)(bq * 8 + hl) * 2048 + lrow) * 256 + d0);
      ktl = k0 + 1; hl = ktl >> 3;
      d0 = (ktl & 7) * 32 + (lane >> 4) * 8;
      aB = ldb8(Oc + ((size_t)(bq * 8 + hl) * 2048 + lrow) * 256 + d0);
    }
    if (r < 31) {
      u16* nxt = blds + (size_t)((r + 1) & 1) * 16384;
      #pragma unroll
      for (int i = 0; i < 16; i++) {
        int fl = w + i * 2;
        int ktg = k0 + 2 + (fl >> 4), nt = fl & 15;
        gload_lds16(pWo + ((size_t)(ktg * 16 + nt) * 64 + lane) * 8,
                    nxt + (size_t)fl * 512);
      }
    }
    #pragma unroll
    for (int kl = 0; kl < 2; kl++) {
      bf16x8 a = kl ? aB : aA;
      const u16* bp = cur + (size_t)kl * 16 * 512 + (size_t)lane * 8;
      #pragma unroll
      for (int nt = 0; nt < 16; nt++) {
        bf16x8 b = ldb8(bp + nt * 512);
        acc[nt] = MFMA(a, b, acc[nt]);
      }
    }
    asm volatile("s_waitcnt vmcnt(0)" ::: "memory");
    __syncthreads();
  }
  int rbase = m0 + (lane >> 4) * 4;
  #pragma unroll
  for (int nt = 0; nt < 16; nt++) {
    int d = nt * 16 + (lane & 15);
    #pragma unroll
    for (int r = 0; r < 4; r++)
      acc[nt][r] += b2f(sbuf[(size_t)(rbase + r) * 256 + d]);
  }
  float mu[4], rs[4];
  #pragma unroll
  for (int r = 0; r < 4; r++) {
    float sm = 0.f;
    #pragma unroll
    for (int nt = 0; nt < 16; nt++) sm += acc[nt][r];
    sm += __shfl_xor(sm, 1); sm += __shfl_xor(sm, 2);
    sm += __shfl_xor(sm, 4); sm += __shfl_xor(sm, 8);
    mu[r] = sm * (1.0f / 256.0f);
    float v = 0.f;
    #pragma unroll
    for (int nt = 0; nt < 16; nt++) { float dd = acc[nt][r] - mu[r]; v += dd * dd; }
    v += __shfl_xor(v, 1); v += __shfl_xor(v, 2);
    v += __shfl_xor(v, 4); v += __shfl_xor(v, 8);
    rs[r] = rsqrtf(v * (1.0f / 256.0f) + 1e-5f);
  }
  #pragma unroll
  for (int nt = 0; nt < 16; nt++) {
    int d = nt * 16 + (lane & 15);
    float gg = b2f(vecs[d]), bb = b2f(vecs[256 + d]);
    #pragma unroll
    for (int r = 0; r < 4; r++)
      xout[(size_t)(rbase + r) * 256 + d] = f2b((acc[nt][r] - mu[r]) * rs[r] * gg + bb);
  }
}

// ---------------------------------------------------------------------------
// Fallback (hc<8): att_out(f32) += O_chunk @ Wo_chunk.  grid (128), 256 thr.
// ---------------------------------------------------------------------------
__global__ __launch_bounds__(256) void accum_kernel(
    const u16* __restrict__ Oc, const u16* __restrict__ pWo,
    float* __restrict__ att_out, int kt0, int hc) {
  __shared__ u16 blds[64 * 512];
  int tid = threadIdx.x, lane = tid & 63, w = tid >> 6;
  int m0 = blockIdx.x * 64 + w * 16;
  int arow = m0 + (lane & 15);
  int bq = arow >> 11, lrow = arow & 2047;
  int ktn = hc * 8;
  f32x4 acc[16] = {};
  for (int k0 = 0; k0 < ktn; k0 += 4) {
    __syncthreads();
    #pragma unroll
    for (int i = 0; i < 16; i++) {
      int fl = w + i * 4;
      int ktg = kt0 + k0 + (fl >> 4), nt = fl & 15;
      gload_lds16(pWo + ((size_t)(ktg * 16 + nt) * 64 + lane) * 8,
                  blds + (size_t)fl * 512);
    }
    asm volatile("s_waitcnt vmcnt(0)" ::: "memory");
    __syncthreads();
    #pragma unroll
    for (int kl = 0; kl < 4; kl++) {
      int ktl = k0 + kl;
      int hl = ktl >> 3;
      int d0 = (ktl & 7) * 32 + (lane >> 4) * 8;
      bf16x8 a = ldb8(Oc + ((size_t)(bq * hc + hl) * 2048 + lrow) * 256 + d0);
      const u16* bp = blds + (size_t)kl * 16 * 512 + (size_t)lane * 8;
      #pragma unroll
      for (int nt = 0; nt < 16; nt++) {
        bf16x8 b = ldb8(bp + nt * 512);
        acc[nt] = MFMA(a, b, acc[nt]);
      }
    }
  }
  int rbase = m0 + (lane >> 4) * 4;
  #pragma unroll
  for (int nt = 0; nt < 16; nt++) {
    int d = nt * 16 + (lane & 15);
    #pragma unroll
    for (int r = 0; r < 4; r++)
      att_out[(size_t)(rbase + r) * 256 + d] += acc[nt][r];
  }
}

// ---------------------------------------------------------------------------
// x = LN1(seq + att_out).  grid (2048), 256 threads; fallback path only.
// ---------------------------------------------------------------------------
__global__ __launch_bounds__(256) void ln1_kernel(
    const float* __restrict__ att_out, const u16* __restrict__ sbuf,
    const u16* __restrict__ vecs, u16* __restrict__ xout) {
  int tid = threadIdx.x, lane = tid & 63, w = tid >> 6;
  int row = blockIdx.x * 4 + w;
  const float* ar = att_out + (size_t)row * 256;
  f32x4 a = *(const f32x4*)(ar + lane * 4);
  uint2 sv = *(const uint2*)(sbuf + (size_t)row * 256 + lane * 4);
  float y[4];
  y[0] = a[0] + b2f((u16)(sv.x & 0xFFFF));
  y[1] = a[1] + b2f((u16)(sv.x >> 16));
  y[2] = a[2] + b2f((u16)(sv.y & 0xFFFF));
  y[3] = a[3] + b2f((u16)(sv.y >> 16));
  float sm = y[0] + y[1] + y[2] + y[3];
  sm += __shfl_xor(sm, 1);  sm += __shfl_xor(sm, 2);  sm += __shfl_xor(sm, 4);
  sm += __shfl_xor(sm, 8);  sm += __shfl_xor(sm, 16); sm += __shfl_xor(sm, 32);
  float mu = sm * (1.0f / 256.0f);
  float v = 0.f;
  #pragma unroll
  for (int j = 0; j < 4; j++) { float d = y[j] - mu; v += d * d; }
  v += __shfl_xor(v, 1);  v += __shfl_xor(v, 2);  v += __shfl_xor(v, 4);
  v += __shfl_xor(v, 8);  v += __shfl_xor(v, 16); v += __shfl_xor(v, 32);
  float rs = rsqrtf(v * (1.0f / 256.0f) + 1e-5f);
  u16 o[4];
  #pragma unroll
  for (int j = 0; j < 4; j++) {
    int d = lane * 4 + j;
    o[j] = f2b((y[j] - mu) * rs * b2f(vecs[d]) + b2f(vecs[256 + d]));
  }
  uint2 ov; ov.x = (u32)o[0] | ((u32)o[1] << 16); ov.y = (u32)o[2] | ((u32)o[3] << 16);
  *(uint2*)(xout + (size_t)row * 256 + lane * 4) = ov;
}

// ---------------------------------------------------------------------------
// FFN + LN2.  out = LN2(x + relu(x@W1+b1)@W2 + b2).
// grid (256), 128 thr (2 waves x 16 complete rows) — full-GPU spread.
// ---------------------------------------------------------------------------
__global__ __launch_bounds__(128) void ffn_ln2_kernel(
    const u16* __restrict__ x, const u16* __restrict__ pW1,
    const u16* __restrict__ pW2, const u16* __restrict__ vecs,
    const void* __restrict__ seq, void* __restrict__ out) {
  __shared__ u16 hbuf[2 * 16 * 136];
  int isf32 = detect_f32(seq);
  int tid = threadIdx.x, lane = tid & 63, w = tid >> 6;   // w in {0,1}
  int m0 = blockIdx.x * 32 + w * 16;
  int arow = m0 + (lane & 15);
  u16* hb = hbuf + w * 16 * 136;
  f32x4 acc1[8] = {};
  #pragma unroll
  for (int kt = 0; kt < 8; kt++) {
    bf16x8 a = ldb8(x + (size_t)arow * 256 + kt * 32 + (lane >> 4) * 8);
    const u16* bp = pW1 + ((size_t)kt * 8 * 64 + lane) * 8;
    #pragma unroll
    for (int nt = 0; nt < 8; nt++) {
      bf16x8 b = ldb8(bp + nt * 512);
      acc1[nt] = MFMA(a, b, acc1[nt]);
    }
  }
  #pragma unroll
  for (int nt = 0; nt < 8; nt++) {
    int col = nt * 16 + (lane & 15);
    float bb = b2f(vecs[512 + col]);
    #pragma unroll
    for (int r = 0; r < 4; r++) {
      float h = fmaxf(acc1[nt][r] + bb, 0.f);
      hb[((lane >> 4) * 4 + r) * 136 + col] = f2b(h);
    }
  }
  __syncthreads();
  f32x4 acc2[16] = {};
  #pragma unroll
  for (int ks = 0; ks < 4; ks++) {
    bf16x8 a = ldb8(hb + (lane & 15) * 136 + ks * 32 + (lane >> 4) * 8);
    const u16* bp = pW2 + ((size_t)ks * 16 * 64 + lane) * 8;
    #pragma unroll
    for (int nt = 0; nt < 16; nt++) {
      bf16x8 b = ldb8(bp + nt * 512);
      acc2[nt] = MFMA(a, b, acc2[nt]);
    }
  }
  int rbase = m0 + (lane >> 4) * 4;
  #pragma unroll
  for (int nt = 0; nt < 16; nt++) {
    int d = nt * 16 + (lane & 15);
    float bb = b2f(vecs[768 + d]);
    #pragma unroll
    for (int r = 0; r < 4; r++)
      acc2[nt][r] += bb + b2f(x[(size_t)(rbase + r) * 256 + d]);
  }
  float mu[4], rs[4];
  #pragma unroll
  for (int r = 0; r < 4; r++) {
    float sm = 0.f;
    #pragma unroll
    for (int nt = 0; nt < 16; nt++) sm += acc2[nt][r];
    sm += __shfl_xor(sm, 1); sm += __shfl_xor(sm, 2);
    sm += __shfl_xor(sm, 4); sm += __shfl_xor(sm, 8);
    mu[r] = sm * (1.0f / 256.0f);
    float v = 0.f;
    #pragma unroll
    for (int nt = 0; nt < 16; nt++) { float dd = acc2[nt][r] - mu[r]; v += dd * dd; }
    v += __shfl_xor(v, 1); v += __shfl_xor(v, 2);
    v += __shfl_xor(v, 4); v += __shfl_xor(v, 8);
    rs[r] = rsqrtf(v * (1.0f / 256.0f) + 1e-5f);
  }
  #pragma unroll
  for (int nt = 0; nt < 16; nt++) {
    int d = nt * 16 + (lane & 15);
    float gg = b2f(vecs[1024 + d]), bb = b2f(vecs[1280 + d]);
    #pragma unroll
    for (int r = 0; r < 4; r++) {
      float val = (acc2[nt][r] - mu[r]) * rs[r] * gg + bb;
      size_t idx = (size_t)(rbase + r) * 256 + d;
      if (isf32) ((float*)out)[idx] = val;
      else       ((u16*)out)[idx]   = f2b(val);
    }
  }
}

// ---------------------------------------------------------------------------
__global__ __launch_bounds__(256) void sentinel_kernel(void* out, int n,
                                                       const void* seq) {
  int isf32 = detect_f32(seq);
  int i = blockIdx.x * 256 + threadIdx.x;
  if (i < n) {
    if (isf32) ((float*)out)[i] = 777.0f;
    else       ((u16*)out)[i]   = 0x4442;
  }
}

// ---------------------------------------------------------------------------
extern "C" void kernel_launch(void* const* d_in, const int* in_sizes, int n_in,
                              void* d_out, int out_size, void* d_ws, size_t ws_size,
                              hipStream_t stream) {
  (void)in_sizes; (void)n_in;
  const void* seq  = d_in[0];
  const void* Wq   = d_in[1];
  const void* Wk   = d_in[2];
  const void* Wv   = d_in[3];
  const void* Wo   = d_in[4];
  const void* g1   = d_in[5];
  const void* be1  = d_in[6];
  const void* W1   = d_in[7];
  const void* b1   = d_in[8];
  const void* W2   = d_in[9];
  const void* b2   = d_in[10];
  const void* g2   = d_in[11];
  const void* be2  = d_in[12];

  size_t o = 0;
  u16* ws = (u16*)d_ws;
  u16* pWq = ws + o; o += 524288;
  u16* pWk = ws + o; o += 524288;
  u16* pWv = ws + o; o += 524288;
  u16* pWo = ws + o; o += 524288;
  u16* pW1 = ws + o; o += 32768;
  u16* pW2 = ws + o; o += 32768;
  float* att = (float*)(ws + o); o += 4194304;   // 2M f32 (fallback path)
  u16* xb   = ws + o; o += 2097152;
  u16* sbuf = ws + o; o += 2097152;
  u16* vecs = ws + o; o += 2048;
  size_t fixed_elems = o;

  int hc = 0;
  for (int c = 8; c >= 1; c >>= 1) {
    size_t need = (fixed_elems + (size_t)4 * c * 2097152) * 2;
    if (need <= ws_size) { hc = c; break; }
  }
  if (hc == 0) {
    sentinel_kernel<<<dim3((out_size + 255) / 256), 256, 0, stream>>>(
        d_out, out_size, seq);
    return;
  }
  u16* Qc = ws + o; o += (size_t)hc * 2097152;
  u16* Kc = ws + o; o += (size_t)hc * 2097152;
  u16* Vc = ws + o; o += (size_t)hc * 2097152;   // V^T [B,hc,D,L]
  u16* Oc = ws + o;

  ingest_kernel<<<dim3(2054), 256, 0, stream>>>(seq, g1, be1, b1, b2, g2, be2,
                                                sbuf, vecs);
  pack_kernel<<<dim3(256, 6), 256, 0, stream>>>(Wq, Wk, Wv, Wo, W1, W2, seq,
                                                pWq, pWk, pWv, pWo, pW1, pW2);
  if (hc == 8) {
    // single-chunk fast path: fused accum+LN1, no f32 att buffer
    qkv_kernel<<<dim3(16, 64, 3), 256, 0, stream>>>(
        sbuf, pWq, pWk, pWv, Qc, Kc, Vc, 0, 8);
    attn_kernel<<<dim3(32 * 16), 256, 0, stream>>>(Qc, Kc, Vc, Oc, 32);
    accum_ln1_kernel<<<dim3(256), 128, 0, stream>>>(Oc, pWo, sbuf, vecs, xb);
  } else {
    hipMemsetAsync(att, 0, 2097152 * sizeof(float), stream);
    int nchunks = 8 / hc;
    for (int c = 0; c < nchunks; c++) {
      int nbh = 4 * hc;
      qkv_kernel<<<dim3(2 * hc, 64, 3), 256, 0, stream>>>(
          sbuf, pWq, pWk, pWv, Qc, Kc, Vc, c * hc * 16, hc);
      attn_kernel<<<dim3(nbh * 16), 256, 0, stream>>>(Qc, Kc, Vc, Oc, nbh);
      accum_kernel<<<dim3(128), 256, 0, stream>>>(Oc, pWo, att, c * hc * 8, hc);
    }
    ln1_kernel<<<dim3(2048), 256, 0, stream>>>(att, sbuf, vecs, xb);
  }
  ffn_ln2_kernel<<<dim3(256), 128, 0, stream>>>(xb, pW1, pW2, vecs, seq,
                                                (void*)d_out);
}

// Round 9
// 342.280 us; speedup vs baseline: 1.4472x; 1.0098x over previous
//
#include <hip/hip_runtime.h>

// ---------------------------------------------------------------------------
// TransformerEncoderLayer on MI355X (gfx950).  B=4 L=2048 D=256 H=8 FF=128.
// Input dtype (fp32 vs bf16) detected at runtime; compute bf16 MFMA, fp32 acc.
// Layouts: A[m=lane&15][k=8*(lane>>4)+j], B[k=8*(lane>>4)+j][n=lane&15],
//          C/D[row=(lane>>4)*4+r][col=lane&15]
// R3: V pre-transposed [B,h,D,L].  R8: 128 q/block, XCD swizzle.
// R12: transposed dataflow (S^T = K Q^T, O^T = V^T P^T), per-lane softmax.
// R13: STATIC-MAX softmax; accum+LN1 fused.
// R16: bare v_exp_f32 + v_cvt_pk_bf16_f32 softmax: 198->177us.
// R18: P redistribution in registers via permlane32/16_swap: 177->173us.
// R19: softmax scale folded into Q (attn 173->169).
// R20/R21: non-attn probes (spread, dbuf, A-prefetch): -3us combined.
// R22: REGIME-BASED occupancy revert.  R13(4w/SIMD)->R14(2w/SIMD) was
//      neutral when softmax-VALU-serial was binding; R16/18/19 removed that
//      constraint and the residual is now ~40% latency/sync at 2 waves/SIMD.
//      Port the cheap softmax onto the 8-wave structure (1 q-tile/wave,
//      512 thr): 128 combined regs/wave (R13 measured 64+64) -> 4 waves/SIMD,
//      LDS 64KB (no plds) -> 2 blocks/CU.  MFMA demand unchanged; latency
//      hiding doubles.  launch_bounds(512,4) pins the register budget.
// ---------------------------------------------------------------------------

typedef unsigned short u16;
typedef unsigned int   u32;
typedef __bf16 bf16x8 __attribute__((ext_vector_type(8)));
typedef __bf16 bf16x2 __attribute__((ext_vector_type(2)));
typedef float  f32x4  __attribute__((ext_vector_type(4)));

#define MFMA(a, b, c) __builtin_amdgcn_mfma_f32_16x16x32_bf16(a, b, c, 0, 0, 0)

#if __has_builtin(__builtin_amdgcn_exp2f)
#define EXP2(x) __builtin_amdgcn_exp2f(x)
#else
#define EXP2(x) exp2f(x)
#endif

#if __has_builtin(__builtin_amdgcn_permlane16_swap) && \
    __has_builtin(__builtin_amdgcn_permlane32_swap)
#define HAS_PERMSWAP 1
#else
#define HAS_PERMSWAP 0
#endif

// softmax scale * log2(e), folded into Q at projection time (R19)
#define CEXP 0.09016844f

__device__ __forceinline__ float b2f(u16 h) {
  return __uint_as_float(((u32)h) << 16);
}
__device__ __forceinline__ u16 f2b(float f) {
  u32 u = __float_as_uint(f);
  u += 0x7FFFu + ((u >> 16) & 1u);   // round-to-nearest-even
  return (u16)(u >> 16);
}
// packed f32x2 -> bf16x2 (RTNE); gfx950 backend emits v_cvt_pk_bf16_f32
__device__ __forceinline__ u32 pkbf(float lo, float hi) {
  bf16x2 v;
  v[0] = (__bf16)lo;
  v[1] = (__bf16)hi;
  return __builtin_bit_cast(u32, v);
}
__device__ __forceinline__ bf16x8 ldb8(const u16* p) { return *(const bf16x8*)p; }

typedef const __attribute__((address_space(1))) u32* gas1_t;
typedef __attribute__((address_space(3))) u32* las3_t;
__device__ __forceinline__ void gload_lds16(const u16* g, u16* lds_base) {
  __builtin_amdgcn_global_load_lds((gas1_t)(const void*)g,
                                   (las3_t)(void*)lds_base, 16, 0, 0);
}

__device__ __forceinline__ int detect_f32(const void* seq) {
  const u32* s = (const u32*)seq;
  int cnt = 0;
  #pragma unroll
  for (int i = 0; i < 64; i++) {
    u32 e = (s[i] >> 7) & 0xFFu;
    cnt += (e >= 100u && e <= 140u) ? 1 : 0;
  }
  return cnt < 48;  // 1 => fp32
}

__device__ __forceinline__ u16 ldw(const void* W, size_t idx, int isf32) {
  return isf32 ? f2b(((const float*)W)[idx]) : ((const u16*)W)[idx];
}

#if HAS_PERMSWAP
// softmax for one q-tile: p = 2^s (scale pre-folded into Q); accumulate
// per-lane l; return PV B-operand fragment in registers via permlane swaps.
__device__ __forceinline__ bf16x8 softmax_pa(f32x4 sn0, f32x4 sn1,
                                             float& lsum) {
  float p00 = EXP2(sn0[0]), p01 = EXP2(sn0[1]);
  float p02 = EXP2(sn0[2]), p03 = EXP2(sn0[3]);
  float p10 = EXP2(sn1[0]), p11 = EXP2(sn1[1]);
  float p12 = EXP2(sn1[2]), p13 = EXP2(sn1[3]);
  lsum += ((p00 + p01) + (p02 + p03)) + ((p10 + p11) + (p12 + p13));
  u32 A0 = pkbf(p00, p01), A1 = pkbf(p02, p03);
  u32 B0 = pkbf(p10, p11), B1 = pkbf(p12, p13);
  auto ra = __builtin_amdgcn_permlane32_swap(A0, B0, false, false);
  auto rb = __builtin_amdgcn_permlane32_swap(A1, B1, false, false);
  auto sa = __builtin_amdgcn_permlane16_swap(ra[0], ra[1], false, false);
  auto sb = __builtin_amdgcn_permlane16_swap(rb[0], rb[1], false, false);
  uint4 wv;
  wv.x = sa[0];  // keys 8Q+0,1
  wv.y = sb[0];  // keys 8Q+2,3
  wv.z = sa[1];  // keys 8Q+4,5
  wv.w = sb[1];  // keys 8Q+6,7
  return __builtin_bit_cast(bf16x8, wv);
}
#endif

// ---------------------------------------------------------------------------
// Ingest: canonicalize seq (2M elems) + 6 small vectors to bf16 in ws.
// ---------------------------------------------------------------------------
__global__ __launch_bounds__(256) void ingest_kernel(
    const void* __restrict__ seq, const void* __restrict__ g1,
    const void* __restrict__ be1, const void* __restrict__ b1,
    const void* __restrict__ b2v, const void* __restrict__ g2,
    const void* __restrict__ be2, u16* __restrict__ sbuf,
    u16* __restrict__ vecs) {
  int isf32 = detect_f32(seq);
  int bx = blockIdx.x, tid = threadIdx.x;
  if (bx < 2048) {
    size_t i = (size_t)bx * 1024 + tid * 4;
    if (isf32) {
      const float* sp = (const float*)seq;
      u16 o0 = f2b(sp[i]), o1 = f2b(sp[i + 1]), o2 = f2b(sp[i + 2]), o3 = f2b(sp[i + 3]);
      uint2 ov; ov.x = (u32)o0 | ((u32)o1 << 16); ov.y = (u32)o2 | ((u32)o3 << 16);
      *(uint2*)(sbuf + i) = ov;
    } else {
      *(uint2*)(sbuf + i) = ((const uint2*)seq)[i >> 2];
    }
  } else {
    int t = bx - 2048;
    const void* src; int n;
    switch (t) {
      case 0: src = g1;  n = 256; break;
      case 1: src = be1; n = 256; break;
      case 2: src = b1;  n = 128; break;
      case 3: src = b2v; n = 256; break;
      case 4: src = g2;  n = 256; break;
      default: src = be2; n = 256; break;
    }
    if (tid < n) vecs[t * 256 + tid] = ldw(src, tid, isf32);
  }
}

// ---------------------------------------------------------------------------
// Pack weights into B-fragment-linear layout.  grid (256, 6), 256 thr.
// ---------------------------------------------------------------------------
__global__ __launch_bounds__(256) void pack_kernel(
    const void* __restrict__ Wq, const void* __restrict__ Wk,
    const void* __restrict__ Wv, const void* __restrict__ Wo,
    const void* __restrict__ W1, const void* __restrict__ W2,
    const void* __restrict__ seq,
    u16* __restrict__ pWq, u16* __restrict__ pWk, u16* __restrict__ pWv,
    u16* __restrict__ pWo, u16* __restrict__ pW1, u16* __restrict__ pW2) {
  int isf32 = detect_f32(seq);
  const void* W; u16* P; int K, N;
  switch (blockIdx.y) {
    case 0: W = Wq; P = pWq; K = 256;  N = 2048; break;
    case 1: W = Wk; P = pWk; K = 256;  N = 2048; break;
    case 2: W = Wv; P = pWv; K = 256;  N = 2048; break;
    case 3: W = Wo; P = pWo; K = 2048; N = 256;  break;
    case 4: W = W1; P = pW1; K = 256;  N = 128;  break;
    default: W = W2; P = pW2; K = 128; N = 256;  break;
  }
  int t = blockIdx.x * 256 + threadIdx.x;
  int total = (K >> 5) * (N >> 4) * 64;
  if (t >= total) return;
  int lane = t & 63, f = t >> 6;
  int NT = N >> 4;
  int kt = f / NT, nt = f - kt * NT;
  int row0 = kt * 32 + ((lane >> 4) << 3);
  int col = nt * 16 + (lane & 15);
  u16 e[8];
  #pragma unroll
  for (int j = 0; j < 8; j++) e[j] = ldw(W, (size_t)(row0 + j) * N + col, isf32);
  uint4 u;
  u.x = (u32)e[0] | ((u32)e[1] << 16);
  u.y = (u32)e[2] | ((u32)e[3] << 16);
  u.z = (u32)e[4] | ((u32)e[5] << 16);
  u.w = (u32)e[6] | ((u32)e[7] << 16);
  *(uint4*)(P + ((size_t)f * 64 + lane) * 8) = u;
}

// ---------------------------------------------------------------------------
// QKV projection for one h-chunk: X(8192x256) @ W(256, hc*256).
// Q,K -> [B,hc,L,D]; V -> transposed [B,hc,D,L].  Coalesced 16B stores via
// LDS transpose.  grid (2*hc, 64, 3), 256 threads.
// R21: A-fragments prefetched to regs before the staging drain.
// ---------------------------------------------------------------------------
__global__ __launch_bounds__(256, 2) void qkv_kernel(
    const u16* __restrict__ X,
    const u16* __restrict__ pWq, const u16* __restrict__ pWk,
    const u16* __restrict__ pWv,
    u16* __restrict__ Qo, u16* __restrict__ Ko, u16* __restrict__ Vo,
    int ntbase, int hc) {
  __shared__ u16 blds[64 * 512];
  const u16* Pw = (blockIdx.z == 0) ? pWq : ((blockIdx.z == 1) ? pWk : pWv);
  u16* Out = (blockIdx.z == 0) ? Qo : ((blockIdx.z == 1) ? Ko : Vo);
  int tid = threadIdx.x, lane = tid & 63, w = tid >> 6;
  int nt0 = ntbase + blockIdx.x * 8;
  int m0 = blockIdx.y * 128 + w * 32;
  // R21: issue all 16 A-loads first; they drain with the weight staging.
  bf16x8 af[2][8];
  #pragma unroll
  for (int kt = 0; kt < 8; kt++) {
    af[0][kt] = ldb8(X + (size_t)(m0 + (lane & 15)) * 256 + kt * 32 + (lane >> 4) * 8);
    af[1][kt] = ldb8(X + (size_t)(m0 + 16 + (lane & 15)) * 256 + kt * 32 + (lane >> 4) * 8);
  }
  // async weight staging: frag fl = w + i*4; dst = blds + fl*512
  #pragma unroll
  for (int i = 0; i < 16; i++) {
    int fl = w + i * 4;
    int kt = fl >> 3, nt = fl & 7;
    gload_lds16(Pw + ((size_t)(kt * 128 + nt0 + nt) * 64 + lane) * 8,
                blds + (size_t)fl * 512);
  }
  asm volatile("s_waitcnt vmcnt(0)" ::: "memory");
  __syncthreads();
  f32x4 acc[2][8] = {};
  #pragma unroll
  for (int kt = 0; kt < 8; kt++) {
    const u16* bp = blds + (size_t)kt * 8 * 512 + (size_t)lane * 8;
    #pragma unroll
    for (int nt = 0; nt < 8; nt++) {
      bf16x8 b = ldb8(bp + nt * 512);
      acc[0][nt] = MFMA(af[0][kt], b, acc[0][nt]);
      acc[1][nt] = MFMA(af[1][kt], b, acc[1][nt]);
    }
  }
  int isv = (blockIdx.z == 2);
  float sc = (blockIdx.z == 0) ? CEXP : 1.0f;   // R19: fold softmax scale into Q
  int hl = blockIdx.x >> 1;
  int dd0 = (blockIdx.x & 1) * 128;
  int m0b = blockIdx.y * 128;
  int bi = m0b >> 11, l0 = m0b & 2047;
  __syncthreads();
  if (!isv) {
    #pragma unroll
    for (int mt = 0; mt < 2; mt++)
      #pragma unroll
      for (int nt = 0; nt < 8; nt++)
        #pragma unroll
        for (int r = 0; r < 4; r++)
          blds[(w * 32 + mt * 16 + (lane >> 4) * 4 + r) * 136 + nt * 16 + (lane & 15)] =
              f2b(acc[mt][nt][r] * sc);
    __syncthreads();
    #pragma unroll
    for (int i = 0; i < 8; i++) {
      int c = tid + i * 256;
      int mloc = c >> 4, q = c & 15;
      uint4 v = *(uint4*)(blds + mloc * 136 + q * 8);
      *(uint4*)(Out + ((size_t)(bi * hc + hl) * 2048 + l0 + mloc) * 256 + dd0 + q * 8) = v;
    }
  } else {
    #pragma unroll
    for (int mt = 0; mt < 2; mt++)
      #pragma unroll
      for (int nt = 0; nt < 8; nt++)
        #pragma unroll
        for (int r = 0; r < 4; r++)
          blds[(nt * 16 + (lane & 15)) * 136 + w * 32 + mt * 16 + (lane >> 4) * 4 + r] =
              f2b(acc[mt][nt][r]);
    __syncthreads();
    #pragma unroll
    for (int i = 0; i < 8; i++) {
      int c = tid + i * 256;
      int nloc = c >> 4, q = c & 15;
      uint4 v = *(uint4*)(blds + nloc * 136 + q * 8);
      *(uint4*)(Out + ((size_t)(bi * hc + hl) * 256 + dd0 + nloc) * 2048 + l0 + q * 8) = v;
    }
  }
}

// ---------------------------------------------------------------------------
// Flash attention, transposed dataflow, STATIC-MAX softmax.
// R22: 8 waves x 16 q (1 q-tile/wave), 512 thr — 4 waves/SIMD for latency
// hiding now that softmax is cheap (R16/R18/R19 ported).  K+V double-
// buffered, ONE barrier/iter.  grid (nbh*16), 128 q/block;
// LDS 65536 B -> 2 blocks/CU (16 waves/CU).
// ---------------------------------------------------------------------------
__global__ __launch_bounds__(512, 4) void attn_kernel(
    const u16* __restrict__ Q, const u16* __restrict__ K,
    const u16* __restrict__ Vt, u16* __restrict__ O, int nbh) {
  __shared__ u16 kbuf[2 * 8192];   // 2 bufs x 16 frags x 512 u16 (frag-linear)
  __shared__ u16 vbuf[2 * 8192];
#if !HAS_PERMSWAP
  __shared__ u16 plds[8 * 640];    // per-wave P [16 q][40] (fallback path)
#endif
  int tid = threadIdx.x, lane = tid & 63, w = tid >> 6;
  int bi2 = blockIdx.x;
  int bh, qt;
  if (nbh >= 8) {
    int G = nbh >> 3;
    bh = (bi2 & 7) * G + (bi2 >> 3) % G;
    qt = bi2 / (8 * G);
  } else {
    bh = bi2 % nbh; qt = bi2 / nbh;
  }
  const u16* Qb  = Q  + (size_t)bh * 2048 * 256;
  const u16* Kb  = K  + (size_t)bh * 2048 * 256;
  const u16* Vtb = Vt + (size_t)bh * 256 * 2048;
  u16* Ob = O + (size_t)bh * 2048 * 256;
  int q0 = qt * 128 + w * 16;
  bf16x8 qf[8];   // B-operand: n=q=lane&15, k=d
  #pragma unroll
  for (int kt = 0; kt < 8; kt++)
    qf[kt] = ldb8(Qb + (size_t)(q0 + (lane & 15)) * 256 + kt * 32 + (lane >> 4) * 8);
  f32x4 o[16] = {};                // O^T: [d=16nt+4quad+r][q=lane&15]
  float lsum = 0.f;                // per-lane partial sum of p
#if !HAS_PERMSWAP
  u16* pl = plds + (size_t)w * 640;
#endif

  // pre-loop: issue K(0), V(0) into buffer 0 (8 waves x 2 frags = 16)
  #pragma unroll
  for (int j = 0; j < 2; j++) {
    int f = w * 2 + j;
    gload_lds16(Kb + (size_t)((f >> 3) * 16 + (lane & 15)) * 256 +
                    (f & 7) * 32 + (lane >> 4) * 8,
                kbuf + f * 512);
    gload_lds16(Vtb + (size_t)(f * 16 + (lane & 15)) * 2048 + (lane >> 4) * 8,
                vbuf + f * 512);
  }

  for (int t = 0; t < 64; t++) {
    int s0i = t * 32;
    // ONE barrier: K(t),V(t) (issued a full iteration ago) landed.
    asm volatile("s_waitcnt vmcnt(0)\ns_barrier" ::: "memory");
    if (t < 63) {
      int nb = (t + 1) & 1;
      #pragma unroll
      for (int j = 0; j < 2; j++) {
        int f = w * 2 + j;
        gload_lds16(Kb + (size_t)(s0i + 32 + (f >> 3) * 16 + (lane & 15)) * 256 +
                        (f & 7) * 32 + (lane >> 4) * 8,
                    kbuf + nb * 8192 + f * 512);
        gload_lds16(Vtb + (size_t)(f * 16 + (lane & 15)) * 2048 + s0i + 32 +
                        (lane >> 4) * 8,
                    vbuf + nb * 8192 + f * 512);
      }
    }
    // S^T = K Q^T: A = K frag (m=key,k=d), B = qf (k=d,n=q).
    const u16* kb = kbuf + (t & 1) * 8192;
    f32x4 s[2] = {};
    __builtin_amdgcn_s_setprio(1);
    #pragma unroll
    for (int ntk = 0; ntk < 2; ntk++)
      #pragma unroll
      for (int kt = 0; kt < 8; kt++) {
        bf16x8 a = ldb8(kb + (size_t)(ntk * 8 + kt) * 512 + lane * 8);
        s[ntk] = MFMA(a, qf[kt], s[ntk]);
      }
    __builtin_amdgcn_s_setprio(0);
#if HAS_PERMSWAP
    // static-max softmax + in-register P redistribution (no LDS roundtrip)
    bf16x8 pa = softmax_pa(s[0], s[1], lsum);
#else
    // fallback: softmax via plds roundtrip
    #pragma unroll
    for (int ntk = 0; ntk < 2; ntk++) {
      float p0 = EXP2(s[ntk][0]);
      float p1 = EXP2(s[ntk][1]);
      float p2 = EXP2(s[ntk][2]);
      float p3 = EXP2(s[ntk][3]);
      lsum += (p0 + p1) + (p2 + p3);
      uint2 pk;
      pk.x = pkbf(p0, p1);
      pk.y = pkbf(p2, p3);
      *(uint2*)(pl + (lane & 15) * 40 + 16 * ntk + 4 * (lane >> 4)) = pk;
    }
    asm volatile("s_waitcnt lgkmcnt(0)" ::: "memory");
    bf16x8 pa = ldb8(pl + (lane & 15) * 40 + (lane >> 4) * 8);
    asm volatile("s_waitcnt lgkmcnt(0)" ::: "memory");
#endif
    // ---- O^T += V^T P^T: A = V frag (m=d,k=key) ----
    const u16* vb0 = vbuf + (t & 1) * 8192;
    __builtin_amdgcn_s_setprio(1);
    #pragma unroll
    for (int nt = 0; nt < 16; nt++) {
      bf16x8 vb = ldb8(vb0 + (size_t)nt * 512 + lane * 8);
      o[nt] = MFMA(vb, pa, o[nt]);
    }
    __builtin_amdgcn_s_setprio(0);
  }
  // final l reduction: sum partials across the 4 quads of this q
  float l = lsum;
  l += __shfl_xor(l, 16);
  l += __shfl_xor(l, 32);
  float linv = 1.0f / l;
  // ---- epilogue: o is O^T [d][q]; transpose via kbuf, b128 writes ----
  u16* el = kbuf + w * 1152;             // per-wave [16 q][72]
  __syncthreads();
  #pragma unroll
  for (int g = 0; g < 4; g++) {
    if (g) asm volatile("s_waitcnt lgkmcnt(0)" ::: "memory");
    #pragma unroll
    for (int t2 = 0; t2 < 4; t2++) {
      int nt = g * 4 + t2;
      uint2 pk;
      pk.x = pkbf(o[nt][0] * linv, o[nt][1] * linv);
      pk.y = pkbf(o[nt][2] * linv, o[nt][3] * linv);
      *(uint2*)(el + (lane & 15) * 72 + t2 * 16 + 4 * (lane >> 4)) = pk;
    }
    asm volatile("s_waitcnt lgkmcnt(0)" ::: "memory");
    #pragma unroll
    for (int rep = 0; rep < 2; rep++) {
      int ch = lane + rep * 64;          // 128 chunks: 16 q-rows x 8
      int row = ch >> 3, c8 = ch & 7;
      uint4 v = *(uint4*)(el + row * 72 + c8 * 8);
      *(uint4*)(Ob + (size_t)(q0 + row) * 256 + g * 64 + c8 * 8) = v;
    }
  }
}

// ---------------------------------------------------------------------------
// Fused (hc==8): x = LN1(seq + O @ Wo).  grid (256), 128 thr (2 waves x 16
// complete rows); Wo staging K-step=2, double-buffered; A-loads hoisted.
// ---------------------------------------------------------------------------
__global__ __launch_bounds__(128) void accum_ln1_kernel(
    const u16* __restrict__ Oc, const u16* __restrict__ pWo,
    const u16* __restrict__ sbuf, const u16* __restrict__ vecs,
    u16* __restrict__ xout) {
  __shared__ u16 blds[2 * 32 * 512];   // 2 bufs x (2 kt x 16 nt) frags
  int tid = threadIdx.x, lane = tid & 63, w = tid >> 6;   // w in {0,1}
  int m0 = blockIdx.x * 32 + w * 16;
  int arow = m0 + (lane & 15);
  int bq = arow >> 11, lrow = arow & 2047;
  f32x4 acc[16] = {};
  // prologue: stage round 0 (kt 0,1) into buf 0
  #pragma unroll
  for (int i = 0; i < 16; i++) {
    int fl = w + i * 2;                // 32 frags across 2 waves
    int ktg = fl >> 4, nt = fl & 15;
    gload_lds16(pWo + ((size_t)(ktg * 16 + nt) * 64 + lane) * 8,
                blds + (size_t)fl * 512);
  }
  asm volatile("s_waitcnt vmcnt(0)" ::: "memory");
  __syncthreads();
  for (int r = 0; r < 32; r++) {
    int k0 = r * 2;
    const u16* cur = blds + (size_t)(r & 1) * 16384;
    // A loads first (issue right after barrier; land under stage+ds)
    bf16x8 aA, aB;
    {
      int ktl = k0, hl = ktl >> 3;
      int d0 = (ktl & 7) * 32 + (lane >> 4) * 8;
      aA = ldb8(Oc + ((size_t)(bq * 8 + hl) * 2048 + lrow) * 256 + d0);
      ktl = k0 + 1; hl = ktl >> 3;
      d0 = (ktl & 7) * 32 + (lane >> 4) * 8;
      aB = ldb8(Oc + ((size_t)(bq * 8 + hl) * 2048 + lrow) * 256 + d0);
    }
    if (r < 31) {
      u16* nxt = blds + (size_t)((r + 1) & 1) * 16384;
      #pragma unroll
      for (int i = 0; i < 16; i++) {
        int fl = w + i * 2;
        int ktg = k0 + 2 + (fl >> 4), nt = fl & 15;
        gload_lds16(pWo + ((size_t)(ktg * 16 + nt) * 64 + lane) * 8,
                    nxt + (size_t)fl * 512);
      }
    }
    #pragma unroll
    for (int kl = 0; kl < 2; kl++) {
      bf16x8 a = kl ? aB : aA;
      const u16* bp = cur + (size_t)kl * 16 * 512 + (size_t)lane * 8;
      #pragma unroll
      for (int nt = 0; nt < 16; nt++) {
        bf16x8 b = ldb8(bp + nt * 512);
        acc[nt] = MFMA(a, b, acc[nt]);
      }
    }
    asm volatile("s_waitcnt vmcnt(0)" ::: "memory");
    __syncthreads();
  }
  int rbase = m0 + (lane >> 4) * 4;
  #pragma unroll
  for (int nt = 0; nt < 16; nt++) {
    int d = nt * 16 + (lane & 15);
    #pragma unroll
    for (int r = 0; r < 4; r++)
      acc[nt][r] += b2f(sbuf[(size_t)(rbase + r) * 256 + d]);
  }
  float mu[4], rs[4];
  #pragma unroll
  for (int r = 0; r < 4; r++) {
    float sm = 0.f;
    #pragma unroll
    for (int nt = 0; nt < 16; nt++) sm += acc[nt][r];
    sm += __shfl_xor(sm, 1); sm += __shfl_xor(sm, 2);
    sm += __shfl_xor(sm, 4); sm += __shfl_xor(sm, 8);
    mu[r] = sm * (1.0f / 256.0f);
    float v = 0.f;
    #pragma unroll
    for (int nt = 0; nt < 16; nt++) { float dd = acc[nt][r] - mu[r]; v += dd * dd; }
    v += __shfl_xor(v, 1); v += __shfl_xor(v, 2);
    v += __shfl_xor(v, 4); v += __shfl_xor(v, 8);
    rs[r] = rsqrtf(v * (1.0f / 256.0f) + 1e-5f);
  }
  #pragma unroll
  for (int nt = 0; nt < 16; nt++) {
    int d = nt * 16 + (lane & 15);
    float gg = b2f(vecs[d]), bb = b2f(vecs[256 + d]);
    #pragma unroll
    for (int r = 0; r < 4; r++)
      xout[(size_t)(rbase + r) * 256 + d] = f2b((acc[nt][r] - mu[r]) * rs[r] * gg + bb);
  }
}

// ---------------------------------------------------------------------------
// Fallback (hc<8): att_out(f32) += O_chunk @ Wo_chunk.  grid (128), 256 thr.
// ---------------------------------------------------------------------------
__global__ __launch_bounds__(256) void accum_kernel(
    const u16* __restrict__ Oc, const u16* __restrict__ pWo,
    float* __restrict__ att_out, int kt0, int hc) {
  __shared__ u16 blds[64 * 512];
  int tid = threadIdx.x, lane = tid & 63, w = tid >> 6;
  int m0 = blockIdx.x * 64 + w * 16;
  int arow = m0 + (lane & 15);
  int bq = arow >> 11, lrow = arow & 2047;
  int ktn = hc * 8;
  f32x4 acc[16] = {};
  for (int k0 = 0; k0 < ktn; k0 += 4) {
    __syncthreads();
    #pragma unroll
    for (int i = 0; i < 16; i++) {
      int fl = w + i * 4;
      int ktg = kt0 + k0 + (fl >> 4), nt = fl & 15;
      gload_lds16(pWo + ((size_t)(ktg * 16 + nt) * 64 + lane) * 8,
                  blds + (size_t)fl * 512);
    }
    asm volatile("s_waitcnt vmcnt(0)" ::: "memory");
    __syncthreads();
    #pragma unroll
    for (int kl = 0; kl < 4; kl++) {
      int ktl = k0 + kl;
      int hl = ktl >> 3;
      int d0 = (ktl & 7) * 32 + (lane >> 4) * 8;
      bf16x8 a = ldb8(Oc + ((size_t)(bq * hc + hl) * 2048 + lrow) * 256 + d0);
      const u16* bp = blds + (size_t)kl * 16 * 512 + (size_t)lane * 8;
      #pragma unroll
      for (int nt = 0; nt < 16; nt++) {
        bf16x8 b = ldb8(bp + nt * 512);
        acc[nt] = MFMA(a, b, acc[nt]);
      }
    }
  }
  int rbase = m0 + (lane >> 4) * 4;
  #pragma unroll
  for (int nt = 0; nt < 16; nt++) {
    int d = nt * 16 + (lane & 15);
    #pragma unroll
    for (int r = 0; r < 4; r++)
      att_out[(size_t)(rbase + r) * 256 + d] += acc[nt][r];
  }
}

// ---------------------------------------------------------------------------
// x = LN1(seq + att_out).  grid (2048), 256 threads; fallback path only.
// ---------------------------------------------------------------------------
__global__ __launch_bounds__(256) void ln1_kernel(
    const float* __restrict__ att_out, const u16* __restrict__ sbuf,
    const u16* __restrict__ vecs, u16* __restrict__ xout) {
  int tid = threadIdx.x, lane = tid & 63, w = tid >> 6;
  int row = blockIdx.x * 4 + w;
  const float* ar = att_out + (size_t)row * 256;
  f32x4 a = *(const f32x4*)(ar + lane * 4);
  uint2 sv = *(const uint2*)(sbuf + (size_t)row * 256 + lane * 4);
  float y[4];
  y[0] = a[0] + b2f((u16)(sv.x & 0xFFFF));
  y[1] = a[1] + b2f((u16)(sv.x >> 16));
  y[2] = a[2] + b2f((u16)(sv.y & 0xFFFF));
  y[3] = a[3] + b2f((u16)(sv.y >> 16));
  float sm = y[0] + y[1] + y[2] + y[3];
  sm += __shfl_xor(sm, 1);  sm += __shfl_xor(sm, 2);  sm += __shfl_xor(sm, 4);
  sm += __shfl_xor(sm, 8);  sm += __shfl_xor(sm, 16); sm += __shfl_xor(sm, 32);
  float mu = sm * (1.0f / 256.0f);
  float v = 0.f;
  #pragma unroll
  for (int j = 0; j < 4; j++) { float d = y[j] - mu; v += d * d; }
  v += __shfl_xor(v, 1);  v += __shfl_xor(v, 2);  v += __shfl_xor(v, 4);
  v += __shfl_xor(v, 8);  v += __shfl_xor(v, 16); v += __shfl_xor(v, 32);
  float rs = rsqrtf(v * (1.0f / 256.0f) + 1e-5f);
  u16 o[4];
  #pragma unroll
  for (int j = 0; j < 4; j++) {
    int d = lane * 4 + j;
    o[j] = f2b((y[j] - mu) * rs * b2f(vecs[d]) + b2f(vecs[256 + d]));
  }
  uint2 ov; ov.x = (u32)o[0] | ((u32)o[1] << 16); ov.y = (u32)o[2] | ((u32)o[3] << 16);
  *(uint2*)(xout + (size_t)row * 256 + lane * 4) = ov;
}

// ---------------------------------------------------------------------------
// FFN + LN2.  out = LN2(x + relu(x@W1+b1)@W2 + b2).
// grid (256), 128 thr (2 waves x 16 complete rows) — full-GPU spread.
// ---------------------------------------------------------------------------
__global__ __launch_bounds__(128) void ffn_ln2_kernel(
    const u16* __restrict__ x, const u16* __restrict__ pW1,
    const u16* __restrict__ pW2, const u16* __restrict__ vecs,
    const void* __restrict__ seq, void* __restrict__ out) {
  __shared__ u16 hbuf[2 * 16 * 136];
  int isf32 = detect_f32(seq);
  int tid = threadIdx.x, lane = tid & 63, w = tid >> 6;   // w in {0,1}
  int m0 = blockIdx.x * 32 + w * 16;
  int arow = m0 + (lane & 15);
  u16* hb = hbuf + w * 16 * 136;
  f32x4 acc1[8] = {};
  #pragma unroll
  for (int kt = 0; kt < 8; kt++) {
    bf16x8 a = ldb8(x + (size_t)arow * 256 + kt * 32 + (lane >> 4) * 8);
    const u16* bp = pW1 + ((size_t)kt * 8 * 64 + lane) * 8;
    #pragma unroll
    for (int nt = 0; nt < 8; nt++) {
      bf16x8 b = ldb8(bp + nt * 512);
      acc1[nt] = MFMA(a, b, acc1[nt]);
    }
  }
  #pragma unroll
  for (int nt = 0; nt < 8; nt++) {
    int col = nt * 16 + (lane & 15);
    float bb = b2f(vecs[512 + col]);
    #pragma unroll
    for (int r = 0; r < 4; r++) {
      float h = fmaxf(acc1[nt][r] + bb, 0.f);
      hb[((lane >> 4) * 4 + r) * 136 + col] = f2b(h);
    }
  }
  __syncthreads();
  f32x4 acc2[16] = {};
  #pragma unroll
  for (int ks = 0; ks < 4; ks++) {
    bf16x8 a = ldb8(hb + (lane & 15) * 136 + ks * 32 + (lane >> 4) * 8);
    const u16* bp = pW2 + ((size_t)ks * 16 * 64 + lane) * 8;
    #pragma unroll
    for (int nt = 0; nt < 16; nt++) {
      bf16x8 b = ldb8(bp + nt * 512);
      acc2[nt] = MFMA(a, b, acc2[nt]);
    }
  }
  int rbase = m0 + (lane >> 4) * 4;
  #pragma unroll
  for (int nt = 0; nt < 16; nt++) {
    int d = nt * 16 + (lane & 15);
    float bb = b2f(vecs[768 + d]);
    #pragma unroll
    for (int r = 0; r < 4; r++)
      acc2[nt][r] += bb + b2f(x[(size_t)(rbase + r) * 256 + d]);
  }
  float mu[4], rs[4];
  #pragma unroll
  for (int r = 0; r < 4; r++) {
    float sm = 0.f;
    #pragma unroll
    for (int nt = 0; nt < 16; nt++) sm += acc2[nt][r];
    sm += __shfl_xor(sm, 1); sm += __shfl_xor(sm, 2);
    sm += __shfl_xor(sm, 4); sm += __shfl_xor(sm, 8);
    mu[r] = sm * (1.0f / 256.0f);
    float v = 0.f;
    #pragma unroll
    for (int nt = 0; nt < 16; nt++) { float dd = acc2[nt][r] - mu[r]; v += dd * dd; }
    v += __shfl_xor(v, 1); v += __shfl_xor(v, 2);
    v += __shfl_xor(v, 4); v += __shfl_xor(v, 8);
    rs[r] = rsqrtf(v * (1.0f / 256.0f) + 1e-5f);
  }
  #pragma unroll
  for (int nt = 0; nt < 16; nt++) {
    int d = nt * 16 + (lane & 15);
    float gg = b2f(vecs[1024 + d]), bb = b2f(vecs[1280 + d]);
    #pragma unroll
    for (int r = 0; r < 4; r++) {
      float val = (acc2[nt][r] - mu[r]) * rs[r] * gg + bb;
      size_t idx = (size_t)(rbase + r) * 256 + d;
      if (isf32) ((float*)out)[idx] = val;
      else       ((u16*)out)[idx]   = f2b(val);
    }
  }
}

// ---------------------------------------------------------------------------
__global__ __launch_bounds__(256) void sentinel_kernel(void* out, int n,
                                                       const void* seq) {
  int isf32 = detect_f32(seq);
  int i = blockIdx.x * 256 + threadIdx.x;
  if (i < n) {
    if (isf32) ((float*)out)[i] = 777.0f;
    else       ((u16*)out)[i]   = 0x4442;
  }
}

// ---------------------------------------------------------------------------
extern "C" void kernel_launch(void* const* d_in, const int* in_sizes, int n_in,
                              void* d_out, int out_size, void* d_ws, size_t ws_size,
                              hipStream_t stream) {
  (void)in_sizes; (void)n_in;
  const void* seq  = d_in[0];
  const void* Wq   = d_in[1];
  const void* Wk   = d_in[2];
  const void* Wv   = d_in[3];
  const void* Wo   = d_in[4];
  const void* g1   = d_in[5];
  const void* be1  = d_in[6];
  const void* W1   = d_in[7];
  const void* b1   = d_in[8];
  const void* W2   = d_in[9];
  const void* b2   = d_in[10];
  const void* g2   = d_in[11];
  const void* be2  = d_in[12];

  size_t o = 0;
  u16* ws = (u16*)d_ws;
  u16* pWq = ws + o; o += 524288;
  u16* pWk = ws + o; o += 524288;
  u16* pWv = ws + o; o += 524288;
  u16* pWo = ws + o; o += 524288;
  u16* pW1 = ws + o; o += 32768;
  u16* pW2 = ws + o; o += 32768;
  float* att = (float*)(ws + o); o += 4194304;   // 2M f32 (fallback path)
  u16* xb   = ws + o; o += 2097152;
  u16* sbuf = ws + o; o += 2097152;
  u16* vecs = ws + o; o += 2048;
  size_t fixed_elems = o;

  int hc = 0;
  for (int c = 8; c >= 1; c >>= 1) {
    size_t need = (fixed_elems + (size_t)4 * c * 2097152) * 2;
    if (need <= ws_size) { hc = c; break; }
  }
  if (hc == 0) {
    sentinel_kernel<<<dim3((out_size + 255) / 256), 256, 0, stream>>>(
        d_out, out_size, seq);
    return;
  }
  u16* Qc = ws + o; o += (size_t)hc * 2097152;
  u16* Kc = ws + o; o += (size_t)hc * 2097152;
  u16* Vc = ws + o; o += (size_t)hc * 2097152;   // V^T [B,hc,D,L]
  u16* Oc = ws + o;

  ingest_kernel<<<dim3(2054), 256, 0, stream>>>(seq, g1, be1, b1, b2, g2, be2,
                                                sbuf, vecs);
  pack_kernel<<<dim3(256, 6), 256, 0, stream>>>(Wq, Wk, Wv, Wo, W1, W2, seq,
                                                pWq, pWk, pWv, pWo, pW1, pW2);
  if (hc == 8) {
    // single-chunk fast path: fused accum+LN1, no f32 att buffer
    qkv_kernel<<<dim3(16, 64, 3), 256, 0, stream>>>(
        sbuf, pWq, pWk, pWv, Qc, Kc, Vc, 0, 8);
    attn_kernel<<<dim3(32 * 16), 512, 0, stream>>>(Qc, Kc, Vc, Oc, 32);
    accum_ln1_kernel<<<dim3(256), 128, 0, stream>>>(Oc, pWo, sbuf, vecs, xb);
  } else {
    hipMemsetAsync(att, 0, 2097152 * sizeof(float), stream);
    int nchunks = 8 / hc;
    for (int c = 0; c < nchunks; c++) {
      int nbh = 4 * hc;
      qkv_kernel<<<dim3(2 * hc, 64, 3), 256, 0, stream>>>(
          sbuf, pWq, pWk, pWv, Qc, Kc, Vc, c * hc * 16, hc);
      attn_kernel<<<dim3(nbh * 16), 512, 0, stream>>>(Qc, Kc, Vc, Oc, nbh);
      accum_kernel<<<dim3(128), 256, 0, stream>>>(Oc, pWo, att, c * hc * 8, hc);
    }
    ln1_kernel<<<dim3(2048), 256, 0, stream>>>(att, sbuf, vecs, xb);
  }
  ffn_ln2_kernel<<<dim3(256), 128, 0, stream>>>(xb, pW1, pW2, vecs, seq,
                                                (void*)d_out);
}

// Round 10
// 341.846 us; speedup vs baseline: 1.4490x; 1.0013x over previous
//
#include <hip/hip_runtime.h>

// ---------------------------------------------------------------------------
// TransformerEncoderLayer on MI355X (gfx950).  B=4 L=2048 D=256 H=8 FF=128.
// Input dtype (fp32 vs bf16) detected at runtime; compute bf16 MFMA, fp32 acc.
// Layouts: A[m=lane&15][k=8*(lane>>4)+j], B[k=8*(lane>>4)+j][n=lane&15],
//          C/D[row=(lane>>4)*4+r][col=lane&15]
// R3: V pre-transposed [B,h,D,L].  R8: 128 q/block, XCD swizzle.
// R12: transposed dataflow (S^T = K Q^T, O^T = V^T P^T), per-lane softmax.
// R13: STATIC-MAX softmax; accum+LN1 fused.
// R16: bare v_exp_f32 + v_cvt_pk_bf16_f32 softmax: 198->177us.
// R18: P redistribution in registers via permlane32/16_swap: 177->173us.
// R19: softmax scale folded into Q (attn 173->169).
// R22: 8-wave/512-thr attn (4 waves/SIMD): 171->164.5us, occ 22->43%.
// R23: PIPELINE-GRAPH reduction.  Non-attn pool (178us) >> roofline work
//      (~60us) -> structural overhead of 6 dependent dispatches + the xb
//      global round-trip.  (a) ingest+pack fused (one dispatch, flat grid).
//      (b) accum_ln1+ffn_ln2 fused: identical 32-row/block partition; LN1
//      output kept in regs (residual) + LDS-transposed for the ffn A-frags;
//      xb never written to global (-12MB traffic, -2 launches).  Verified
//      math untouched; bf16 rounding of x preserved bit-exactly.
// ---------------------------------------------------------------------------

typedef unsigned short u16;
typedef unsigned int   u32;
typedef __bf16 bf16x8 __attribute__((ext_vector_type(8)));
typedef __bf16 bf16x2 __attribute__((ext_vector_type(2)));
typedef float  f32x4  __attribute__((ext_vector_type(4)));

#define MFMA(a, b, c) __builtin_amdgcn_mfma_f32_16x16x32_bf16(a, b, c, 0, 0, 0)

#if __has_builtin(__builtin_amdgcn_exp2f)
#define EXP2(x) __builtin_amdgcn_exp2f(x)
#else
#define EXP2(x) exp2f(x)
#endif

#if __has_builtin(__builtin_amdgcn_permlane16_swap) && \
    __has_builtin(__builtin_amdgcn_permlane32_swap)
#define HAS_PERMSWAP 1
#else
#define HAS_PERMSWAP 0
#endif

// softmax scale * log2(e), folded into Q at projection time (R19)
#define CEXP 0.09016844f

__device__ __forceinline__ float b2f(u16 h) {
  return __uint_as_float(((u32)h) << 16);
}
__device__ __forceinline__ u16 f2b(float f) {
  u32 u = __float_as_uint(f);
  u += 0x7FFFu + ((u >> 16) & 1u);   // round-to-nearest-even
  return (u16)(u >> 16);
}
// packed f32x2 -> bf16x2 (RTNE); gfx950 backend emits v_cvt_pk_bf16_f32
__device__ __forceinline__ u32 pkbf(float lo, float hi) {
  bf16x2 v;
  v[0] = (__bf16)lo;
  v[1] = (__bf16)hi;
  return __builtin_bit_cast(u32, v);
}
__device__ __forceinline__ bf16x8 ldb8(const u16* p) { return *(const bf16x8*)p; }

typedef const __attribute__((address_space(1))) u32* gas1_t;
typedef __attribute__((address_space(3))) u32* las3_t;
__device__ __forceinline__ void gload_lds16(const u16* g, u16* lds_base) {
  __builtin_amdgcn_global_load_lds((gas1_t)(const void*)g,
                                   (las3_t)(void*)lds_base, 16, 0, 0);
}

__device__ __forceinline__ int detect_f32(const void* seq) {
  const u32* s = (const u32*)seq;
  int cnt = 0;
  #pragma unroll
  for (int i = 0; i < 64; i++) {
    u32 e = (s[i] >> 7) & 0xFFu;
    cnt += (e >= 100u && e <= 140u) ? 1 : 0;
  }
  return cnt < 48;  // 1 => fp32
}

__device__ __forceinline__ u16 ldw(const void* W, size_t idx, int isf32) {
  return isf32 ? f2b(((const float*)W)[idx]) : ((const u16*)W)[idx];
}

#if HAS_PERMSWAP
// softmax for one q-tile: p = 2^s (scale pre-folded into Q); accumulate
// per-lane l; return PV B-operand fragment in registers via permlane swaps.
__device__ __forceinline__ bf16x8 softmax_pa(f32x4 sn0, f32x4 sn1,
                                             float& lsum) {
  float p00 = EXP2(sn0[0]), p01 = EXP2(sn0[1]);
  float p02 = EXP2(sn0[2]), p03 = EXP2(sn0[3]);
  float p10 = EXP2(sn1[0]), p11 = EXP2(sn1[1]);
  float p12 = EXP2(sn1[2]), p13 = EXP2(sn1[3]);
  lsum += ((p00 + p01) + (p02 + p03)) + ((p10 + p11) + (p12 + p13));
  u32 A0 = pkbf(p00, p01), A1 = pkbf(p02, p03);
  u32 B0 = pkbf(p10, p11), B1 = pkbf(p12, p13);
  auto ra = __builtin_amdgcn_permlane32_swap(A0, B0, false, false);
  auto rb = __builtin_amdgcn_permlane32_swap(A1, B1, false, false);
  auto sa = __builtin_amdgcn_permlane16_swap(ra[0], ra[1], false, false);
  auto sb = __builtin_amdgcn_permlane16_swap(rb[0], rb[1], false, false);
  uint4 wv;
  wv.x = sa[0];  // keys 8Q+0,1
  wv.y = sb[0];  // keys 8Q+2,3
  wv.z = sa[1];  // keys 8Q+4,5
  wv.w = sb[1];  // keys 8Q+6,7
  return __builtin_bit_cast(bf16x8, wv);
}
#endif

// ---------------------------------------------------------------------------
// Ingest body: canonicalize seq (2M elems) + 6 small vectors to bf16 in ws.
// ---------------------------------------------------------------------------
__device__ __forceinline__ void ingest_body(
    int bx, int tid, int isf32,
    const void* __restrict__ seq, const void* __restrict__ g1,
    const void* __restrict__ be1, const void* __restrict__ b1,
    const void* __restrict__ b2v, const void* __restrict__ g2,
    const void* __restrict__ be2, u16* __restrict__ sbuf,
    u16* __restrict__ vecs) {
  if (bx < 2048) {
    size_t i = (size_t)bx * 1024 + tid * 4;
    if (isf32) {
      const float* sp = (const float*)seq;
      u16 o0 = f2b(sp[i]), o1 = f2b(sp[i + 1]), o2 = f2b(sp[i + 2]), o3 = f2b(sp[i + 3]);
      uint2 ov; ov.x = (u32)o0 | ((u32)o1 << 16); ov.y = (u32)o2 | ((u32)o3 << 16);
      *(uint2*)(sbuf + i) = ov;
    } else {
      *(uint2*)(sbuf + i) = ((const uint2*)seq)[i >> 2];
    }
  } else {
    int t = bx - 2048;
    const void* src; int n;
    switch (t) {
      case 0: src = g1;  n = 256; break;
      case 1: src = be1; n = 256; break;
      case 2: src = b1;  n = 128; break;
      case 3: src = b2v; n = 256; break;
      case 4: src = g2;  n = 256; break;
      default: src = be2; n = 256; break;
    }
    if (tid < n) vecs[t * 256 + tid] = ldw(src, tid, isf32);
  }
}

// ---------------------------------------------------------------------------
// Pack body: weights into B-fragment-linear layout.  (px in [0,256), py in
// [0,6), 256 thr.)
// ---------------------------------------------------------------------------
__device__ __forceinline__ void pack_body(
    int px, int py, int tid, int isf32,
    const void* __restrict__ Wq, const void* __restrict__ Wk,
    const void* __restrict__ Wv, const void* __restrict__ Wo,
    const void* __restrict__ W1, const void* __restrict__ W2,
    u16* __restrict__ pWq, u16* __restrict__ pWk, u16* __restrict__ pWv,
    u16* __restrict__ pWo, u16* __restrict__ pW1, u16* __restrict__ pW2) {
  const void* W; u16* P; int K, N;
  switch (py) {
    case 0: W = Wq; P = pWq; K = 256;  N = 2048; break;
    case 1: W = Wk; P = pWk; K = 256;  N = 2048; break;
    case 2: W = Wv; P = pWv; K = 256;  N = 2048; break;
    case 3: W = Wo; P = pWo; K = 2048; N = 256;  break;
    case 4: W = W1; P = pW1; K = 256;  N = 128;  break;
    default: W = W2; P = pW2; K = 128; N = 256;  break;
  }
  int t = px * 256 + tid;
  int total = (K >> 5) * (N >> 4) * 64;
  if (t >= total) return;
  int lane = t & 63, f = t >> 6;
  int NT = N >> 4;
  int kt = f / NT, nt = f - kt * NT;
  int row0 = kt * 32 + ((lane >> 4) << 3);
  int col = nt * 16 + (lane & 15);
  u16 e[8];
  #pragma unroll
  for (int j = 0; j < 8; j++) e[j] = ldw(W, (size_t)(row0 + j) * N + col, isf32);
  uint4 u;
  u.x = (u32)e[0] | ((u32)e[1] << 16);
  u.y = (u32)e[2] | ((u32)e[3] << 16);
  u.z = (u32)e[4] | ((u32)e[5] << 16);
  u.w = (u32)e[6] | ((u32)e[7] << 16);
  *(uint4*)(P + ((size_t)f * 64 + lane) * 8) = u;
}

// ---------------------------------------------------------------------------
// R23: fused ingest + pack.  grid (2054 + 1536) = 3590, 256 thr.
// ---------------------------------------------------------------------------
__global__ __launch_bounds__(256) void ingest_pack_kernel(
    const void* __restrict__ seq, const void* __restrict__ g1,
    const void* __restrict__ be1, const void* __restrict__ b1,
    const void* __restrict__ b2v, const void* __restrict__ g2,
    const void* __restrict__ be2, u16* __restrict__ sbuf,
    u16* __restrict__ vecs,
    const void* __restrict__ Wq, const void* __restrict__ Wk,
    const void* __restrict__ Wv, const void* __restrict__ Wo,
    const void* __restrict__ W1, const void* __restrict__ W2,
    u16* __restrict__ pWq, u16* __restrict__ pWk, u16* __restrict__ pWv,
    u16* __restrict__ pWo, u16* __restrict__ pW1, u16* __restrict__ pW2) {
  int isf32 = detect_f32(seq);
  int bx = blockIdx.x, tid = threadIdx.x;
  if (bx < 2054) {
    ingest_body(bx, tid, isf32, seq, g1, be1, b1, b2v, g2, be2, sbuf, vecs);
  } else {
    int bxp = bx - 2054;
    pack_body(bxp & 255, bxp >> 8, tid, isf32, Wq, Wk, Wv, Wo, W1, W2,
              pWq, pWk, pWv, pWo, pW1, pW2);
  }
}

// ---------------------------------------------------------------------------
// QKV projection for one h-chunk: X(8192x256) @ W(256, hc*256).
// Q,K -> [B,hc,L,D]; V -> transposed [B,hc,D,L].  Coalesced 16B stores via
// LDS transpose.  grid (2*hc, 64, 3), 256 threads.
// R21: A-fragments prefetched to regs before the staging drain.
// ---------------------------------------------------------------------------
__global__ __launch_bounds__(256, 2) void qkv_kernel(
    const u16* __restrict__ X,
    const u16* __restrict__ pWq, const u16* __restrict__ pWk,
    const u16* __restrict__ pWv,
    u16* __restrict__ Qo, u16* __restrict__ Ko, u16* __restrict__ Vo,
    int ntbase, int hc) {
  __shared__ u16 blds[64 * 512];
  const u16* Pw = (blockIdx.z == 0) ? pWq : ((blockIdx.z == 1) ? pWk : pWv);
  u16* Out = (blockIdx.z == 0) ? Qo : ((blockIdx.z == 1) ? Ko : Vo);
  int tid = threadIdx.x, lane = tid & 63, w = tid >> 6;
  int nt0 = ntbase + blockIdx.x * 8;
  int m0 = blockIdx.y * 128 + w * 32;
  // R21: issue all 16 A-loads first; they drain with the weight staging.
  bf16x8 af[2][8];
  #pragma unroll
  for (int kt = 0; kt < 8; kt++) {
    af[0][kt] = ldb8(X + (size_t)(m0 + (lane & 15)) * 256 + kt * 32 + (lane >> 4) * 8);
    af[1][kt] = ldb8(X + (size_t)(m0 + 16 + (lane & 15)) * 256 + kt * 32 + (lane >> 4) * 8);
  }
  // async weight staging: frag fl = w + i*4; dst = blds + fl*512
  #pragma unroll
  for (int i = 0; i < 16; i++) {
    int fl = w + i * 4;
    int kt = fl >> 3, nt = fl & 7;
    gload_lds16(Pw + ((size_t)(kt * 128 + nt0 + nt) * 64 + lane) * 8,
                blds + (size_t)fl * 512);
  }
  asm volatile("s_waitcnt vmcnt(0)" ::: "memory");
  __syncthreads();
  f32x4 acc[2][8] = {};
  #pragma unroll
  for (int kt = 0; kt < 8; kt++) {
    const u16* bp = blds + (size_t)kt * 8 * 512 + (size_t)lane * 8;
    #pragma unroll
    for (int nt = 0; nt < 8; nt++) {
      bf16x8 b = ldb8(bp + nt * 512);
      acc[0][nt] = MFMA(af[0][kt], b, acc[0][nt]);
      acc[1][nt] = MFMA(af[1][kt], b, acc[1][nt]);
    }
  }
  int isv = (blockIdx.z == 2);
  float sc = (blockIdx.z == 0) ? CEXP : 1.0f;   // R19: fold softmax scale into Q
  int hl = blockIdx.x >> 1;
  int dd0 = (blockIdx.x & 1) * 128;
  int m0b = blockIdx.y * 128;
  int bi = m0b >> 11, l0 = m0b & 2047;
  __syncthreads();
  if (!isv) {
    #pragma unroll
    for (int mt = 0; mt < 2; mt++)
      #pragma unroll
      for (int nt = 0; nt < 8; nt++)
        #pragma unroll
        for (int r = 0; r < 4; r++)
          blds[(w * 32 + mt * 16 + (lane >> 4) * 4 + r) * 136 + nt * 16 + (lane & 15)] =
              f2b(acc[mt][nt][r] * sc);
    __syncthreads();
    #pragma unroll
    for (int i = 0; i < 8; i++) {
      int c = tid + i * 256;
      int mloc = c >> 4, q = c & 15;
      uint4 v = *(uint4*)(blds + mloc * 136 + q * 8);
      *(uint4*)(Out + ((size_t)(bi * hc + hl) * 2048 + l0 + mloc) * 256 + dd0 + q * 8) = v;
    }
  } else {
    #pragma unroll
    for (int mt = 0; mt < 2; mt++)
      #pragma unroll
      for (int nt = 0; nt < 8; nt++)
        #pragma unroll
        for (int r = 0; r < 4; r++)
          blds[(nt * 16 + (lane & 15)) * 136 + w * 32 + mt * 16 + (lane >> 4) * 4 + r] =
              f2b(acc[mt][nt][r]);
    __syncthreads();
    #pragma unroll
    for (int i = 0; i < 8; i++) {
      int c = tid + i * 256;
      int nloc = c >> 4, q = c & 15;
      uint4 v = *(uint4*)(blds + nloc * 136 + q * 8);
      *(uint4*)(Out + ((size_t)(bi * hc + hl) * 256 + dd0 + nloc) * 2048 + l0 + q * 8) = v;
    }
  }
}

// ---------------------------------------------------------------------------
// Flash attention, transposed dataflow, STATIC-MAX softmax.
// R22: 8 waves x 16 q (1 q-tile/wave), 512 thr — 4 waves/SIMD.  K+V double-
// buffered, ONE barrier/iter.  grid (nbh*16), 128 q/block;
// LDS 65536 B -> 2 blocks/CU (16 waves/CU).
// ---------------------------------------------------------------------------
__global__ __launch_bounds__(512, 4) void attn_kernel(
    const u16* __restrict__ Q, const u16* __restrict__ K,
    const u16* __restrict__ Vt, u16* __restrict__ O, int nbh) {
  __shared__ u16 kbuf[2 * 8192];   // 2 bufs x 16 frags x 512 u16 (frag-linear)
  __shared__ u16 vbuf[2 * 8192];
#if !HAS_PERMSWAP
  __shared__ u16 plds[8 * 640];    // per-wave P [16 q][40] (fallback path)
#endif
  int tid = threadIdx.x, lane = tid & 63, w = tid >> 6;
  int bi2 = blockIdx.x;
  int bh, qt;
  if (nbh >= 8) {
    int G = nbh >> 3;
    bh = (bi2 & 7) * G + (bi2 >> 3) % G;
    qt = bi2 / (8 * G);
  } else {
    bh = bi2 % nbh; qt = bi2 / nbh;
  }
  const u16* Qb  = Q  + (size_t)bh * 2048 * 256;
  const u16* Kb  = K  + (size_t)bh * 2048 * 256;
  const u16* Vtb = Vt + (size_t)bh * 256 * 2048;
  u16* Ob = O + (size_t)bh * 2048 * 256;
  int q0 = qt * 128 + w * 16;
  bf16x8 qf[8];   // B-operand: n=q=lane&15, k=d
  #pragma unroll
  for (int kt = 0; kt < 8; kt++)
    qf[kt] = ldb8(Qb + (size_t)(q0 + (lane & 15)) * 256 + kt * 32 + (lane >> 4) * 8);
  f32x4 o[16] = {};                // O^T: [d=16nt+4quad+r][q=lane&15]
  float lsum = 0.f;                // per-lane partial sum of p
#if !HAS_PERMSWAP
  u16* pl = plds + (size_t)w * 640;
#endif

  // pre-loop: issue K(0), V(0) into buffer 0 (8 waves x 2 frags = 16)
  #pragma unroll
  for (int j = 0; j < 2; j++) {
    int f = w * 2 + j;
    gload_lds16(Kb + (size_t)((f >> 3) * 16 + (lane & 15)) * 256 +
                    (f & 7) * 32 + (lane >> 4) * 8,
                kbuf + f * 512);
    gload_lds16(Vtb + (size_t)(f * 16 + (lane & 15)) * 2048 + (lane >> 4) * 8,
                vbuf + f * 512);
  }

  for (int t = 0; t < 64; t++) {
    int s0i = t * 32;
    // ONE barrier: K(t),V(t) (issued a full iteration ago) landed.
    asm volatile("s_waitcnt vmcnt(0)\ns_barrier" ::: "memory");
    if (t < 63) {
      int nb = (t + 1) & 1;
      #pragma unroll
      for (int j = 0; j < 2; j++) {
        int f = w * 2 + j;
        gload_lds16(Kb + (size_t)(s0i + 32 + (f >> 3) * 16 + (lane & 15)) * 256 +
                        (f & 7) * 32 + (lane >> 4) * 8,
                    kbuf + nb * 8192 + f * 512);
        gload_lds16(Vtb + (size_t)(f * 16 + (lane & 15)) * 2048 + s0i + 32 +
                        (lane >> 4) * 8,
                    vbuf + nb * 8192 + f * 512);
      }
    }
    // S^T = K Q^T: A = K frag (m=key,k=d), B = qf (k=d,n=q).
    const u16* kb = kbuf + (t & 1) * 8192;
    f32x4 s[2] = {};
    __builtin_amdgcn_s_setprio(1);
    #pragma unroll
    for (int ntk = 0; ntk < 2; ntk++)
      #pragma unroll
      for (int kt = 0; kt < 8; kt++) {
        bf16x8 a = ldb8(kb + (size_t)(ntk * 8 + kt) * 512 + lane * 8);
        s[ntk] = MFMA(a, qf[kt], s[ntk]);
      }
    __builtin_amdgcn_s_setprio(0);
#if HAS_PERMSWAP
    // static-max softmax + in-register P redistribution (no LDS roundtrip)
    bf16x8 pa = softmax_pa(s[0], s[1], lsum);
#else
    // fallback: softmax via plds roundtrip
    #pragma unroll
    for (int ntk = 0; ntk < 2; ntk++) {
      float p0 = EXP2(s[ntk][0]);
      float p1 = EXP2(s[ntk][1]);
      float p2 = EXP2(s[ntk][2]);
      float p3 = EXP2(s[ntk][3]);
      lsum += (p0 + p1) + (p2 + p3);
      uint2 pk;
      pk.x = pkbf(p0, p1);
      pk.y = pkbf(p2, p3);
      *(uint2*)(pl + (lane & 15) * 40 + 16 * ntk + 4 * (lane >> 4)) = pk;
    }
    asm volatile("s_waitcnt lgkmcnt(0)" ::: "memory");
    bf16x8 pa = ldb8(pl + (lane & 15) * 40 + (lane >> 4) * 8);
    asm volatile("s_waitcnt lgkmcnt(0)" ::: "memory");
#endif
    // ---- O^T += V^T P^T: A = V frag (m=d,k=key) ----
    const u16* vb0 = vbuf + (t & 1) * 8192;
    __builtin_amdgcn_s_setprio(1);
    #pragma unroll
    for (int nt = 0; nt < 16; nt++) {
      bf16x8 vb = ldb8(vb0 + (size_t)nt * 512 + lane * 8);
      o[nt] = MFMA(vb, pa, o[nt]);
    }
    __builtin_amdgcn_s_setprio(0);
  }
  // final l reduction: sum partials across the 4 quads of this q
  float l = lsum;
  l += __shfl_xor(l, 16);
  l += __shfl_xor(l, 32);
  float linv = 1.0f / l;
  // ---- epilogue: o is O^T [d][q]; transpose via kbuf, b128 writes ----
  u16* el = kbuf + w * 1152;             // per-wave [16 q][72]
  __syncthreads();
  #pragma unroll
  for (int g = 0; g < 4; g++) {
    if (g) asm volatile("s_waitcnt lgkmcnt(0)" ::: "memory");
    #pragma unroll
    for (int t2 = 0; t2 < 4; t2++) {
      int nt = g * 4 + t2;
      uint2 pk;
      pk.x = pkbf(o[nt][0] * linv, o[nt][1] * linv);
      pk.y = pkbf(o[nt][2] * linv, o[nt][3] * linv);
      *(uint2*)(el + (lane & 15) * 72 + t2 * 16 + 4 * (lane >> 4)) = pk;
    }
    asm volatile("s_waitcnt lgkmcnt(0)" ::: "memory");
    #pragma unroll
    for (int rep = 0; rep < 2; rep++) {
      int ch = lane + rep * 64;          // 128 chunks: 16 q-rows x 8
      int row = ch >> 3, c8 = ch & 7;
      uint4 v = *(uint4*)(el + row * 72 + c8 * 8);
      *(uint4*)(Ob + (size_t)(q0 + row) * 256 + g * 64 + c8 * 8) = v;
    }
  }
}

// ---------------------------------------------------------------------------
// R23 fused (hc==8): out = LN2( x + relu(x@W1+b1)@W2 + b2 ) where
// x = LN1(seq + O@Wo), computed IN-KERNEL (never hits global).
// grid (256), 128 thr (2 waves x 16 complete rows).
// Phase A: accum+LN1 (Wo staged K-step=2 double-buffered, A-loads hoisted).
// Phase B: x kept in regs (residual) + LDS-transposed for ffn A-frags;
// GEMM1(relu) -> hbuf -> GEMM2 -> +residual -> LN2 -> out.
// ---------------------------------------------------------------------------
__global__ __launch_bounds__(128) void accum_ln1_ffn_ln2_kernel(
    const u16* __restrict__ Oc, const u16* __restrict__ pWo,
    const u16* __restrict__ sbuf, const u16* __restrict__ vecs,
    const u16* __restrict__ pW1, const u16* __restrict__ pW2,
    const void* __restrict__ seq, void* __restrict__ out) {
  __shared__ u16 blds[2 * 32 * 512];   // 64KB: Wo dbuf; reused in phase B
  int tid = threadIdx.x, lane = tid & 63, w = tid >> 6;   // w in {0,1}
  int m0 = blockIdx.x * 32 + w * 16;
  int arow = m0 + (lane & 15);
  int bq = arow >> 11, lrow = arow & 2047;
  f32x4 acc[16] = {};
  // ---- Phase A: x = LN1(seq + O @ Wo) ----
  #pragma unroll
  for (int i = 0; i < 16; i++) {
    int fl = w + i * 2;                // 32 frags across 2 waves
    int ktg = fl >> 4, nt = fl & 15;
    gload_lds16(pWo + ((size_t)(ktg * 16 + nt) * 64 + lane) * 8,
                blds + (size_t)fl * 512);
  }
  asm volatile("s_waitcnt vmcnt(0)" ::: "memory");
  __syncthreads();
  for (int r = 0; r < 32; r++) {
    int k0 = r * 2;
    const u16* cur = blds + (size_t)(r & 1) * 16384;
    bf16x8 aA, aB;
    {
      int ktl = k0, hl = ktl >> 3;
      int d0 = (ktl & 7) * 32 + (lane >> 4) * 8;
      aA = ldb8(Oc + ((size_t)(bq * 8 + hl) * 2048 + lrow) * 256 + d0);
      ktl = k0 + 1; hl = ktl >> 3;
      d0 = (ktl & 7) * 32 + (lane >> 4) * 8;
      aB = ldb8(Oc + ((size_t)(bq * 8 + hl) * 2048 + lrow) * 256 + d0);
    }
    if (r < 31) {
      u16* nxt = blds + (size_t)((r + 1) & 1) * 16384;
      #pragma unroll
      for (int i = 0; i < 16; i++) {
        int fl = w + i * 2;
        int ktg = k0 + 2 + (fl >> 4), nt = fl & 15;
        gload_lds16(pWo + ((size_t)(ktg * 16 + nt) * 64 + lane) * 8,
                    nxt + (size_t)fl * 512);
      }
    }
    #pragma unroll
    for (int kl = 0; kl < 2; kl++) {
      bf16x8 a = kl ? aB : aA;
      const u16* bp = cur + (size_t)kl * 16 * 512 + (size_t)lane * 8;
      #pragma unroll
      for (int nt = 0; nt < 16; nt++) {
        bf16x8 b = ldb8(bp + nt * 512);
        acc[nt] = MFMA(a, b, acc[nt]);
      }
    }
    asm volatile("s_waitcnt vmcnt(0)" ::: "memory");
    __syncthreads();
  }
  int rbase = m0 + (lane >> 4) * 4;
  #pragma unroll
  for (int nt = 0; nt < 16; nt++) {
    int d = nt * 16 + (lane & 15);
    #pragma unroll
    for (int r = 0; r < 4; r++)
      acc[nt][r] += b2f(sbuf[(size_t)(rbase + r) * 256 + d]);
  }
  float mu[4], rs[4];
  #pragma unroll
  for (int r = 0; r < 4; r++) {
    float sm = 0.f;
    #pragma unroll
    for (int nt = 0; nt < 16; nt++) sm += acc[nt][r];
    sm += __shfl_xor(sm, 1); sm += __shfl_xor(sm, 2);
    sm += __shfl_xor(sm, 4); sm += __shfl_xor(sm, 8);
    mu[r] = sm * (1.0f / 256.0f);
    float v = 0.f;
    #pragma unroll
    for (int nt = 0; nt < 16; nt++) { float dd = acc[nt][r] - mu[r]; v += dd * dd; }
    v += __shfl_xor(v, 1); v += __shfl_xor(v, 2);
    v += __shfl_xor(v, 4); v += __shfl_xor(v, 8);
    rs[r] = rsqrtf(v * (1.0f / 256.0f) + 1e-5f);
  }
  // x in bf16 (C/D layout) -> keep in regs (residual) + transpose via LDS.
  // xl: per-warp [16 rows][264] u16 (row pad 8 -> bank shift 4/row).
  u16* xw = blds + (size_t)w * 16 * 264;
  uint2 xp[16];
  #pragma unroll
  for (int nt = 0; nt < 16; nt++) {
    int d = nt * 16 + (lane & 15);
    float gg = b2f(vecs[d]), bb = b2f(vecs[256 + d]);
    u16 e[4];
    #pragma unroll
    for (int r = 0; r < 4; r++) {
      e[r] = f2b((acc[nt][r] - mu[r]) * rs[r] * gg + bb);
      xw[((lane >> 4) * 4 + r) * 264 + d] = e[r];
    }
    xp[nt].x = (u32)e[0] | ((u32)e[1] << 16);
    xp[nt].y = (u32)e[2] | ((u32)e[3] << 16);
  }
  __syncthreads();
  // ---- Phase B: ffn + LN2 on the warp's 16 rows ----
  int isf32 = detect_f32(seq);
  u16* hb = blds + 16384 + (size_t)w * 16 * 136;   // per-warp [16][136]
  f32x4 acc1[8] = {};
  #pragma unroll
  for (int kt = 0; kt < 8; kt++) {
    bf16x8 a = ldb8(xw + (size_t)(lane & 15) * 264 + kt * 32 + (lane >> 4) * 8);
    const u16* bp = pW1 + ((size_t)kt * 8 * 64 + lane) * 8;
    #pragma unroll
    for (int nt = 0; nt < 8; nt++) {
      bf16x8 b = ldb8(bp + nt * 512);
      acc1[nt] = MFMA(a, b, acc1[nt]);
    }
  }
  #pragma unroll
  for (int nt = 0; nt < 8; nt++) {
    int col = nt * 16 + (lane & 15);
    float bb = b2f(vecs[512 + col]);
    #pragma unroll
    for (int r = 0; r < 4; r++) {
      float h = fmaxf(acc1[nt][r] + bb, 0.f);
      hb[((lane >> 4) * 4 + r) * 136 + col] = f2b(h);
    }
  }
  __syncthreads();
  f32x4 acc2[16] = {};
  #pragma unroll
  for (int ks = 0; ks < 4; ks++) {
    bf16x8 a = ldb8(hb + (size_t)(lane & 15) * 136 + ks * 32 + (lane >> 4) * 8);
    const u16* bp = pW2 + ((size_t)ks * 16 * 64 + lane) * 8;
    #pragma unroll
    for (int nt = 0; nt < 16; nt++) {
      bf16x8 b = ldb8(bp + nt * 512);
      acc2[nt] = MFMA(a, b, acc2[nt]);
    }
  }
  #pragma unroll
  for (int nt = 0; nt < 16; nt++) {
    int d = nt * 16 + (lane & 15);
    float bb = b2f(vecs[768 + d]);
    acc2[nt][0] += bb + b2f((u16)(xp[nt].x & 0xFFFF));
    acc2[nt][1] += bb + b2f((u16)(xp[nt].x >> 16));
    acc2[nt][2] += bb + b2f((u16)(xp[nt].y & 0xFFFF));
    acc2[nt][3] += bb + b2f((u16)(xp[nt].y >> 16));
  }
  float mu2[4], rs2[4];
  #pragma unroll
  for (int r = 0; r < 4; r++) {
    float sm = 0.f;
    #pragma unroll
    for (int nt = 0; nt < 16; nt++) sm += acc2[nt][r];
    sm += __shfl_xor(sm, 1); sm += __shfl_xor(sm, 2);
    sm += __shfl_xor(sm, 4); sm += __shfl_xor(sm, 8);
    mu2[r] = sm * (1.0f / 256.0f);
    float v = 0.f;
    #pragma unroll
    for (int nt = 0; nt < 16; nt++) { float dd = acc2[nt][r] - mu2[r]; v += dd * dd; }
    v += __shfl_xor(v, 1); v += __shfl_xor(v, 2);
    v += __shfl_xor(v, 4); v += __shfl_xor(v, 8);
    rs2[r] = rsqrtf(v * (1.0f / 256.0f) + 1e-5f);
  }
  #pragma unroll
  for (int nt = 0; nt < 16; nt++) {
    int d = nt * 16 + (lane & 15);
    float gg = b2f(vecs[1024 + d]), bb = b2f(vecs[1280 + d]);
    #pragma unroll
    for (int r = 0; r < 4; r++) {
      float val = (acc2[nt][r] - mu2[r]) * rs2[r] * gg + bb;
      size_t idx = (size_t)(rbase + r) * 256 + d;
      if (isf32) ((float*)out)[idx] = val;
      else       ((u16*)out)[idx]   = f2b(val);
    }
  }
}

// ---------------------------------------------------------------------------
// Fallback (hc<8): att_out(f32) += O_chunk @ Wo_chunk.  grid (128), 256 thr.
// ---------------------------------------------------------------------------
__global__ __launch_bounds__(256) void accum_kernel(
    const u16* __restrict__ Oc, const u16* __restrict__ pWo,
    float* __restrict__ att_out, int kt0, int hc) {
  __shared__ u16 blds[64 * 512];
  int tid = threadIdx.x, lane = tid & 63, w = tid >> 6;
  int m0 = blockIdx.x * 64 + w * 16;
  int arow = m0 + (lane & 15);
  int bq = arow >> 11, lrow = arow & 2047;
  int ktn = hc * 8;
  f32x4 acc[16] = {};
  for (int k0 = 0; k0 < ktn; k0 += 4) {
    __syncthreads();
    #pragma unroll
    for (int i = 0; i < 16; i++) {
      int fl = w + i * 4;
      int ktg = kt0 + k0 + (fl >> 4), nt = fl & 15;
      gload_lds16(pWo + ((size_t)(ktg * 16 + nt) * 64 + lane) * 8,
                  blds + (size_t)fl * 512);
    }
    asm volatile("s_waitcnt vmcnt(0)" ::: "memory");
    __syncthreads();
    #pragma unroll
    for (int kl = 0; kl < 4; kl++) {
      int ktl = k0 + kl;
      int hl = ktl >> 3;
      int d0 = (ktl & 7) * 32 + (lane >> 4) * 8;
      bf16x8 a = ldb8(Oc + ((size_t)(bq * hc + hl) * 2048 + lrow) * 256 + d0);
      const u16* bp = blds + (size_t)kl * 16 * 512 + (size_t)lane * 8;
      #pragma unroll
      for (int nt = 0; nt < 16; nt++) {
        bf16x8 b = ldb8(bp + nt * 512);
        acc[nt] = MFMA(a, b, acc[nt]);
      }
    }
  }
  int rbase = m0 + (lane >> 4) * 4;
  #pragma unroll
  for (int nt = 0; nt < 16; nt++) {
    int d = nt * 16 + (lane & 15);
    #pragma unroll
    for (int r = 0; r < 4; r++)
      att_out[(size_t)(rbase + r) * 256 + d] += acc[nt][r];
  }
}

// ---------------------------------------------------------------------------
// x = LN1(seq + att_out).  grid (2048), 256 threads; fallback path only.
// ---------------------------------------------------------------------------
__global__ __launch_bounds__(256) void ln1_kernel(
    const float* __restrict__ att_out, const u16* __restrict__ sbuf,
    const u16* __restrict__ vecs, u16* __restrict__ xout) {
  int tid = threadIdx.x, lane = tid & 63, w = tid >> 6;
  int row = blockIdx.x * 4 + w;
  const float* ar = att_out + (size_t)row * 256;
  f32x4 a = *(const f32x4*)(ar + lane * 4);
  uint2 sv = *(const uint2*)(sbuf + (size_t)row * 256 + lane * 4);
  float y[4];
  y[0] = a[0] + b2f((u16)(sv.x & 0xFFFF));
  y[1] = a[1] + b2f((u16)(sv.x >> 16));
  y[2] = a[2] + b2f((u16)(sv.y & 0xFFFF));
  y[3] = a[3] + b2f((u16)(sv.y >> 16));
  float sm = y[0] + y[1] + y[2] + y[3];
  sm += __shfl_xor(sm, 1);  sm += __shfl_xor(sm, 2);  sm += __shfl_xor(sm, 4);
  sm += __shfl_xor(sm, 8);  sm += __shfl_xor(sm, 16); sm += __shfl_xor(sm, 32);
  float mu = sm * (1.0f / 256.0f);
  float v = 0.f;
  #pragma unroll
  for (int j = 0; j < 4; j++) { float d = y[j] - mu; v += d * d; }
  v += __shfl_xor(v, 1);  v += __shfl_xor(v, 2);  v += __shfl_xor(v, 4);
  v += __shfl_xor(v, 8);  v += __shfl_xor(v, 16); v += __shfl_xor(v, 32);
  float rs = rsqrtf(v * (1.0f / 256.0f) + 1e-5f);
  u16 o[4];
  #pragma unroll
  for (int j = 0; j < 4; j++) {
    int d = lane * 4 + j;
    o[j] = f2b((y[j] - mu) * rs * b2f(vecs[d]) + b2f(vecs[256 + d]));
  }
  uint2 ov; ov.x = (u32)o[0] | ((u32)o[1] << 16); ov.y = (u32)o[2] | ((u32)o[3] << 16);
  *(uint2*)(xout + (size_t)row * 256 + lane * 4) = ov;
}

// ---------------------------------------------------------------------------
// FFN + LN2 (fallback path).  grid (256), 128 thr.
// ---------------------------------------------------------------------------
__global__ __launch_bounds__(128) void ffn_ln2_kernel(
    const u16* __restrict__ x, const u16* __restrict__ pW1,
    const u16* __restrict__ pW2, const u16* __restrict__ vecs,
    const void* __restrict__ seq, void* __restrict__ out) {
  __shared__ u16 hbuf[2 * 16 * 136];
  int isf32 = detect_f32(seq);
  int tid = threadIdx.x, lane = tid & 63, w = tid >> 6;   // w in {0,1}
  int m0 = blockIdx.x * 32 + w * 16;
  int arow = m0 + (lane & 15);
  u16* hb = hbuf + w * 16 * 136;
  f32x4 acc1[8] = {};
  #pragma unroll
  for (int kt = 0; kt < 8; kt++) {
    bf16x8 a = ldb8(x + (size_t)arow * 256 + kt * 32 + (lane >> 4) * 8);
    const u16* bp = pW1 + ((size_t)kt * 8 * 64 + lane) * 8;
    #pragma unroll
    for (int nt = 0; nt < 8; nt++) {
      bf16x8 b = ldb8(bp + nt * 512);
      acc1[nt] = MFMA(a, b, acc1[nt]);
    }
  }
  #pragma unroll
  for (int nt = 0; nt < 8; nt++) {
    int col = nt * 16 + (lane & 15);
    float bb = b2f(vecs[512 + col]);
    #pragma unroll
    for (int r = 0; r < 4; r++) {
      float h = fmaxf(acc1[nt][r] + bb, 0.f);
      hb[((lane >> 4) * 4 + r) * 136 + col] = f2b(h);
    }
  }
  __syncthreads();
  f32x4 acc2[16] = {};
  #pragma unroll
  for (int ks = 0; ks < 4; ks++) {
    bf16x8 a = ldb8(hb + (lane & 15) * 136 + ks * 32 + (lane >> 4) * 8);
    const u16* bp = pW2 + ((size_t)ks * 16 * 64 + lane) * 8;
    #pragma unroll
    for (int nt = 0; nt < 16; nt++) {
      bf16x8 b = ldb8(bp + nt * 512);
      acc2[nt] = MFMA(a, b, acc2[nt]);
    }
  }
  int rbase = m0 + (lane >> 4) * 4;
  #pragma unroll
  for (int nt = 0; nt < 16; nt++) {
    int d = nt * 16 + (lane & 15);
    float bb = b2f(vecs[768 + d]);
    #pragma unroll
    for (int r = 0; r < 4; r++)
      acc2[nt][r] += bb + b2f(x[(size_t)(rbase + r) * 256 + d]);
  }
  float mu[4], rs[4];
  #pragma unroll
  for (int r = 0; r < 4; r++) {
    float sm = 0.f;
    #pragma unroll
    for (int nt = 0; nt < 16; nt++) sm += acc2[nt][r];
    sm += __shfl_xor(sm, 1); sm += __shfl_xor(sm, 2);
    sm += __shfl_xor(sm, 4); sm += __shfl_xor(sm, 8);
    mu[r] = sm * (1.0f / 256.0f);
    float v = 0.f;
    #pragma unroll
    for (int nt = 0; nt < 16; nt++) { float dd = acc2[nt][r] - mu[r]; v += dd * dd; }
    v += __shfl_xor(v, 1); v += __shfl_xor(v, 2);
    v += __shfl_xor(v, 4); v += __shfl_xor(v, 8);
    rs[r] = rsqrtf(v * (1.0f / 256.0f) + 1e-5f);
  }
  #pragma unroll
  for (int nt = 0; nt < 16; nt++) {
    int d = nt * 16 + (lane & 15);
    float gg = b2f(vecs[1024 + d]), bb = b2f(vecs[1280 + d]);
    #pragma unroll
    for (int r = 0; r < 4; r++) {
      float val = (acc2[nt][r] - mu[r]) * rs[r] * gg + bb;
      size_t idx = (size_t)(rbase + r) * 256 + d;
      if (isf32) ((float*)out)[idx] = val;
      else       ((u16*)out)[idx]   = f2b(val);
    }
  }
}

// ---------------------------------------------------------------------------
__global__ __launch_bounds__(256) void sentinel_kernel(void* out, int n,
                                                       const void* seq) {
  int isf32 = detect_f32(seq);
  int i = blockIdx.x * 256 + threadIdx.x;
  if (i < n) {
    if (isf32) ((float*)out)[i] = 777.0f;
    else       ((u16*)out)[i]   = 0x4442;
  }
}

// ---------------------------------------------------------------------------
extern "C" void kernel_launch(void* const* d_in, const int* in_sizes, int n_in,
                              void* d_out, int out_size, void* d_ws, size_t ws_size,
                              hipStream_t stream) {
  (void)in_sizes; (void)n_in;
  const void* seq  = d_in[0];
  const void* Wq   = d_in[1];
  const void* Wk   = d_in[2];
  const void* Wv   = d_in[3];
  const void* Wo   = d_in[4];
  const void* g1   = d_in[5];
  const void* be1  = d_in[6];
  const void* W1   = d_in[7];
  const void* b1   = d_in[8];
  const void* W2   = d_in[9];
  const void* b2   = d_in[10];
  const void* g2   = d_in[11];
  const void* be2  = d_in[12];

  size_t o = 0;
  u16* ws = (u16*)d_ws;
  u16* pWq = ws + o; o += 524288;
  u16* pWk = ws + o; o += 524288;
  u16* pWv = ws + o; o += 524288;
  u16* pWo = ws + o; o += 524288;
  u16* pW1 = ws + o; o += 32768;
  u16* pW2 = ws + o; o += 32768;
  float* att = (float*)(ws + o); o += 4194304;   // 2M f32 (fallback path)
  u16* xb   = ws + o; o += 2097152;
  u16* sbuf = ws + o; o += 2097152;
  u16* vecs = ws + o; o += 2048;
  size_t fixed_elems = o;

  int hc = 0;
  for (int c = 8; c >= 1; c >>= 1) {
    size_t need = (fixed_elems + (size_t)4 * c * 2097152) * 2;
    if (need <= ws_size) { hc = c; break; }
  }
  if (hc == 0) {
    sentinel_kernel<<<dim3((out_size + 255) / 256), 256, 0, stream>>>(
        d_out, out_size, seq);
    return;
  }
  u16* Qc = ws + o; o += (size_t)hc * 2097152;
  u16* Kc = ws + o; o += (size_t)hc * 2097152;
  u16* Vc = ws + o; o += (size_t)hc * 2097152;   // V^T [B,hc,D,L]
  u16* Oc = ws + o;

  ingest_pack_kernel<<<dim3(2054 + 1536), 256, 0, stream>>>(
      seq, g1, be1, b1, b2, g2, be2, sbuf, vecs,
      Wq, Wk, Wv, Wo, W1, W2, pWq, pWk, pWv, pWo, pW1, pW2);
  if (hc == 8) {
    // single-chunk fast path: 4 dispatches total
    qkv_kernel<<<dim3(16, 64, 3), 256, 0, stream>>>(
        sbuf, pWq, pWk, pWv, Qc, Kc, Vc, 0, 8);
    attn_kernel<<<dim3(32 * 16), 512, 0, stream>>>(Qc, Kc, Vc, Oc, 32);
    accum_ln1_ffn_ln2_kernel<<<dim3(256), 128, 0, stream>>>(
        Oc, pWo, sbuf, vecs, pW1, pW2, seq, (void*)d_out);
  } else {
    hipMemsetAsync(att, 0, 2097152 * sizeof(float), stream);
    int nchunks = 8 / hc;
    for (int c = 0; c < nchunks; c++) {
      int nbh = 4 * hc;
      qkv_kernel<<<dim3(2 * hc, 64, 3), 256, 0, stream>>>(
          sbuf, pWq, pWk, pWv, Qc, Kc, Vc, c * hc * 16, hc);
      attn_kernel<<<dim3(nbh * 16), 512, 0, stream>>>(Qc, Kc, Vc, Oc, nbh);
      accum_kernel<<<dim3(128), 256, 0, stream>>>(Oc, pWo, att, c * hc * 8, hc);
    }
    ln1_kernel<<<dim3(2048), 256, 0, stream>>>(att, sbuf, vecs, xb);
    ffn_ln2_kernel<<<dim3(256), 128, 0, stream>>>(xb, pW1, pW2, vecs, seq,
                                                  (void*)d_out);
  }
}

// Round 11
// 334.031 us; speedup vs baseline: 1.4829x; 1.0234x over previous
//
#include <hip/hip_runtime.h>

// ---------------------------------------------------------------------------
// TransformerEncoderLayer on MI355X (gfx950).  B=4 L=2048 D=256 H=8 FF=128.
// Input dtype (fp32 vs bf16) detected at runtime; compute bf16 MFMA, fp32 acc.
// Layouts: A[m=lane&15][k=8*(lane>>4)+j], B[k=8*(lane>>4)+j][n=lane&15],
//          C/D[row=(lane>>4)*4+r][col=lane&15]
// R3: V pre-transposed [B,h,D,L].  R12: transposed attn dataflow.
// R16/R18/R19: cheap softmax (v_exp_f32, cvt_pk, permlane P, scale in Q).
// R22: 8-wave/512-thr attn (4 waves/SIMD): 171->164.5us, occ 22->43%.
// R23: ingest+pack fused; accum_ln1+ffn_ln2 fused (xb never global). ~null
//      -> non-attn cost is INSIDE kernels; qkv is the only big-enough pool.
// R24: qkv WEIGHT-RESIDENT restructure.  Old: grid(16,64,3)=3072 blocks,
//      each re-staged the same 64KB weight tile (196MB staged, serial
//      stage->drain->compute per block; 12 drains/CU).  New: grid(16,16,3)
//      =768 blocks x 4 row-tiles each; weights staged ONCE per block
//      (48MB), NO barrier in the y-loop (per-wave epilogue buffers,
//      lgkmcnt ordering only), A(y+1) prefetched under epilogue(y).
//      Epilogue rebuilt per-wave in 4 col-groups of 32 ([32][40] slices);
//      LDS 74KB -> still 2 blocks/CU.  Output bytes identical.
// ---------------------------------------------------------------------------

typedef unsigned short u16;
typedef unsigned int   u32;
typedef __bf16 bf16x8 __attribute__((ext_vector_type(8)));
typedef __bf16 bf16x2 __attribute__((ext_vector_type(2)));
typedef float  f32x4  __attribute__((ext_vector_type(4)));

#define MFMA(a, b, c) __builtin_amdgcn_mfma_f32_16x16x32_bf16(a, b, c, 0, 0, 0)

#if __has_builtin(__builtin_amdgcn_exp2f)
#define EXP2(x) __builtin_amdgcn_exp2f(x)
#else
#define EXP2(x) exp2f(x)
#endif

#if __has_builtin(__builtin_amdgcn_permlane16_swap) && \
    __has_builtin(__builtin_amdgcn_permlane32_swap)
#define HAS_PERMSWAP 1
#else
#define HAS_PERMSWAP 0
#endif

// softmax scale * log2(e), folded into Q at projection time (R19)
#define CEXP 0.09016844f

__device__ __forceinline__ float b2f(u16 h) {
  return __uint_as_float(((u32)h) << 16);
}
__device__ __forceinline__ u16 f2b(float f) {
  u32 u = __float_as_uint(f);
  u += 0x7FFFu + ((u >> 16) & 1u);   // round-to-nearest-even
  return (u16)(u >> 16);
}
// packed f32x2 -> bf16x2 (RTNE); gfx950 backend emits v_cvt_pk_bf16_f32
__device__ __forceinline__ u32 pkbf(float lo, float hi) {
  bf16x2 v;
  v[0] = (__bf16)lo;
  v[1] = (__bf16)hi;
  return __builtin_bit_cast(u32, v);
}
__device__ __forceinline__ bf16x8 ldb8(const u16* p) { return *(const bf16x8*)p; }

typedef const __attribute__((address_space(1))) u32* gas1_t;
typedef __attribute__((address_space(3))) u32* las3_t;
__device__ __forceinline__ void gload_lds16(const u16* g, u16* lds_base) {
  __builtin_amdgcn_global_load_lds((gas1_t)(const void*)g,
                                   (las3_t)(void*)lds_base, 16, 0, 0);
}

__device__ __forceinline__ int detect_f32(const void* seq) {
  const u32* s = (const u32*)seq;
  int cnt = 0;
  #pragma unroll
  for (int i = 0; i < 64; i++) {
    u32 e = (s[i] >> 7) & 0xFFu;
    cnt += (e >= 100u && e <= 140u) ? 1 : 0;
  }
  return cnt < 48;  // 1 => fp32
}

__device__ __forceinline__ u16 ldw(const void* W, size_t idx, int isf32) {
  return isf32 ? f2b(((const float*)W)[idx]) : ((const u16*)W)[idx];
}

#if HAS_PERMSWAP
// softmax for one q-tile: p = 2^s (scale pre-folded into Q); accumulate
// per-lane l; return PV B-operand fragment in registers via permlane swaps.
__device__ __forceinline__ bf16x8 softmax_pa(f32x4 sn0, f32x4 sn1,
                                             float& lsum) {
  float p00 = EXP2(sn0[0]), p01 = EXP2(sn0[1]);
  float p02 = EXP2(sn0[2]), p03 = EXP2(sn0[3]);
  float p10 = EXP2(sn1[0]), p11 = EXP2(sn1[1]);
  float p12 = EXP2(sn1[2]), p13 = EXP2(sn1[3]);
  lsum += ((p00 + p01) + (p02 + p03)) + ((p10 + p11) + (p12 + p13));
  u32 A0 = pkbf(p00, p01), A1 = pkbf(p02, p03);
  u32 B0 = pkbf(p10, p11), B1 = pkbf(p12, p13);
  auto ra = __builtin_amdgcn_permlane32_swap(A0, B0, false, false);
  auto rb = __builtin_amdgcn_permlane32_swap(A1, B1, false, false);
  auto sa = __builtin_amdgcn_permlane16_swap(ra[0], ra[1], false, false);
  auto sb = __builtin_amdgcn_permlane16_swap(rb[0], rb[1], false, false);
  uint4 wv;
  wv.x = sa[0];  // keys 8Q+0,1
  wv.y = sb[0];  // keys 8Q+2,3
  wv.z = sa[1];  // keys 8Q+4,5
  wv.w = sb[1];  // keys 8Q+6,7
  return __builtin_bit_cast(bf16x8, wv);
}
#endif

// ---------------------------------------------------------------------------
// Ingest body: canonicalize seq (2M elems) + 6 small vectors to bf16 in ws.
// ---------------------------------------------------------------------------
__device__ __forceinline__ void ingest_body(
    int bx, int tid, int isf32,
    const void* __restrict__ seq, const void* __restrict__ g1,
    const void* __restrict__ be1, const void* __restrict__ b1,
    const void* __restrict__ b2v, const void* __restrict__ g2,
    const void* __restrict__ be2, u16* __restrict__ sbuf,
    u16* __restrict__ vecs) {
  if (bx < 2048) {
    size_t i = (size_t)bx * 1024 + tid * 4;
    if (isf32) {
      const float* sp = (const float*)seq;
      u16 o0 = f2b(sp[i]), o1 = f2b(sp[i + 1]), o2 = f2b(sp[i + 2]), o3 = f2b(sp[i + 3]);
      uint2 ov; ov.x = (u32)o0 | ((u32)o1 << 16); ov.y = (u32)o2 | ((u32)o3 << 16);
      *(uint2*)(sbuf + i) = ov;
    } else {
      *(uint2*)(sbuf + i) = ((const uint2*)seq)[i >> 2];
    }
  } else {
    int t = bx - 2048;
    const void* src; int n;
    switch (t) {
      case 0: src = g1;  n = 256; break;
      case 1: src = be1; n = 256; break;
      case 2: src = b1;  n = 128; break;
      case 3: src = b2v; n = 256; break;
      case 4: src = g2;  n = 256; break;
      default: src = be2; n = 256; break;
    }
    if (tid < n) vecs[t * 256 + tid] = ldw(src, tid, isf32);
  }
}

// ---------------------------------------------------------------------------
// Pack body: weights into B-fragment-linear layout.
// ---------------------------------------------------------------------------
__device__ __forceinline__ void pack_body(
    int px, int py, int tid, int isf32,
    const void* __restrict__ Wq, const void* __restrict__ Wk,
    const void* __restrict__ Wv, const void* __restrict__ Wo,
    const void* __restrict__ W1, const void* __restrict__ W2,
    u16* __restrict__ pWq, u16* __restrict__ pWk, u16* __restrict__ pWv,
    u16* __restrict__ pWo, u16* __restrict__ pW1, u16* __restrict__ pW2) {
  const void* W; u16* P; int K, N;
  switch (py) {
    case 0: W = Wq; P = pWq; K = 256;  N = 2048; break;
    case 1: W = Wk; P = pWk; K = 256;  N = 2048; break;
    case 2: W = Wv; P = pWv; K = 256;  N = 2048; break;
    case 3: W = Wo; P = pWo; K = 2048; N = 256;  break;
    case 4: W = W1; P = pW1; K = 256;  N = 128;  break;
    default: W = W2; P = pW2; K = 128; N = 256;  break;
  }
  int t = px * 256 + tid;
  int total = (K >> 5) * (N >> 4) * 64;
  if (t >= total) return;
  int lane = t & 63, f = t >> 6;
  int NT = N >> 4;
  int kt = f / NT, nt = f - kt * NT;
  int row0 = kt * 32 + ((lane >> 4) << 3);
  int col = nt * 16 + (lane & 15);
  u16 e[8];
  #pragma unroll
  for (int j = 0; j < 8; j++) e[j] = ldw(W, (size_t)(row0 + j) * N + col, isf32);
  uint4 u;
  u.x = (u32)e[0] | ((u32)e[1] << 16);
  u.y = (u32)e[2] | ((u32)e[3] << 16);
  u.z = (u32)e[4] | ((u32)e[5] << 16);
  u.w = (u32)e[6] | ((u32)e[7] << 16);
  *(uint4*)(P + ((size_t)f * 64 + lane) * 8) = u;
}

// ---------------------------------------------------------------------------
// R23: fused ingest + pack.  grid (2054 + 1536) = 3590, 256 thr.
// ---------------------------------------------------------------------------
__global__ __launch_bounds__(256) void ingest_pack_kernel(
    const void* __restrict__ seq, const void* __restrict__ g1,
    const void* __restrict__ be1, const void* __restrict__ b1,
    const void* __restrict__ b2v, const void* __restrict__ g2,
    const void* __restrict__ be2, u16* __restrict__ sbuf,
    u16* __restrict__ vecs,
    const void* __restrict__ Wq, const void* __restrict__ Wk,
    const void* __restrict__ Wv, const void* __restrict__ Wo,
    const void* __restrict__ W1, const void* __restrict__ W2,
    u16* __restrict__ pWq, u16* __restrict__ pWk, u16* __restrict__ pWv,
    u16* __restrict__ pWo, u16* __restrict__ pW1, u16* __restrict__ pW2) {
  int isf32 = detect_f32(seq);
  int bx = blockIdx.x, tid = threadIdx.x;
  if (bx < 2054) {
    ingest_body(bx, tid, isf32, seq, g1, be1, b1, b2v, g2, be2, sbuf, vecs);
  } else {
    int bxp = bx - 2054;
    pack_body(bxp & 255, bxp >> 8, tid, isf32, Wq, Wk, Wv, Wo, W1, W2,
              pWq, pWk, pWv, pWo, pW1, pW2);
  }
}

// ---------------------------------------------------------------------------
// R24 QKV projection: X(8192x256) @ W(256, hc*256).
// Q,K -> [B,hc,L,D]; V -> transposed [B,hc,D,L].
// grid (2*hc, 16, 3), 256 thr, 2 blocks/CU.  Weights staged ONCE (64KB LDS,
// resident), then 4 row-tiles (y-loop, 512 rows) with NO barriers: per-wave
// epilogue slices ([32][40] u16, 4 col-groups of 32), A(y+1) prefetched
// under epilogue(y).  Output bytes identical to the old kernel.
// ---------------------------------------------------------------------------
__global__ __launch_bounds__(256, 2) void qkv_kernel(
    const u16* __restrict__ X,
    const u16* __restrict__ pWq, const u16* __restrict__ pWk,
    const u16* __restrict__ pWv,
    u16* __restrict__ Qo, u16* __restrict__ Ko, u16* __restrict__ Vo,
    int ntbase, int hc) {
  __shared__ u16 blds[64 * 512];   // weight tile, resident across y
  __shared__ u16 ebuf[4 * 1280];   // per-wave epilogue [32 rows][40]
  const u16* Pw = (blockIdx.z == 0) ? pWq : ((blockIdx.z == 1) ? pWk : pWv);
  u16* Out = (blockIdx.z == 0) ? Qo : ((blockIdx.z == 1) ? Ko : Vo);
  int tid = threadIdx.x, lane = tid & 63, w = tid >> 6;
  int nt0 = ntbase + blockIdx.x * 8;
  int isv = (blockIdx.z == 2);
  float sc = (blockIdx.z == 0) ? CEXP : 1.0f;   // R19: softmax scale in Q
  int hl = blockIdx.x >> 1;
  int dd0 = (blockIdx.x & 1) * 128;
  u16* eb = ebuf + (size_t)w * 1280;
  // stage weights once (async) + prefetch A for y=0
  #pragma unroll
  for (int i = 0; i < 16; i++) {
    int fl = w + i * 4;
    int kt = fl >> 3, nt = fl & 7;
    gload_lds16(Pw + ((size_t)(kt * 128 + nt0 + nt) * 64 + lane) * 8,
                blds + (size_t)fl * 512);
  }
  bf16x8 af[2][8];
  {
    int m0 = blockIdx.y * 512 + w * 32;
    #pragma unroll
    for (int kt = 0; kt < 8; kt++) {
      af[0][kt] = ldb8(X + (size_t)(m0 + (lane & 15)) * 256 + kt * 32 + (lane >> 4) * 8);
      af[1][kt] = ldb8(X + (size_t)(m0 + 16 + (lane & 15)) * 256 + kt * 32 + (lane >> 4) * 8);
    }
  }
  asm volatile("s_waitcnt vmcnt(0)" ::: "memory");
  __syncthreads();
  for (int y = 0; y < 4; y++) {
    int m0b = blockIdx.y * 512 + y * 128;
    f32x4 acc[2][8] = {};
    #pragma unroll
    for (int kt = 0; kt < 8; kt++) {
      const u16* bp = blds + (size_t)kt * 8 * 512 + (size_t)lane * 8;
      #pragma unroll
      for (int nt = 0; nt < 8; nt++) {
        bf16x8 b = ldb8(bp + nt * 512);
        acc[0][nt] = MFMA(af[0][kt], b, acc[0][nt]);
        acc[1][nt] = MFMA(af[1][kt], b, acc[1][nt]);
      }
    }
    // prefetch A for next y (lands under the epilogue stores below)
    if (y < 3) {
      int m1 = m0b + 128 + w * 32;
      #pragma unroll
      for (int kt = 0; kt < 8; kt++) {
        af[0][kt] = ldb8(X + (size_t)(m1 + (lane & 15)) * 256 + kt * 32 + (lane >> 4) * 8);
        af[1][kt] = ldb8(X + (size_t)(m1 + 16 + (lane & 15)) * 256 + kt * 32 + (lane >> 4) * 8);
      }
    }
    int bi = m0b >> 11, l0 = m0b & 2047;
    if (!isv) {
      // Q/K: per-wave rows w*32..w*32+31; 4 col-groups of 32
      #pragma unroll
      for (int g = 0; g < 4; g++) {
        #pragma unroll
        for (int mt = 0; mt < 2; mt++)
          #pragma unroll
          for (int nt2 = 0; nt2 < 2; nt2++) {
            int nt = g * 2 + nt2;
            #pragma unroll
            for (int r = 0; r < 4; r++)
              eb[(mt * 16 + (lane >> 4) * 4 + r) * 40 + nt2 * 16 + (lane & 15)] =
                  f2b(acc[mt][nt][r] * sc);
          }
        asm volatile("s_waitcnt lgkmcnt(0)" ::: "memory");
        #pragma unroll
        for (int rep = 0; rep < 2; rep++) {
          int ch = lane + rep * 64;        // 128 chunks: 32 rows x 4
          int row = ch >> 2, c8 = ch & 3;
          uint4 v = *(uint4*)(eb + row * 40 + c8 * 8);
          *(uint4*)(Out + ((size_t)(bi * hc + hl) * 2048 + l0 + w * 32 + row) * 256 +
                    dd0 + g * 32 + c8 * 8) = v;
        }
        asm volatile("s_waitcnt lgkmcnt(0)" ::: "memory");
      }
    } else {
      // V^T: per-wave lrows w*32..w*32+31; 4 dcol-groups of 32
      #pragma unroll
      for (int g = 0; g < 4; g++) {
        #pragma unroll
        for (int mt = 0; mt < 2; mt++)
          #pragma unroll
          for (int nt2 = 0; nt2 < 2; nt2++) {
            int nt = g * 2 + nt2;
            #pragma unroll
            for (int r = 0; r < 4; r++)
              eb[(nt2 * 16 + (lane & 15)) * 40 + mt * 16 + (lane >> 4) * 4 + r] =
                  f2b(acc[mt][nt][r]);
          }
        asm volatile("s_waitcnt lgkmcnt(0)" ::: "memory");
        #pragma unroll
        for (int rep = 0; rep < 2; rep++) {
          int ch = lane + rep * 64;        // 128 chunks: 32 dcols x 4
          int dc = ch >> 2, c8 = ch & 3;
          uint4 v = *(uint4*)(eb + dc * 40 + c8 * 8);
          *(uint4*)(Out + ((size_t)(bi * hc + hl) * 256 + dd0 + g * 32 + dc) * 2048 +
                    l0 + w * 32 + c8 * 8) = v;
        }
        asm volatile("s_waitcnt lgkmcnt(0)" ::: "memory");
      }
    }
  }
}

// ---------------------------------------------------------------------------
// Flash attention, transposed dataflow, STATIC-MAX softmax.
// R22: 8 waves x 16 q (1 q-tile/wave), 512 thr — 4 waves/SIMD.  K+V double-
// buffered, ONE barrier/iter.  grid (nbh*16), 128 q/block;
// LDS 65536 B -> 2 blocks/CU (16 waves/CU).
// ---------------------------------------------------------------------------
__global__ __launch_bounds__(512, 4) void attn_kernel(
    const u16* __restrict__ Q, const u16* __restrict__ K,
    const u16* __restrict__ Vt, u16* __restrict__ O, int nbh) {
  __shared__ u16 kbuf[2 * 8192];   // 2 bufs x 16 frags x 512 u16 (frag-linear)
  __shared__ u16 vbuf[2 * 8192];
#if !HAS_PERMSWAP
  __shared__ u16 plds[8 * 640];    // per-wave P [16 q][40] (fallback path)
#endif
  int tid = threadIdx.x, lane = tid & 63, w = tid >> 6;
  int bi2 = blockIdx.x;
  int bh, qt;
  if (nbh >= 8) {
    int G = nbh >> 3;
    bh = (bi2 & 7) * G + (bi2 >> 3) % G;
    qt = bi2 / (8 * G);
  } else {
    bh = bi2 % nbh; qt = bi2 / nbh;
  }
  const u16* Qb  = Q  + (size_t)bh * 2048 * 256;
  const u16* Kb  = K  + (size_t)bh * 2048 * 256;
  const u16* Vtb = Vt + (size_t)bh * 256 * 2048;
  u16* Ob = O + (size_t)bh * 2048 * 256;
  int q0 = qt * 128 + w * 16;
  bf16x8 qf[8];   // B-operand: n=q=lane&15, k=d
  #pragma unroll
  for (int kt = 0; kt < 8; kt++)
    qf[kt] = ldb8(Qb + (size_t)(q0 + (lane & 15)) * 256 + kt * 32 + (lane >> 4) * 8);
  f32x4 o[16] = {};                // O^T: [d=16nt+4quad+r][q=lane&15]
  float lsum = 0.f;                // per-lane partial sum of p
#if !HAS_PERMSWAP
  u16* pl = plds + (size_t)w * 640;
#endif

  // pre-loop: issue K(0), V(0) into buffer 0 (8 waves x 2 frags = 16)
  #pragma unroll
  for (int j = 0; j < 2; j++) {
    int f = w * 2 + j;
    gload_lds16(Kb + (size_t)((f >> 3) * 16 + (lane & 15)) * 256 +
                    (f & 7) * 32 + (lane >> 4) * 8,
                kbuf + f * 512);
    gload_lds16(Vtb + (size_t)(f * 16 + (lane & 15)) * 2048 + (lane >> 4) * 8,
                vbuf + f * 512);
  }

  for (int t = 0; t < 64; t++) {
    int s0i = t * 32;
    // ONE barrier: K(t),V(t) (issued a full iteration ago) landed.
    asm volatile("s_waitcnt vmcnt(0)\ns_barrier" ::: "memory");
    if (t < 63) {
      int nb = (t + 1) & 1;
      #pragma unroll
      for (int j = 0; j < 2; j++) {
        int f = w * 2 + j;
        gload_lds16(Kb + (size_t)(s0i + 32 + (f >> 3) * 16 + (lane & 15)) * 256 +
                        (f & 7) * 32 + (lane >> 4) * 8,
                    kbuf + nb * 8192 + f * 512);
        gload_lds16(Vtb + (size_t)(f * 16 + (lane & 15)) * 2048 + s0i + 32 +
                        (lane >> 4) * 8,
                    vbuf + nb * 8192 + f * 512);
      }
    }
    // S^T = K Q^T: A = K frag (m=key,k=d), B = qf (k=d,n=q).
    const u16* kb = kbuf + (t & 1) * 8192;
    f32x4 s[2] = {};
    __builtin_amdgcn_s_setprio(1);
    #pragma unroll
    for (int ntk = 0; ntk < 2; ntk++)
      #pragma unroll
      for (int kt = 0; kt < 8; kt++) {
        bf16x8 a = ldb8(kb + (size_t)(ntk * 8 + kt) * 512 + lane * 8);
        s[ntk] = MFMA(a, qf[kt], s[ntk]);
      }
    __builtin_amdgcn_s_setprio(0);
#if HAS_PERMSWAP
    // static-max softmax + in-register P redistribution (no LDS roundtrip)
    bf16x8 pa = softmax_pa(s[0], s[1], lsum);
#else
    // fallback: softmax via plds roundtrip
    #pragma unroll
    for (int ntk = 0; ntk < 2; ntk++) {
      float p0 = EXP2(s[ntk][0]);
      float p1 = EXP2(s[ntk][1]);
      float p2 = EXP2(s[ntk][2]);
      float p3 = EXP2(s[ntk][3]);
      lsum += (p0 + p1) + (p2 + p3);
      uint2 pk;
      pk.x = pkbf(p0, p1);
      pk.y = pkbf(p2, p3);
      *(uint2*)(pl + (lane & 15) * 40 + 16 * ntk + 4 * (lane >> 4)) = pk;
    }
    asm volatile("s_waitcnt lgkmcnt(0)" ::: "memory");
    bf16x8 pa = ldb8(pl + (lane & 15) * 40 + (lane >> 4) * 8);
    asm volatile("s_waitcnt lgkmcnt(0)" ::: "memory");
#endif
    // ---- O^T += V^T P^T: A = V frag (m=d,k=key) ----
    const u16* vb0 = vbuf + (t & 1) * 8192;
    __builtin_amdgcn_s_setprio(1);
    #pragma unroll
    for (int nt = 0; nt < 16; nt++) {
      bf16x8 vb = ldb8(vb0 + (size_t)nt * 512 + lane * 8);
      o[nt] = MFMA(vb, pa, o[nt]);
    }
    __builtin_amdgcn_s_setprio(0);
  }
  // final l reduction: sum partials across the 4 quads of this q
  float l = lsum;
  l += __shfl_xor(l, 16);
  l += __shfl_xor(l, 32);
  float linv = 1.0f / l;
  // ---- epilogue: o is O^T [d][q]; transpose via kbuf, b128 writes ----
  u16* el = kbuf + w * 1152;             // per-wave [16 q][72]
  __syncthreads();
  #pragma unroll
  for (int g = 0; g < 4; g++) {
    if (g) asm volatile("s_waitcnt lgkmcnt(0)" ::: "memory");
    #pragma unroll
    for (int t2 = 0; t2 < 4; t2++) {
      int nt = g * 4 + t2;
      uint2 pk;
      pk.x = pkbf(o[nt][0] * linv, o[nt][1] * linv);
      pk.y = pkbf(o[nt][2] * linv, o[nt][3] * linv);
      *(uint2*)(el + (lane & 15) * 72 + t2 * 16 + 4 * (lane >> 4)) = pk;
    }
    asm volatile("s_waitcnt lgkmcnt(0)" ::: "memory");
    #pragma unroll
    for (int rep = 0; rep < 2; rep++) {
      int ch = lane + rep * 64;          // 128 chunks: 16 q-rows x 8
      int row = ch >> 3, c8 = ch & 7;
      uint4 v = *(uint4*)(el + row * 72 + c8 * 8);
      *(uint4*)(Ob + (size_t)(q0 + row) * 256 + g * 64 + c8 * 8) = v;
    }
  }
}

// ---------------------------------------------------------------------------
// R23 fused (hc==8): out = LN2( x + relu(x@W1+b1)@W2 + b2 ) where
// x = LN1(seq + O@Wo), computed IN-KERNEL (never hits global).
// grid (256), 128 thr (2 waves x 16 complete rows).
// ---------------------------------------------------------------------------
__global__ __launch_bounds__(128) void accum_ln1_ffn_ln2_kernel(
    const u16* __restrict__ Oc, const u16* __restrict__ pWo,
    const u16* __restrict__ sbuf, const u16* __restrict__ vecs,
    const u16* __restrict__ pW1, const u16* __restrict__ pW2,
    const void* __restrict__ seq, void* __restrict__ out) {
  __shared__ u16 blds[2 * 32 * 512];   // 64KB: Wo dbuf; reused in phase B
  int tid = threadIdx.x, lane = tid & 63, w = tid >> 6;   // w in {0,1}
  int m0 = blockIdx.x * 32 + w * 16;
  int arow = m0 + (lane & 15);
  int bq = arow >> 11, lrow = arow & 2047;
  f32x4 acc[16] = {};
  // ---- Phase A: x = LN1(seq + O @ Wo) ----
  #pragma unroll
  for (int i = 0; i < 16; i++) {
    int fl = w + i * 2;                // 32 frags across 2 waves
    int ktg = fl >> 4, nt = fl & 15;
    gload_lds16(pWo + ((size_t)(ktg * 16 + nt) * 64 + lane) * 8,
                blds + (size_t)fl * 512);
  }
  asm volatile("s_waitcnt vmcnt(0)" ::: "memory");
  __syncthreads();
  for (int r = 0; r < 32; r++) {
    int k0 = r * 2;
    const u16* cur = blds + (size_t)(r & 1) * 16384;
    bf16x8 aA, aB;
    {
      int ktl = k0, hl = ktl >> 3;
      int d0 = (ktl & 7) * 32 + (lane >> 4) * 8;
      aA = ldb8(Oc + ((size_t)(bq * 8 + hl) * 2048 + lrow) * 256 + d0);
      ktl = k0 + 1; hl = ktl >> 3;
      d0 = (ktl & 7) * 32 + (lane >> 4) * 8;
      aB = ldb8(Oc + ((size_t)(bq * 8 + hl) * 2048 + lrow) * 256 + d0);
    }
    if (r < 31) {
      u16* nxt = blds + (size_t)((r + 1) & 1) * 16384;
      #pragma unroll
      for (int i = 0; i < 16; i++) {
        int fl = w + i * 2;
        int ktg = k0 + 2 + (fl >> 4), nt = fl & 15;
        gload_lds16(pWo + ((size_t)(ktg * 16 + nt) * 64 + lane) * 8,
                    nxt + (size_t)fl * 512);
      }
    }
    #pragma unroll
    for (int kl = 0; kl < 2; kl++) {
      bf16x8 a = kl ? aB : aA;
      const u16* bp = cur + (size_t)kl * 16 * 512 + (size_t)lane * 8;
      #pragma unroll
      for (int nt = 0; nt < 16; nt++) {
        bf16x8 b = ldb8(bp + nt * 512);
        acc[nt] = MFMA(a, b, acc[nt]);
      }
    }
    asm volatile("s_waitcnt vmcnt(0)" ::: "memory");
    __syncthreads();
  }
  int rbase = m0 + (lane >> 4) * 4;
  #pragma unroll
  for (int nt = 0; nt < 16; nt++) {
    int d = nt * 16 + (lane & 15);
    #pragma unroll
    for (int r = 0; r < 4; r++)
      acc[nt][r] += b2f(sbuf[(size_t)(rbase + r) * 256 + d]);
  }
  float mu[4], rs[4];
  #pragma unroll
  for (int r = 0; r < 4; r++) {
    float sm = 0.f;
    #pragma unroll
    for (int nt = 0; nt < 16; nt++) sm += acc[nt][r];
    sm += __shfl_xor(sm, 1); sm += __shfl_xor(sm, 2);
    sm += __shfl_xor(sm, 4); sm += __shfl_xor(sm, 8);
    mu[r] = sm * (1.0f / 256.0f);
    float v = 0.f;
    #pragma unroll
    for (int nt = 0; nt < 16; nt++) { float dd = acc[nt][r] - mu[r]; v += dd * dd; }
    v += __shfl_xor(v, 1); v += __shfl_xor(v, 2);
    v += __shfl_xor(v, 4); v += __shfl_xor(v, 8);
    rs[r] = rsqrtf(v * (1.0f / 256.0f) + 1e-5f);
  }
  // x in bf16 (C/D layout) -> keep in regs (residual) + transpose via LDS.
  u16* xw = blds + (size_t)w * 16 * 264;
  uint2 xp[16];
  #pragma unroll
  for (int nt = 0; nt < 16; nt++) {
    int d = nt * 16 + (lane & 15);
    float gg = b2f(vecs[d]), bb = b2f(vecs[256 + d]);
    u16 e[4];
    #pragma unroll
    for (int r = 0; r < 4; r++) {
      e[r] = f2b((acc[nt][r] - mu[r]) * rs[r] * gg + bb);
      xw[((lane >> 4) * 4 + r) * 264 + d] = e[r];
    }
    xp[nt].x = (u32)e[0] | ((u32)e[1] << 16);
    xp[nt].y = (u32)e[2] | ((u32)e[3] << 16);
  }
  __syncthreads();
  // ---- Phase B: ffn + LN2 on the warp's 16 rows ----
  int isf32 = detect_f32(seq);
  u16* hb = blds + 16384 + (size_t)w * 16 * 136;   // per-warp [16][136]
  f32x4 acc1[8] = {};
  #pragma unroll
  for (int kt = 0; kt < 8; kt++) {
    bf16x8 a = ldb8(xw + (size_t)(lane & 15) * 264 + kt * 32 + (lane >> 4) * 8);
    const u16* bp = pW1 + ((size_t)kt * 8 * 64 + lane) * 8;
    #pragma unroll
    for (int nt = 0; nt < 8; nt++) {
      bf16x8 b = ldb8(bp + nt * 512);
      acc1[nt] = MFMA(a, b, acc1[nt]);
    }
  }
  #pragma unroll
  for (int nt = 0; nt < 8; nt++) {
    int col = nt * 16 + (lane & 15);
    float bb = b2f(vecs[512 + col]);
    #pragma unroll
    for (int r = 0; r < 4; r++) {
      float h = fmaxf(acc1[nt][r] + bb, 0.f);
      hb[((lane >> 4) * 4 + r) * 136 + col] = f2b(h);
    }
  }
  __syncthreads();
  f32x4 acc2[16] = {};
  #pragma unroll
  for (int ks = 0; ks < 4; ks++) {
    bf16x8 a = ldb8(hb + (size_t)(lane & 15) * 136 + ks * 32 + (lane >> 4) * 8);
    const u16* bp = pW2 + ((size_t)ks * 16 * 64 + lane) * 8;
    #pragma unroll
    for (int nt = 0; nt < 16; nt++) {
      bf16x8 b = ldb8(bp + nt * 512);
      acc2[nt] = MFMA(a, b, acc2[nt]);
    }
  }
  #pragma unroll
  for (int nt = 0; nt < 16; nt++) {
    int d = nt * 16 + (lane & 15);
    float bb = b2f(vecs[768 + d]);
    acc2[nt][0] += bb + b2f((u16)(xp[nt].x & 0xFFFF));
    acc2[nt][1] += bb + b2f((u16)(xp[nt].x >> 16));
    acc2[nt][2] += bb + b2f((u16)(xp[nt].y & 0xFFFF));
    acc2[nt][3] += bb + b2f((u16)(xp[nt].y >> 16));
  }
  float mu2[4], rs2[4];
  #pragma unroll
  for (int r = 0; r < 4; r++) {
    float sm = 0.f;
    #pragma unroll
    for (int nt = 0; nt < 16; nt++) sm += acc2[nt][r];
    sm += __shfl_xor(sm, 1); sm += __shfl_xor(sm, 2);
    sm += __shfl_xor(sm, 4); sm += __shfl_xor(sm, 8);
    mu2[r] = sm * (1.0f / 256.0f);
    float v = 0.f;
    #pragma unroll
    for (int nt = 0; nt < 16; nt++) { float dd = acc2[nt][r] - mu2[r]; v += dd * dd; }
    v += __shfl_xor(v, 1); v += __shfl_xor(v, 2);
    v += __shfl_xor(v, 4); v += __shfl_xor(v, 8);
    rs2[r] = rsqrtf(v * (1.0f / 256.0f) + 1e-5f);
  }
  #pragma unroll
  for (int nt = 0; nt < 16; nt++) {
    int d = nt * 16 + (lane & 15);
    float gg = b2f(vecs[1024 + d]), bb = b2f(vecs[1280 + d]);
    #pragma unroll
    for (int r = 0; r < 4; r++) {
      float val = (acc2[nt][r] - mu2[r]) * rs2[r] * gg + bb;
      size_t idx = (size_t)(rbase + r) * 256 + d;
      if (isf32) ((float*)out)[idx] = val;
      else       ((u16*)out)[idx]   = f2b(val);
    }
  }
}

// ---------------------------------------------------------------------------
// Fallback (hc<8): att_out(f32) += O_chunk @ Wo_chunk.  grid (128), 256 thr.
// ---------------------------------------------------------------------------
__global__ __launch_bounds__(256) void accum_kernel(
    const u16* __restrict__ Oc, const u16* __restrict__ pWo,
    float* __restrict__ att_out, int kt0, int hc) {
  __shared__ u16 blds[64 * 512];
  int tid = threadIdx.x, lane = tid & 63, w = tid >> 6;
  int m0 = blockIdx.x * 64 + w * 16;
  int arow = m0 + (lane & 15);
  int bq = arow >> 11, lrow = arow & 2047;
  int ktn = hc * 8;
  f32x4 acc[16] = {};
  for (int k0 = 0; k0 < ktn; k0 += 4) {
    __syncthreads();
    #pragma unroll
    for (int i = 0; i < 16; i++) {
      int fl = w + i * 4;
      int ktg = kt0 + k0 + (fl >> 4), nt = fl & 15;
      gload_lds16(pWo + ((size_t)(ktg * 16 + nt) * 64 + lane) * 8,
                  blds + (size_t)fl * 512);
    }
    asm volatile("s_waitcnt vmcnt(0)" ::: "memory");
    __syncthreads();
    #pragma unroll
    for (int kl = 0; kl < 4; kl++) {
      int ktl = k0 + kl;
      int hl = ktl >> 3;
      int d0 = (ktl & 7) * 32 + (lane >> 4) * 8;
      bf16x8 a = ldb8(Oc + ((size_t)(bq * hc + hl) * 2048 + lrow) * 256 + d0);
      const u16* bp = blds + (size_t)kl * 16 * 512 + (size_t)lane * 8;
      #pragma unroll
      for (int nt = 0; nt < 16; nt++) {
        bf16x8 b = ldb8(bp + nt * 512);
        acc[nt] = MFMA(a, b, acc[nt]);
      }
    }
  }
  int rbase = m0 + (lane >> 4) * 4;
  #pragma unroll
  for (int nt = 0; nt < 16; nt++) {
    int d = nt * 16 + (lane & 15);
    #pragma unroll
    for (int r = 0; r < 4; r++)
      att_out[(size_t)(rbase + r) * 256 + d] += acc[nt][r];
  }
}

// ---------------------------------------------------------------------------
// x = LN1(seq + att_out).  grid (2048), 256 threads; fallback path only.
// ---------------------------------------------------------------------------
__global__ __launch_bounds__(256) void ln1_kernel(
    const float* __restrict__ att_out, const u16* __restrict__ sbuf,
    const u16* __restrict__ vecs, u16* __restrict__ xout) {
  int tid = threadIdx.x, lane = tid & 63, w = tid >> 6;
  int row = blockIdx.x * 4 + w;
  const float* ar = att_out + (size_t)row * 256;
  f32x4 a = *(const f32x4*)(ar + lane * 4);
  uint2 sv = *(const uint2*)(sbuf + (size_t)row * 256 + lane * 4);
  float y[4];
  y[0] = a[0] + b2f((u16)(sv.x & 0xFFFF));
  y[1] = a[1] + b2f((u16)(sv.x >> 16));
  y[2] = a[2] + b2f((u16)(sv.y & 0xFFFF));
  y[3] = a[3] + b2f((u16)(sv.y >> 16));
  float sm = y[0] + y[1] + y[2] + y[3];
  sm += __shfl_xor(sm, 1);  sm += __shfl_xor(sm, 2);  sm += __shfl_xor(sm, 4);
  sm += __shfl_xor(sm, 8);  sm += __shfl_xor(sm, 16); sm += __shfl_xor(sm, 32);
  float mu = sm * (1.0f / 256.0f);
  float v = 0.f;
  #pragma unroll
  for (int j = 0; j < 4; j++) { float d = y[j] - mu; v += d * d; }
  v += __shfl_xor(v, 1);  v += __shfl_xor(v, 2);  v += __shfl_xor(v, 4);
  v += __shfl_xor(v, 8);  v += __shfl_xor(v, 16); v += __shfl_xor(v, 32);
  float rs = rsqrtf(v * (1.0f / 256.0f) + 1e-5f);
  u16 o[4];
  #pragma unroll
  for (int j = 0; j < 4; j++) {
    int d = lane * 4 + j;
    o[j] = f2b((y[j] - mu) * rs * b2f(vecs[d]) + b2f(vecs[256 + d]));
  }
  uint2 ov; ov.x = (u32)o[0] | ((u32)o[1] << 16); ov.y = (u32)o[2] | ((u32)o[3] << 16);
  *(uint2*)(xout + (size_t)row * 256 + lane * 4) = ov;
}

// ---------------------------------------------------------------------------
// FFN + LN2 (fallback path).  grid (256), 128 thr.
// ---------------------------------------------------------------------------
__global__ __launch_bounds__(128) void ffn_ln2_kernel(
    const u16* __restrict__ x, const u16* __restrict__ pW1,
    const u16* __restrict__ pW2, const u16* __restrict__ vecs,
    const void* __restrict__ seq, void* __restrict__ out) {
  __shared__ u16 hbuf[2 * 16 * 136];
  int isf32 = detect_f32(seq);
  int tid = threadIdx.x, lane = tid & 63, w = tid >> 6;   // w in {0,1}
  int m0 = blockIdx.x * 32 + w * 16;
  int arow = m0 + (lane & 15);
  u16* hb = hbuf + w * 16 * 136;
  f32x4 acc1[8] = {};
  #pragma unroll
  for (int kt = 0; kt < 8; kt++) {
    bf16x8 a = ldb8(x + (size_t)arow * 256 + kt * 32 + (lane >> 4) * 8);
    const u16* bp = pW1 + ((size_t)kt * 8 * 64 + lane) * 8;
    #pragma unroll
    for (int nt = 0; nt < 8; nt++) {
      bf16x8 b = ldb8(bp + nt * 512);
      acc1[nt] = MFMA(a, b, acc1[nt]);
    }
  }
  #pragma unroll
  for (int nt = 0; nt < 8; nt++) {
    int col = nt * 16 + (lane & 15);
    float bb = b2f(vecs[512 + col]);
    #pragma unroll
    for (int r = 0; r < 4; r++) {
      float h = fmaxf(acc1[nt][r] + bb, 0.f);
      hb[((lane >> 4) * 4 + r) * 136 + col] = f2b(h);
    }
  }
  __syncthreads();
  f32x4 acc2[16] = {};
  #pragma unroll
  for (int ks = 0; ks < 4; ks++) {
    bf16x8 a = ldb8(hb + (lane & 15) * 136 + ks * 32 + (lane >> 4) * 8);
    const u16* bp = pW2 + ((size_t)ks * 16 * 64 + lane) * 8;
    #pragma unroll
    for (int nt = 0; nt < 16; nt++) {
      bf16x8 b = ldb8(bp + nt * 512);
      acc2[nt] = MFMA(a, b, acc2[nt]);
    }
  }
  int rbase = m0 + (lane >> 4) * 4;
  #pragma unroll
  for (int nt = 0; nt < 16; nt++) {
    int d = nt * 16 + (lane & 15);
    float bb = b2f(vecs[768 + d]);
    #pragma unroll
    for (int r = 0; r < 4; r++)
      acc2[nt][r] += bb + b2f(x[(size_t)(rbase + r) * 256 + d]);
  }
  float mu[4], rs[4];
  #pragma unroll
  for (int r = 0; r < 4; r++) {
    float sm = 0.f;
    #pragma unroll
    for (int nt = 0; nt < 16; nt++) sm += acc2[nt][r];
    sm += __shfl_xor(sm, 1); sm += __shfl_xor(sm, 2);
    sm += __shfl_xor(sm, 4); sm += __shfl_xor(sm, 8);
    mu[r] = sm * (1.0f / 256.0f);
    float v = 0.f;
    #pragma unroll
    for (int nt = 0; nt < 16; nt++) { float dd = acc2[nt][r] - mu[r]; v += dd * dd; }
    v += __shfl_xor(v, 1); v += __shfl_xor(v, 2);
    v += __shfl_xor(v, 4); v += __shfl_xor(v, 8);
    rs[r] = rsqrtf(v * (1.0f / 256.0f) + 1e-5f);
  }
  #pragma unroll
  for (int nt = 0; nt < 16; nt++) {
    int d = nt * 16 + (lane & 15);
    float gg = b2f(vecs[1024 + d]), bb = b2f(vecs[1280 + d]);
    #pragma unroll
    for (int r = 0; r < 4; r++) {
      float val = (acc2[nt][r] - mu[r]) * rs[r] * gg + bb;
      size_t idx = (size_t)(rbase + r) * 256 + d;
      if (isf32) ((float*)out)[idx] = val;
      else       ((u16*)out)[idx]   = f2b(val);
    }
  }
}

// ---------------------------------------------------------------------------
__global__ __launch_bounds__(256) void sentinel_kernel(void* out, int n,
                                                       const void* seq) {
  int isf32 = detect_f32(seq);
  int i = blockIdx.x * 256 + threadIdx.x;
  if (i < n) {
    if (isf32) ((float*)out)[i] = 777.0f;
    else       ((u16*)out)[i]   = 0x4442;
  }
}

// ---------------------------------------------------------------------------
extern "C" void kernel_launch(void* const* d_in, const int* in_sizes, int n_in,
                              void* d_out, int out_size, void* d_ws, size_t ws_size,
                              hipStream_t stream) {
  (void)in_sizes; (void)n_in;
  const void* seq  = d_in[0];
  const void* Wq   = d_in[1];
  const void* Wk   = d_in[2];
  const void* Wv   = d_in[3];
  const void* Wo   = d_in[4];
  const void* g1   = d_in[5];
  const void* be1  = d_in[6];
  const void* W1   = d_in[7];
  const void* b1   = d_in[8];
  const void* W2   = d_in[9];
  const void* b2   = d_in[10];
  const void* g2   = d_in[11];
  const void* be2  = d_in[12];

  size_t o = 0;
  u16* ws = (u16*)d_ws;
  u16* pWq = ws + o; o += 524288;
  u16* pWk = ws + o; o += 524288;
  u16* pWv = ws + o; o += 524288;
  u16* pWo = ws + o; o += 524288;
  u16* pW1 = ws + o; o += 32768;
  u16* pW2 = ws + o; o += 32768;
  float* att = (float*)(ws + o); o += 4194304;   // 2M f32 (fallback path)
  u16* xb   = ws + o; o += 2097152;
  u16* sbuf = ws + o; o += 2097152;
  u16* vecs = ws + o; o += 2048;
  size_t fixed_elems = o;

  int hc = 0;
  for (int c = 8; c >= 1; c >>= 1) {
    size_t need = (fixed_elems + (size_t)4 * c * 2097152) * 2;
    if (need <= ws_size) { hc = c; break; }
  }
  if (hc == 0) {
    sentinel_kernel<<<dim3((out_size + 255) / 256), 256, 0, stream>>>(
        d_out, out_size, seq);
    return;
  }
  u16* Qc = ws + o; o += (size_t)hc * 2097152;
  u16* Kc = ws + o; o += (size_t)hc * 2097152;
  u16* Vc = ws + o; o += (size_t)hc * 2097152;   // V^T [B,hc,D,L]
  u16* Oc = ws + o;

  ingest_pack_kernel<<<dim3(2054 + 1536), 256, 0, stream>>>(
      seq, g1, be1, b1, b2, g2, be2, sbuf, vecs,
      Wq, Wk, Wv, Wo, W1, W2, pWq, pWk, pWv, pWo, pW1, pW2);
  if (hc == 8) {
    // single-chunk fast path: 4 dispatches total
    qkv_kernel<<<dim3(16, 16, 3), 256, 0, stream>>>(
        sbuf, pWq, pWk, pWv, Qc, Kc, Vc, 0, 8);
    attn_kernel<<<dim3(32 * 16), 512, 0, stream>>>(Qc, Kc, Vc, Oc, 32);
    accum_ln1_ffn_ln2_kernel<<<dim3(256), 128, 0, stream>>>(
        Oc, pWo, sbuf, vecs, pW1, pW2, seq, (void*)d_out);
  } else {
    hipMemsetAsync(att, 0, 2097152 * sizeof(float), stream);
    int nchunks = 8 / hc;
    for (int c = 0; c < nchunks; c++) {
      int nbh = 4 * hc;
      qkv_kernel<<<dim3(2 * hc, 16, 3), 256, 0, stream>>>(
          sbuf, pWq, pWk, pWv, Qc, Kc, Vc, c * hc * 16, hc);
      attn_kernel<<<dim3(nbh * 16), 512, 0, stream>>>(Qc, Kc, Vc, Oc, nbh);
      accum_kernel<<<dim3(128), 256, 0, stream>>>(Oc, pWo, att, c * hc * 8, hc);
    }
    ln1_kernel<<<dim3(2048), 256, 0, stream>>>(att, sbuf, vecs, xb);
    ffn_ln2_kernel<<<dim3(256), 128, 0, stream>>>(xb, pW1, pW2, vecs, seq,
                                                  (void*)d_out);
  }
}